// Round 5
// baseline (746.057 us; speedup 1.0000x reference)
//
#include <hip/hip_runtime.h>
#include <hip/hip_bf16.h>

typedef __bf16 bf16;
typedef __attribute__((ext_vector_type(8))) __bf16 bf16x8;
typedef __attribute__((ext_vector_type(4))) __bf16 bf16x4;
typedef __attribute__((ext_vector_type(4))) float f32x4;

__device__ __forceinline__ bf16 f2bf(float f) { return (bf16)f; }

// async global->LDS, 16B per lane. LDS dest must be uniform-base + lane*16.
__device__ __forceinline__ void async_cp16(const void* g, void* l) {
    __builtin_amdgcn_global_load_lds(
        (const __attribute__((address_space(1))) unsigned int*)g,
        (__attribute__((address_space(3))) unsigned int*)l, 16, 0, 0);
}

// ---------------------------------------------------------------------------
// Positional encoding value for channel c, token t (t = h*64 + w)
// ---------------------------------------------------------------------------
__device__ __forceinline__ float pe_val(int c, int t) {
    int h = t >> 6, w = t & 63;
    int i = c >> 2, j = c & 3;
    float div = expf(-0.14391156831212787f * (float)i);
    float arg = ((j < 2) ? (float)w : (float)h) * div;
    return (j & 1) ? cosf(arg) : sinf(arg);
}

// ---------------------------------------------------------------------------
// Encode: feat (4,256,4096) f32 -> Xb[b,t,c] bf16, P2b bf16 (PE added).
// ---------------------------------------------------------------------------
__global__ __launch_bounds__(1024) void encode_kernel(const float* __restrict__ ref,
                                                      const float* __restrict__ src,
                                                      bf16* __restrict__ Xb,
                                                      bf16* __restrict__ P2b) {
    __shared__ float tile[32][33];
    int n = blockIdx.z >> 1, sel = blockIdx.z & 1;
    const float* f = sel ? src : ref;
    int t = blockIdx.x * 32 + threadIdx.x;
    int c = blockIdx.y * 32 + threadIdx.y;
    float v = f[((size_t)n * 256 + c) * 4096 + t] + pe_val(c, t);
    tile[threadIdx.y][threadIdx.x] = v;
    __syncthreads();
    int tt = blockIdx.x * 32 + threadIdx.y;
    int cc = blockIdx.y * 32 + threadIdx.x;
    float o = tile[threadIdx.x][threadIdx.y];
    int bx = sel ? 4 + n : n;
    int bp = sel ? n : 4 + n;
    Xb [((size_t)bx * 4096 + tt) * 256 + cc] = f2bf(o);
    P2b[((size_t)bp * 4096 + tt) * 256 + cc] = f2bf(o);
}

// ---------------------------------------------------------------------------
// Weight transpose+convert: W[K,N] f32 -> Wt[N,K] bf16, all 24 mats, 1 launch
// ---------------------------------------------------------------------------
__global__ __launch_bounds__(1024) void wt_conv(const float* __restrict__ Wq, const float* __restrict__ Wk,
                                                const float* __restrict__ Wv, const float* __restrict__ Wo,
                                                const float* __restrict__ W1, const float* __restrict__ W2,
                                                bf16* __restrict__ Wt) {
    __shared__ float t[32][33];
    int z = blockIdx.z, L = z / 6, m = z - L * 6;
    const float* src; int K, N, doff;
    if      (m == 0) { src = Wq + L * 65536;  K = 256; N = 256; doff = 0; }
    else if (m == 1) { src = Wk + L * 65536;  K = 256; N = 256; doff = 65536; }
    else if (m == 2) { src = Wv + L * 65536;  K = 256; N = 256; doff = 131072; }
    else if (m == 3) { src = Wo + L * 65536;  K = 256; N = 256; doff = 196608; }
    else if (m == 4) { src = W1 + L * 131072; K = 256; N = 512; doff = 262144; }
    else             { src = W2 + L * 131072; K = 512; N = 256; doff = 393216; }
    int n0 = blockIdx.x * 32, k0 = blockIdx.y * 32;
    if (n0 >= N || k0 >= K) return;
    t[threadIdx.y][threadIdx.x] = src[(size_t)(k0 + threadIdx.y) * N + n0 + threadIdx.x];
    __syncthreads();
    bf16* dst = Wt + (size_t)L * 524288 + doff;
    dst[(size_t)(n0 + threadIdx.y) * K + k0 + threadIdx.x] = f2bf(t[threadIdx.x][threadIdx.y]);
}

// ---------------------------------------------------------------------------
// Fused QKV GEMM. LDS-staged epilogue -> bf16x8 (16B) coalesced stores.
// (verified: 55.5 -> 42.9 us vs scalar-store epilogue)
// ---------------------------------------------------------------------------
__global__ __launch_bounds__(256) void gemm_qkv(const bf16* __restrict__ Aq,
                                                const bf16* __restrict__ Akv,
                                                const bf16* __restrict__ Wt,
                                                const float* __restrict__ bq,
                                                const float* __restrict__ bk,
                                                const float* __restrict__ bv,
                                                bf16* __restrict__ Q,
                                                bf16* __restrict__ Ko,
                                                bf16* __restrict__ V) {
    __shared__ __align__(16) char qsm[128 * 140 * 2];  // 35840 B
    bf16* Als = (bf16*)qsm;              // [128][64] during K loop
    bf16* Bls = (bf16*)(qsm + 16384);    // [128][64] during K loop
    bf16* Cls = (bf16*)qsm;              // [128][140] epilogue
    int tid = threadIdx.x;
    int wave = tid >> 6, lane = tid & 63;
    int bm = blockIdx.y * 128, bn = blockIdx.x * 128;
    int wm = (wave >> 1) * 64, wn = (wave & 1) * 64;
    int l15 = lane & 15, g = lane >> 4;
    const int K = 256;

    int seg = bn >> 8, cloc = bn & 255;
    const bf16* A = seg == 0 ? Aq : Akv;
    const float* bias = seg == 0 ? bq : (seg == 1 ? bk : bv);
    bf16* Out = seg == 0 ? Q : (seg == 1 ? Ko : V);
    bool do_elu = seg < 2;

    f32x4 acc[4][4] = {};

    for (int k0 = 0; k0 < K; k0 += 64) {
#pragma unroll
        for (int r = 0; r < 4; ++r) {
            int Lc = r * 256 + tid;
            int row = Lc >> 3, cs = Lc & 7;
            int gc = cs ^ (row & 7);
            async_cp16(A  + (size_t)(bm + row) * K + k0 + gc * 8, &Als[Lc * 8]);
            async_cp16(Wt + (size_t)(bn + row) * K + k0 + gc * 8, &Bls[Lc * 8]);
        }
        __syncthreads();
#pragma unroll
        for (int ks = 0; ks < 2; ++ks) {
            bf16x8 af[4], bfr[4];
#pragma unroll
            for (int i = 0; i < 4; ++i) {
                int row = wm + i * 16 + l15;
                int c = ks * 4 + g;
                af[i] = *(bf16x8*)&Als[row * 64 + ((c ^ (row & 7)) * 8)];
            }
#pragma unroll
            for (int j = 0; j < 4; ++j) {
                int row = wn + j * 16 + l15;
                int c = ks * 4 + g;
                bfr[j] = *(bf16x8*)&Bls[row * 64 + ((c ^ (row & 7)) * 8)];
            }
#pragma unroll
            for (int i = 0; i < 4; ++i)
#pragma unroll
                for (int j = 0; j < 4; ++j)
                    acc[i][j] = __builtin_amdgcn_mfma_f32_16x16x32_bf16(af[i], bfr[j], acc[i][j], 0, 0, 0);
        }
        __syncthreads();
    }

    int r4 = (lane >> 4) * 4;
#pragma unroll
    for (int i = 0; i < 4; ++i) {
#pragma unroll
        for (int j = 0; j < 4; ++j) {
            int col = wn + j * 16 + l15;
            float bvv = bias[cloc + col];
#pragma unroll
            for (int r = 0; r < 4; ++r) {
                float v = acc[i][j][r] + bvv;
                if (do_elu) v = v > 0.f ? v + 1.f : expf(v);
                Cls[(wm + i * 16 + r4 + r) * 140 + col] = f2bf(v);
            }
        }
    }
    __syncthreads();
    int row = tid >> 1, half = tid & 1;
    const bf16* srcr = Cls + row * 140 + half * 64;
    bf16* dstr = Out + (size_t)(bm + row) * 256 + cloc + half * 64;
#pragma unroll
    for (int u = 0; u < 8; ++u)
        *(bf16x8*)(dstr + u * 8) = *(const bf16x8*)(srcr + u * 8);
}

// ---------------------------------------------------------------------------
// MFMA GEMM (FFN1): relu(A @ Wt^T + bias), LDS-staged vectorized epilogue.
// ---------------------------------------------------------------------------
template <int RELU>
__global__ __launch_bounds__(256) void gemm_mfma(const bf16* __restrict__ A,
                                                 const bf16* __restrict__ Wt,
                                                 const float* __restrict__ bias,
                                                 bf16* __restrict__ C,
                                                 int N, int K) {
    __shared__ __align__(16) char qsm[128 * 140 * 2];
    bf16* Als = (bf16*)qsm;
    bf16* Bls = (bf16*)(qsm + 16384);
    bf16* Cls = (bf16*)qsm;
    int tid = threadIdx.x;
    int wave = tid >> 6, lane = tid & 63;
    int bm = blockIdx.y * 128, bn = blockIdx.x * 128;
    int wm = (wave >> 1) * 64, wn = (wave & 1) * 64;
    int l15 = lane & 15, g = lane >> 4;

    f32x4 acc[4][4] = {};

    for (int k0 = 0; k0 < K; k0 += 64) {
#pragma unroll
        for (int r = 0; r < 4; ++r) {
            int Lc = r * 256 + tid;
            int row = Lc >> 3, cs = Lc & 7;
            int gc = cs ^ (row & 7);
            async_cp16(A  + (size_t)(bm + row) * K + k0 + gc * 8, &Als[Lc * 8]);
            async_cp16(Wt + (size_t)(bn + row) * K + k0 + gc * 8, &Bls[Lc * 8]);
        }
        __syncthreads();
#pragma unroll
        for (int ks = 0; ks < 2; ++ks) {
            bf16x8 af[4], bfr[4];
#pragma unroll
            for (int i = 0; i < 4; ++i) {
                int row = wm + i * 16 + l15;
                int c = ks * 4 + g;
                af[i] = *(bf16x8*)&Als[row * 64 + ((c ^ (row & 7)) * 8)];
            }
#pragma unroll
            for (int j = 0; j < 4; ++j) {
                int row = wn + j * 16 + l15;
                int c = ks * 4 + g;
                bfr[j] = *(bf16x8*)&Bls[row * 64 + ((c ^ (row & 7)) * 8)];
            }
#pragma unroll
            for (int i = 0; i < 4; ++i)
#pragma unroll
                for (int j = 0; j < 4; ++j)
                    acc[i][j] = __builtin_amdgcn_mfma_f32_16x16x32_bf16(af[i], bfr[j], acc[i][j], 0, 0, 0);
        }
        __syncthreads();
    }

    int r4 = (lane >> 4) * 4;
#pragma unroll
    for (int i = 0; i < 4; ++i) {
#pragma unroll
        for (int j = 0; j < 4; ++j) {
            int col = wn + j * 16 + l15;
            float bvv = bias[bn + col];
#pragma unroll
            for (int r = 0; r < 4; ++r) {
                float v = acc[i][j][r] + bvv;
                if (RELU) v = fmaxf(v, 0.f);
                Cls[(wm + i * 16 + r4 + r) * 140 + col] = f2bf(v);
            }
        }
    }
    __syncthreads();
    int row = tid >> 1, half = tid & 1;
    const bf16* srcr = Cls + row * 140 + half * 64;
    bf16* dstr = C + (size_t)(bm + row) * N + bn + half * 64;
#pragma unroll
    for (int u = 0; u < 8; ++u)
        *(bf16x8*)(dstr + u * 8) = *(const bf16x8*)(srcr + u * 8);
}

// ---------------------------------------------------------------------------
// Fused GEMM (N=256) + residual + LayerNorm epilogue writing Xb in place.
// (FFN2 path)
// ---------------------------------------------------------------------------
__global__ __launch_bounds__(512) void gemm_ln(const bf16* __restrict__ A,
                                               const bf16* __restrict__ Wt,
                                               const float* __restrict__ bias,
                                               bf16* __restrict__ Xb,
                                               const float* __restrict__ g,
                                               const float* __restrict__ b,
                                               int K) {
    __shared__ __align__(16) char smem[128 * 260 * 2];  // 66560 B
    bf16* Als = (bf16*)smem;            // [128][64]  16 KB (during K loop)
    bf16* Bls = (bf16*)(smem + 16384);  // [256][64]  32 KB (during K loop)
    bf16* Cls = (bf16*)smem;            // [128][260] after K loop

    int tid = threadIdx.x;
    int wave = tid >> 6, lane = tid & 63;
    int bm = blockIdx.x * 128;
    int wm = (wave >> 2) * 64, wn = (wave & 3) * 64;
    int l15 = lane & 15, gg = lane >> 4;

    f32x4 acc[4][4] = {};

    for (int k0 = 0; k0 < K; k0 += 64) {
#pragma unroll
        for (int r = 0; r < 2; ++r) {   // A tile: 128x64
            int Lc = r * 512 + tid;
            int row = Lc >> 3, cs = Lc & 7;
            int gc = cs ^ (row & 7);
            async_cp16(A + (size_t)(bm + row) * K + k0 + gc * 8, &Als[Lc * 8]);
        }
#pragma unroll
        for (int r = 0; r < 4; ++r) {   // B tile: 256x64
            int Lc = r * 512 + tid;
            int row = Lc >> 3, cs = Lc & 7;
            int gc = cs ^ (row & 7);
            async_cp16(Wt + (size_t)row * K + k0 + gc * 8, &Bls[Lc * 8]);
        }
        __syncthreads();
#pragma unroll
        for (int ks = 0; ks < 2; ++ks) {
            bf16x8 af[4], bfr[4];
#pragma unroll
            for (int i = 0; i < 4; ++i) {
                int row = wm + i * 16 + l15;
                int c = ks * 4 + gg;
                af[i] = *(bf16x8*)&Als[row * 64 + ((c ^ (row & 7)) * 8)];
            }
#pragma unroll
            for (int j = 0; j < 4; ++j) {
                int row = wn + j * 16 + l15;
                int c = ks * 4 + gg;
                bfr[j] = *(bf16x8*)&Bls[row * 64 + ((c ^ (row & 7)) * 8)];
            }
#pragma unroll
            for (int i = 0; i < 4; ++i)
#pragma unroll
                for (int j = 0; j < 4; ++j)
                    acc[i][j] = __builtin_amdgcn_mfma_f32_16x16x32_bf16(af[i], bfr[j], acc[i][j], 0, 0, 0);
        }
        __syncthreads();
    }

    int r4 = (lane >> 4) * 4;
#pragma unroll
    for (int j = 0; j < 4; ++j) {
        int col = wn + j * 16 + l15;
        float bvv = bias[col];
#pragma unroll
        for (int i = 0; i < 4; ++i)
#pragma unroll
            for (int r = 0; r < 4; ++r)
                Cls[(wm + i * 16 + r4 + r) * 260 + col] = f2bf(acc[i][j][r] + bvv);
    }
    __syncthreads();

    int c4 = lane * 4;
    float4 gw = *(const float4*)&g[c4];
    float4 bw = *(const float4*)&b[c4];
#pragma unroll 2
    for (int rw = 0; rw < 16; ++rw) {
        int row = wave * 16 + rw;
        size_t gidx = (size_t)(bm + row) * 256 + c4;
        bf16x4 xb = *(const bf16x4*)(Xb + gidx);
        bf16x4 cb = *(const bf16x4*)&Cls[row * 260 + c4];
        float4 v;
        v.x = (float)xb[0] + (float)cb[0];
        v.y = (float)xb[1] + (float)cb[1];
        v.z = (float)xb[2] + (float)cb[2];
        v.w = (float)xb[3] + (float)cb[3];
        float s  = v.x + v.y + v.z + v.w;
        float sq = v.x * v.x + v.y * v.y + v.z * v.z + v.w * v.w;
#pragma unroll
        for (int off = 32; off > 0; off >>= 1) {
            s  += __shfl_xor(s,  off);
            sq += __shfl_xor(sq, off);
        }
        float mean = s * (1.f / 256.f);
        float var  = sq * (1.f / 256.f) - mean * mean;
        float rstd = rsqrtf(var + 1e-5f);
        bf16x4 ob;
        ob[0] = f2bf((v.x - mean) * rstd * gw.x + bw.x);
        ob[1] = f2bf((v.y - mean) * rstd * gw.y + bw.y);
        ob[2] = f2bf((v.z - mean) * rstd * gw.z + bw.z);
        ob[3] = f2bf((v.w - mean) * rstd * gw.w + bw.w);
        *(bf16x4*)(Xb + gidx) = ob;
    }
}

// ---------------------------------------------------------------------------
// Fused attention + O-projection + residual + LN1 (R3 version, measured 54.6us)
// ---------------------------------------------------------------------------
__global__ __launch_bounds__(512) void attn_oln(const bf16* __restrict__ Qb,
                                                const float* __restrict__ KV,
                                                const float* __restrict__ Ksum,
                                                const bf16* __restrict__ Wt,
                                                const float* __restrict__ bias,
                                                bf16* __restrict__ Xb,
                                                const float* __restrict__ g,
                                                const float* __restrict__ b) {
    __shared__ __align__(16) char smem[132096];
    __shared__ float Zs[32][8];
    float* Qs  = (float*)smem;               // [32][260] f32 (phase 1)
    bf16*  Wls = (bf16*)smem;                // [256*64]  (phase 2)
    bf16*  Cls = (bf16*)smem;                // [128][260] (phase 3)
    bf16*  Bt  = (bf16*)(smem + 66560);      // [4][128][64] swizzled A-tile

    int tid = threadIdx.x;
    int r0 = blockIdx.x * 128;               // global row (= n*4096 + token)
    int n = r0 >> 12;

    int c = tid & 255, tg = tid >> 8;
    int h = c >> 5, m = c & 31;
    float kvr[32];
    const float* kvp = KV + (size_t)(n * 8 + h) * 1024 + m * 32;
#pragma unroll
    for (int q4 = 0; q4 < 8; ++q4) *(float4*)&kvr[q4 * 4] = *(const float4*)(kvp + q4 * 4);

    int col8 = (c >> 3) & 7, elem = c & 7, slice = c >> 6;

    for (int it = 0; it < 4; ++it) {
        int t0 = it * 32;
        const bf16* qsrc = Qb + (size_t)(r0 + t0) * 256;
#pragma unroll
        for (int kk = 0; kk < 2; ++kk) {
            int e8 = kk * 512 + tid;
            bf16x8 v = *(const bf16x8*)(qsrc + (size_t)e8 * 8);
            int t = e8 >> 5, c8 = e8 & 31;
#pragma unroll
            for (int u = 0; u < 8; ++u) Qs[t * 260 + c8 * 8 + u] = (float)v[u];
        }
        __syncthreads();
        if (tid < 256) {
            int tz = tid >> 3, hz = tid & 7;
            const float* ksp = Ksum + n * 256 + hz * 32;
            float z = 0.f;
#pragma unroll
            for (int q4 = 0; q4 < 8; ++q4) {
                float4 qv = *(float4*)&Qs[tz * 260 + hz * 32 + q4 * 4];
                float4 kq = *(const float4*)(ksp + q4 * 4);
                z += qv.x * kq.x + qv.y * kq.y + qv.z * kq.z + qv.w * kq.w;
            }
            Zs[tz][hz] = 1.f / (z + 1e-6f);
        }
        __syncthreads();
#pragma unroll 2
        for (int tt = 0; tt < 16; ++tt) {
            int t = tg * 16 + tt;
            float acc = 0.f;
#pragma unroll
            for (int q4 = 0; q4 < 8; ++q4) {
                float4 qv = *(float4*)&Qs[t * 260 + h * 32 + q4 * 4];
                acc += qv.x * kvr[q4 * 4 + 0] + qv.y * kvr[q4 * 4 + 1]
                     + qv.z * kvr[q4 * 4 + 2] + qv.w * kvr[q4 * 4 + 3];
            }
            int row = t0 + t;
            Bt[slice * 8192 + row * 64 + ((col8 ^ (row & 7)) * 8) + elem] =
                f2bf(acc * Zs[t][h]);
        }
        __syncthreads();
    }

    // Phase 2: C[128][256] = Bt @ Wo^T
    int wave = tid >> 6, lane = tid & 63;
    int wm = (wave >> 2) * 64, wn = (wave & 3) * 64;
    int l15 = lane & 15, gg = lane >> 4;
    f32x4 acc[4][4] = {};

    for (int k0 = 0; k0 < 256; k0 += 64) {
#pragma unroll
        for (int r = 0; r < 4; ++r) {   // Wo tile: 256x64
            int Lc = r * 512 + tid;
            int row = Lc >> 3, cs = Lc & 7;
            int gc = cs ^ (row & 7);
            async_cp16(Wt + (size_t)row * 256 + k0 + gc * 8, &Wls[Lc * 8]);
        }
        __syncthreads();
        const bf16* Asl = Bt + (k0 >> 6) * 8192;
#pragma unroll
        for (int ks = 0; ks < 2; ++ks) {
            bf16x8 af[4], bfr[4];
#pragma unroll
            for (int i = 0; i < 4; ++i) {
                int row = wm + i * 16 + l15;
                int cc = ks * 4 + gg;
                af[i] = *(bf16x8*)&Asl[row * 64 + ((cc ^ (row & 7)) * 8)];
            }
#pragma unroll
            for (int j = 0; j < 4; ++j) {
                int row = wn + j * 16 + l15;
                int cc = ks * 4 + gg;
                bfr[j] = *(bf16x8*)&Wls[row * 64 + ((cc ^ (row & 7)) * 8)];
            }
#pragma unroll
            for (int i = 0; i < 4; ++i)
#pragma unroll
                for (int j = 0; j < 4; ++j)
                    acc[i][j] = __builtin_amdgcn_mfma_f32_16x16x32_bf16(af[i], bfr[j], acc[i][j], 0, 0, 0);
        }
        __syncthreads();
    }

    // Phase 3: C -> LDS, residual + LN into Xb
    int r4 = (lane >> 4) * 4;
#pragma unroll
    for (int j = 0; j < 4; ++j) {
        int col = wn + j * 16 + l15;
        float bvv = bias[col];
#pragma unroll
        for (int i = 0; i < 4; ++i)
#pragma unroll
            for (int r = 0; r < 4; ++r)
                Cls[(wm + i * 16 + r4 + r) * 260 + col] = f2bf(acc[i][j][r] + bvv);
    }
    __syncthreads();

    int c4 = lane * 4;
    float4 gw = *(const float4*)&g[c4];
    float4 bw = *(const float4*)&b[c4];
#pragma unroll 2
    for (int rw = 0; rw < 16; ++rw) {
        int row = wave * 16 + rw;
        size_t gidx = (size_t)(r0 + row) * 256 + c4;
        bf16x4 xb = *(const bf16x4*)(Xb + gidx);
        bf16x4 cb = *(const bf16x4*)&Cls[row * 260 + c4];
        float4 v;
        v.x = (float)xb[0] + (float)cb[0];
        v.y = (float)xb[1] + (float)cb[1];
        v.z = (float)xb[2] + (float)cb[2];
        v.w = (float)xb[3] + (float)cb[3];
        float s  = v.x + v.y + v.z + v.w;
        float sq = v.x * v.x + v.y * v.y + v.z * v.z + v.w * v.w;
#pragma unroll
        for (int off = 32; off > 0; off >>= 1) {
            s  += __shfl_xor(s,  off);
            sq += __shfl_xor(sq, off);
        }
        float mean = s * (1.f / 256.f);
        float var  = sq * (1.f / 256.f) - mean * mean;
        float rstd = rsqrtf(var + 1e-5f);
        bf16x4 ob;
        ob[0] = f2bf((v.x - mean) * rstd * gw.x + bw.x);
        ob[1] = f2bf((v.y - mean) * rstd * gw.y + bw.y);
        ob[2] = f2bf((v.z - mean) * rstd * gw.z + bw.z);
        ob[3] = f2bf((v.w - mean) * rstd * gw.w + bw.w);
        *(bf16x4*)(Xb + gidx) = ob;
    }
}

// ---------------------------------------------------------------------------
// KV prep: grid (32 sp, 64 nh), 256 thr = 4 waves.
// ---------------------------------------------------------------------------
__global__ __launch_bounds__(256) void kv_prep_part(const bf16* __restrict__ Kb,
                                                    const bf16* __restrict__ Vb,
                                                    float* __restrict__ Pkv,
                                                    float* __restrict__ Pks) {
    __shared__ float Ks[128][32];
    __shared__ float Vs[128][32];
    int sp = blockIdx.x;
    int nh = blockIdx.y;
    int n = nh >> 3, h = nh & 7;
    int tid = threadIdx.x;
    int wave = tid >> 6, lane = tid & 63;
    int mg = lane >> 3;
    int dg = lane & 7;
    size_t base = ((size_t)n * 4096 + sp * 128) * 256 + h * 32;

#pragma unroll
    for (int p = 0; p < 2; ++p) {
        int r = p * 64 + (tid >> 2);
        int c = (tid & 3) * 8;
        bf16x8 k8 = *(const bf16x8*)(Kb + base + (size_t)r * 256 + c);
        bf16x8 v8 = *(const bf16x8*)(Vb + base + (size_t)r * 256 + c);
#pragma unroll
        for (int u = 0; u < 8; ++u) { Ks[r][c + u] = (float)k8[u]; Vs[r][c + u] = (float)v8[u]; }
    }
    __syncthreads();

    float acc[4][4] = {};
    float ks4[4] = {};
    int s0 = wave * 32;
    for (int s = s0; s < s0 + 32; ++s) {
        float4 kq = *(float4*)&Ks[s][dg * 4];
        float4 vq = *(float4*)&Vs[s][mg * 4];
        ks4[0] += kq.x; ks4[1] += kq.y; ks4[2] += kq.z; ks4[3] += kq.w;
        acc[0][0] += vq.x * kq.x; acc[0][1] += vq.x * kq.y; acc[0][2] += vq.x * kq.z; acc[0][3] += vq.x * kq.w;
        acc[1][0] += vq.y * kq.x; acc[1][1] += vq.y * kq.y; acc[1][2] += vq.y * kq.z; acc[1][3] += vq.y * kq.w;
        acc[2][0] += vq.z * kq.x; acc[2][1] += vq.z * kq.y; acc[2][2] += vq.z * kq.z; acc[2][3] += vq.z * kq.w;
        acc[3][0] += vq.w * kq.x; acc[3][1] += vq.w * kq.y; acc[3][2] += vq.w * kq.z; acc[3][3] += vq.w * kq.w;
    }
    __syncthreads();

    float* R  = &Ks[0][0];
    float* RS = &Vs[0][0];
#pragma unroll
    for (int mi = 0; mi < 4; ++mi)
#pragma unroll
        for (int dj = 0; dj < 4; ++dj)
            R[wave * 1024 + (mg * 4 + mi) * 32 + dg * 4 + dj] = acc[mi][dj];
    if (mg == 0)
#pragma unroll
        for (int dj = 0; dj < 4; ++dj) RS[wave * 32 + dg * 4 + dj] = ks4[dj];
    __syncthreads();

    int e = tid * 4;
    float4 o0 = *(float4*)&R[e];
    float4 o1 = *(float4*)&R[1024 + e];
    float4 o2 = *(float4*)&R[2048 + e];
    float4 o3 = *(float4*)&R[3072 + e];
    float4 o = make_float4(o0.x + o1.x + o2.x + o3.x, o0.y + o1.y + o2.y + o3.y,
                           o0.z + o1.z + o2.z + o3.z, o0.w + o1.w + o2.w + o3.w);
    *(float4*)&Pkv[((size_t)nh * 32 + sp) * 1024 + e] = o;
    if (tid < 32)
        Pks[((size_t)nh * 32 + sp) * 32 + tid] = RS[tid] + RS[32 + tid] + RS[64 + tid] + RS[96 + tid];
}

// grid (64 nh, 4 quarters), 64 threads (1 wave).
__global__ __launch_bounds__(64) void kv_reduce(const float* __restrict__ Pkv,
                                                const float* __restrict__ Pks,
                                                float* __restrict__ KV,
                                                float* __restrict__ Ksum) {
    int nh = blockIdx.x;
    int q = blockIdx.y;
    int e = (q * 64 + threadIdx.x) * 4;
    float4 s = make_float4(0.f, 0.f, 0.f, 0.f);
    for (int sp = 0; sp < 32; ++sp) {
        float4 p = *(const float4*)&Pkv[((size_t)nh * 32 + sp) * 1024 + e];
        s.x += p.x; s.y += p.y; s.z += p.z; s.w += p.w;
    }
    *(float4*)&KV[(size_t)nh * 1024 + e] = s;
    if (q == 0 && threadIdx.x < 32) {
        float ss = 0.f;
        for (int sp = 0; sp < 32; ++sp) ss += Pks[((size_t)nh * 32 + sp) * 32 + threadIdx.x];
        Ksum[nh * 32 + threadIdx.x] = ss;
    }
}

// ---------------------------------------------------------------------------
// Store: Xb[b,t,c] bf16 -> out[b,c,t] f32
// ---------------------------------------------------------------------------
__global__ __launch_bounds__(1024) void store_kernel(const bf16* __restrict__ Xb,
                                                     float* __restrict__ out) {
    __shared__ float tile[32][33];
    int b = blockIdx.z;
    int t0 = blockIdx.x * 32, c0 = blockIdx.y * 32;
    tile[threadIdx.y][threadIdx.x] =
        (float)Xb[((size_t)b * 4096 + t0 + threadIdx.y) * 256 + c0 + threadIdx.x];
    __syncthreads();
    out[((size_t)b * 256 + c0 + threadIdx.y) * 4096 + t0 + threadIdx.x] =
        tile[threadIdx.x][threadIdx.y];
}

// ---------------------------------------------------------------------------
extern "C" void kernel_launch(void* const* d_in, const int* in_sizes, int n_in,
                              void* d_out, int out_size, void* d_ws, size_t ws_size,
                              hipStream_t stream) {
    const float* ref  = (const float*)d_in[0];
    const float* srcf = (const float*)d_in[1];
    const float* Wq = (const float*)d_in[2];
    const float* bq = (const float*)d_in[3];
    const float* Wk = (const float*)d_in[4];
    const float* bk = (const float*)d_in[5];
    const float* Wv = (const float*)d_in[6];
    const float* bv = (const float*)d_in[7];
    const float* Wo = (const float*)d_in[8];
    const float* bo = (const float*)d_in[9];
    const float* W1 = (const float*)d_in[10];
    const float* b1 = (const float*)d_in[11];
    const float* W2 = (const float*)d_in[12];
    const float* b2 = (const float*)d_in[13];
    const float* g1 = (const float*)d_in[14];
    const float* be1 = (const float*)d_in[15];
    const float* g2 = (const float*)d_in[16];
    const float* be2 = (const float*)d_in[17];

    const size_t SZ = (size_t)8 * 4096 * 256;
    float* ws  = (float*)d_ws;
    float* KVb = ws;                          // 65536 f32
    float* Ksb = KVb + 65536;                 // 2048 f32
    float* Pkv = Ksb + 2048;                  // 2,097,152 f32
    float* Pks = Pkv + 2097152;               // 65536 f32
    bf16*  Wt  = (bf16*)(Pks + 65536);        // 2,097,152 bf16
    bf16*  Xb  = Wt + 2097152;                // SZ bf16 (residual stream)
    bf16*  P2b = Xb + SZ;                     // SZ bf16
    bf16*  Qb  = P2b + SZ;                    // SZ bf16
    // K/V live in d_out (exact 2*SZ bf16 fit); dead before store_kernel runs.
    bf16*  Kb  = (bf16*)d_out;
    bf16*  Vb  = Kb + SZ;
    bf16*  Hb  = Kb;                          // alias: FFN hidden spans Kb+Vb

    wt_conv<<<dim3(16, 16, 24), dim3(32, 32), 0, stream>>>(Wq, Wk, Wv, Wo, W1, W2, Wt);
    encode_kernel<<<dim3(128, 8, 8), dim3(32, 32), 0, stream>>>(ref, srcf, Xb, P2b);

    for (int L = 0; L < 4; ++L) {
        const bf16* WtL = Wt + (size_t)L * 524288;
        const bf16* Akv = (L & 1) ? P2b : Xb;
        gemm_qkv<<<dim3(6, 256), 256, 0, stream>>>(Xb, Akv, WtL,
                                                   bq + L * 256, bk + L * 256, bv + L * 256,
                                                   Qb, Kb, Vb);
        kv_prep_part<<<dim3(32, 64), 256, 0, stream>>>(Kb, Vb, Pkv, Pks);
        kv_reduce<<<dim3(64, 4), 64, 0, stream>>>(Pkv, Pks, KVb, Ksb);
        // attention + O-proj + residual + LN1 fused (R3 version)
        attn_oln<<<256, 512, 0, stream>>>(Qb, KVb, Ksb, WtL + 196608, bo + L * 256,
                                          Xb, g1 + L * 256, be1 + L * 256);
        // FFN1 (relu) -> Hb
        gemm_mfma<1><<<dim3(4, 256), 256, 0, stream>>>(Xb, WtL + 262144, b1 + L * 512, Hb, 512, 256);
        // FFN2 + residual + LN2 fused
        gemm_ln<<<256, 512, 0, stream>>>(Hb, WtL + 393216, b2 + L * 256, Xb,
                                         g2 + L * 256, be2 + L * 256, 512);
    }

    store_kernel<<<dim3(128, 8, 8), dim3(32, 32), 0, stream>>>(Xb, (float*)d_out);
}

// Round 6
// 745.528 us; speedup vs baseline: 1.0007x; 1.0007x over previous
//
#include <hip/hip_runtime.h>
#include <hip/hip_bf16.h>

typedef __bf16 bf16;
typedef __attribute__((ext_vector_type(8))) __bf16 bf16x8;
typedef __attribute__((ext_vector_type(4))) __bf16 bf16x4;
typedef __attribute__((ext_vector_type(4))) float f32x4;

__device__ __forceinline__ bf16 f2bf(float f) { return (bf16)f; }

// async global->LDS, 16B per lane. LDS dest must be uniform-base + lane*16.
__device__ __forceinline__ void async_cp16(const void* g, void* l) {
    __builtin_amdgcn_global_load_lds(
        (const __attribute__((address_space(1))) unsigned int*)g,
        (__attribute__((address_space(3))) unsigned int*)l, 16, 0, 0);
}

// ---------------------------------------------------------------------------
// Positional encoding value for channel c, token t (t = h*64 + w)
// ---------------------------------------------------------------------------
__device__ __forceinline__ float pe_val(int c, int t) {
    int h = t >> 6, w = t & 63;
    int i = c >> 2, j = c & 3;
    float div = expf(-0.14391156831212787f * (float)i);
    float arg = ((j < 2) ? (float)w : (float)h) * div;
    return (j & 1) ? cosf(arg) : sinf(arg);
}

// ---------------------------------------------------------------------------
// Encode: feat (4,256,4096) f32 -> Xb[b,t,c] bf16, P2b bf16 (PE added).
// ---------------------------------------------------------------------------
__global__ __launch_bounds__(1024) void encode_kernel(const float* __restrict__ ref,
                                                      const float* __restrict__ src,
                                                      bf16* __restrict__ Xb,
                                                      bf16* __restrict__ P2b) {
    __shared__ float tile[32][33];
    int n = blockIdx.z >> 1, sel = blockIdx.z & 1;
    const float* f = sel ? src : ref;
    int t = blockIdx.x * 32 + threadIdx.x;
    int c = blockIdx.y * 32 + threadIdx.y;
    float v = f[((size_t)n * 256 + c) * 4096 + t] + pe_val(c, t);
    tile[threadIdx.y][threadIdx.x] = v;
    __syncthreads();
    int tt = blockIdx.x * 32 + threadIdx.y;
    int cc = blockIdx.y * 32 + threadIdx.x;
    float o = tile[threadIdx.x][threadIdx.y];
    int bx = sel ? 4 + n : n;
    int bp = sel ? n : 4 + n;
    Xb [((size_t)bx * 4096 + tt) * 256 + cc] = f2bf(o);
    P2b[((size_t)bp * 4096 + tt) * 256 + cc] = f2bf(o);
}

// ---------------------------------------------------------------------------
// Weight transpose+convert: W[K,N] f32 -> Wt[N,K] bf16, all 24 mats, 1 launch
// ---------------------------------------------------------------------------
__global__ __launch_bounds__(1024) void wt_conv(const float* __restrict__ Wq, const float* __restrict__ Wk,
                                                const float* __restrict__ Wv, const float* __restrict__ Wo,
                                                const float* __restrict__ W1, const float* __restrict__ W2,
                                                bf16* __restrict__ Wt) {
    __shared__ float t[32][33];
    int z = blockIdx.z, L = z / 6, m = z - L * 6;
    const float* src; int K, N, doff;
    if      (m == 0) { src = Wq + L * 65536;  K = 256; N = 256; doff = 0; }
    else if (m == 1) { src = Wk + L * 65536;  K = 256; N = 256; doff = 65536; }
    else if (m == 2) { src = Wv + L * 65536;  K = 256; N = 256; doff = 131072; }
    else if (m == 3) { src = Wo + L * 65536;  K = 256; N = 256; doff = 196608; }
    else if (m == 4) { src = W1 + L * 131072; K = 256; N = 512; doff = 262144; }
    else             { src = W2 + L * 131072; K = 512; N = 256; doff = 393216; }
    int n0 = blockIdx.x * 32, k0 = blockIdx.y * 32;
    if (n0 >= N || k0 >= K) return;
    t[threadIdx.y][threadIdx.x] = src[(size_t)(k0 + threadIdx.y) * N + n0 + threadIdx.x];
    __syncthreads();
    bf16* dst = Wt + (size_t)L * 524288 + doff;
    dst[(size_t)(n0 + threadIdx.y) * K + k0 + threadIdx.x] = f2bf(t[threadIdx.x][threadIdx.y]);
}

// ---------------------------------------------------------------------------
// Fused QKV GEMM (R3 version, scalar-store epilogue).
// ---------------------------------------------------------------------------
__global__ __launch_bounds__(256) void gemm_qkv(const bf16* __restrict__ Aq,
                                                const bf16* __restrict__ Akv,
                                                const bf16* __restrict__ Wt,
                                                const float* __restrict__ bq,
                                                const float* __restrict__ bk,
                                                const float* __restrict__ bv,
                                                bf16* __restrict__ Q,
                                                bf16* __restrict__ Ko,
                                                bf16* __restrict__ V) {
    __shared__ bf16 Als[128 * 64];
    __shared__ bf16 Bls[128 * 64];
    int tid = threadIdx.x;
    int wave = tid >> 6, lane = tid & 63;
    int bm = blockIdx.y * 128, bn = blockIdx.x * 128;
    int wm = (wave >> 1) * 64, wn = (wave & 1) * 64;
    int l15 = lane & 15, g = lane >> 4;
    const int K = 256;

    int seg = bn >> 8, cloc = bn & 255;
    const bf16* A = seg == 0 ? Aq : Akv;
    const float* bias = seg == 0 ? bq : (seg == 1 ? bk : bv);
    bf16* Out = seg == 0 ? Q : (seg == 1 ? Ko : V);
    bool do_elu = seg < 2;

    f32x4 acc[4][4] = {};

    for (int k0 = 0; k0 < K; k0 += 64) {
#pragma unroll
        for (int r = 0; r < 4; ++r) {
            int Lc = r * 256 + tid;
            int row = Lc >> 3, cs = Lc & 7;
            int gc = cs ^ (row & 7);
            async_cp16(A  + (size_t)(bm + row) * K + k0 + gc * 8, &Als[Lc * 8]);
            async_cp16(Wt + (size_t)(bn + row) * K + k0 + gc * 8, &Bls[Lc * 8]);
        }
        __syncthreads();
#pragma unroll
        for (int ks = 0; ks < 2; ++ks) {
            bf16x8 af[4], bfr[4];
#pragma unroll
            for (int i = 0; i < 4; ++i) {
                int row = wm + i * 16 + l15;
                int c = ks * 4 + g;
                af[i] = *(bf16x8*)&Als[row * 64 + ((c ^ (row & 7)) * 8)];
            }
#pragma unroll
            for (int j = 0; j < 4; ++j) {
                int row = wn + j * 16 + l15;
                int c = ks * 4 + g;
                bfr[j] = *(bf16x8*)&Bls[row * 64 + ((c ^ (row & 7)) * 8)];
            }
#pragma unroll
            for (int i = 0; i < 4; ++i)
#pragma unroll
                for (int j = 0; j < 4; ++j)
                    acc[i][j] = __builtin_amdgcn_mfma_f32_16x16x32_bf16(af[i], bfr[j], acc[i][j], 0, 0, 0);
        }
        __syncthreads();
    }

    int r4 = (lane >> 4) * 4;
#pragma unroll
    for (int i = 0; i < 4; ++i) {
#pragma unroll
        for (int j = 0; j < 4; ++j) {
            int cj = cloc + wn + j * 16 + l15;
            float bvv = bias[cj];
#pragma unroll
            for (int r = 0; r < 4; ++r) {
                int row = bm + wm + i * 16 + r4 + r;
                float v = acc[i][j][r] + bvv;
                if (do_elu) v = v > 0.f ? v + 1.f : expf(v);
                Out[(size_t)row * 256 + cj] = f2bf(v);
            }
        }
    }
}

// ---------------------------------------------------------------------------
// MFMA GEMM (FFN1, R3 version, scalar-store epilogue).
// ---------------------------------------------------------------------------
template <int RELU>
__global__ __launch_bounds__(256) void gemm_mfma(const bf16* __restrict__ A,
                                                 const bf16* __restrict__ Wt,
                                                 const float* __restrict__ bias,
                                                 bf16* __restrict__ C,
                                                 int N, int K) {
    __shared__ bf16 Als[128 * 64];
    __shared__ bf16 Bls[128 * 64];
    int tid = threadIdx.x;
    int wave = tid >> 6, lane = tid & 63;
    int bm = blockIdx.y * 128, bn = blockIdx.x * 128;
    int wm = (wave >> 1) * 64, wn = (wave & 1) * 64;
    int l15 = lane & 15, g = lane >> 4;

    f32x4 acc[4][4] = {};

    for (int k0 = 0; k0 < K; k0 += 64) {
#pragma unroll
        for (int r = 0; r < 4; ++r) {
            int Lc = r * 256 + tid;
            int row = Lc >> 3, cs = Lc & 7;
            int gc = cs ^ (row & 7);
            async_cp16(A  + (size_t)(bm + row) * K + k0 + gc * 8, &Als[Lc * 8]);
            async_cp16(Wt + (size_t)(bn + row) * K + k0 + gc * 8, &Bls[Lc * 8]);
        }
        __syncthreads();
#pragma unroll
        for (int ks = 0; ks < 2; ++ks) {
            bf16x8 af[4], bfr[4];
#pragma unroll
            for (int i = 0; i < 4; ++i) {
                int row = wm + i * 16 + l15;
                int c = ks * 4 + g;
                af[i] = *(bf16x8*)&Als[row * 64 + ((c ^ (row & 7)) * 8)];
            }
#pragma unroll
            for (int j = 0; j < 4; ++j) {
                int row = wn + j * 16 + l15;
                int c = ks * 4 + g;
                bfr[j] = *(bf16x8*)&Bls[row * 64 + ((c ^ (row & 7)) * 8)];
            }
#pragma unroll
            for (int i = 0; i < 4; ++i)
#pragma unroll
                for (int j = 0; j < 4; ++j)
                    acc[i][j] = __builtin_amdgcn_mfma_f32_16x16x32_bf16(af[i], bfr[j], acc[i][j], 0, 0, 0);
        }
        __syncthreads();
    }

    int r4 = (lane >> 4) * 4;
#pragma unroll
    for (int i = 0; i < 4; ++i) {
#pragma unroll
        for (int j = 0; j < 4; ++j) {
            int col = bn + wn + j * 16 + l15;
            float bvv = bias[col];
#pragma unroll
            for (int r = 0; r < 4; ++r) {
                int row = bm + wm + i * 16 + r4 + r;
                float v = acc[i][j][r] + bvv;
                if (RELU) v = fmaxf(v, 0.f);
                C[(size_t)row * N + col] = f2bf(v);
            }
        }
    }
}

// ---------------------------------------------------------------------------
// Fused GEMM (N=256) + residual + LayerNorm epilogue (FFN2 path, R3 version)
// ---------------------------------------------------------------------------
__global__ __launch_bounds__(512) void gemm_ln(const bf16* __restrict__ A,
                                               const bf16* __restrict__ Wt,
                                               const float* __restrict__ bias,
                                               bf16* __restrict__ Xb,
                                               const float* __restrict__ g,
                                               const float* __restrict__ b,
                                               int K) {
    __shared__ __align__(16) char smem[128 * 260 * 2];  // 66560 B
    bf16* Als = (bf16*)smem;            // [128][64]  16 KB (during K loop)
    bf16* Bls = (bf16*)(smem + 16384);  // [256][64]  32 KB (during K loop)
    bf16* Cls = (bf16*)smem;            // [128][260] after K loop

    int tid = threadIdx.x;
    int wave = tid >> 6, lane = tid & 63;
    int bm = blockIdx.x * 128;
    int wm = (wave >> 2) * 64, wn = (wave & 3) * 64;
    int l15 = lane & 15, gg = lane >> 4;

    f32x4 acc[4][4] = {};

    for (int k0 = 0; k0 < K; k0 += 64) {
#pragma unroll
        for (int r = 0; r < 2; ++r) {   // A tile: 128x64
            int Lc = r * 512 + tid;
            int row = Lc >> 3, cs = Lc & 7;
            int gc = cs ^ (row & 7);
            async_cp16(A + (size_t)(bm + row) * K + k0 + gc * 8, &Als[Lc * 8]);
        }
#pragma unroll
        for (int r = 0; r < 4; ++r) {   // B tile: 256x64
            int Lc = r * 512 + tid;
            int row = Lc >> 3, cs = Lc & 7;
            int gc = cs ^ (row & 7);
            async_cp16(Wt + (size_t)row * K + k0 + gc * 8, &Bls[Lc * 8]);
        }
        __syncthreads();
#pragma unroll
        for (int ks = 0; ks < 2; ++ks) {
            bf16x8 af[4], bfr[4];
#pragma unroll
            for (int i = 0; i < 4; ++i) {
                int row = wm + i * 16 + l15;
                int c = ks * 4 + gg;
                af[i] = *(bf16x8*)&Als[row * 64 + ((c ^ (row & 7)) * 8)];
            }
#pragma unroll
            for (int j = 0; j < 4; ++j) {
                int row = wn + j * 16 + l15;
                int c = ks * 4 + gg;
                bfr[j] = *(bf16x8*)&Bls[row * 64 + ((c ^ (row & 7)) * 8)];
            }
#pragma unroll
            for (int i = 0; i < 4; ++i)
#pragma unroll
                for (int j = 0; j < 4; ++j)
                    acc[i][j] = __builtin_amdgcn_mfma_f32_16x16x32_bf16(af[i], bfr[j], acc[i][j], 0, 0, 0);
        }
        __syncthreads();
    }

    int r4 = (lane >> 4) * 4;
#pragma unroll
    for (int j = 0; j < 4; ++j) {
        int col = wn + j * 16 + l15;
        float bvv = bias[col];
#pragma unroll
        for (int i = 0; i < 4; ++i)
#pragma unroll
            for (int r = 0; r < 4; ++r)
                Cls[(wm + i * 16 + r4 + r) * 260 + col] = f2bf(acc[i][j][r] + bvv);
    }
    __syncthreads();

    int c4 = lane * 4;
    float4 gw = *(const float4*)&g[c4];
    float4 bw = *(const float4*)&b[c4];
#pragma unroll 2
    for (int rw = 0; rw < 16; ++rw) {
        int row = wave * 16 + rw;
        size_t gidx = (size_t)(bm + row) * 256 + c4;
        bf16x4 xb = *(const bf16x4*)(Xb + gidx);
        bf16x4 cb = *(const bf16x4*)&Cls[row * 260 + c4];
        float4 v;
        v.x = (float)xb[0] + (float)cb[0];
        v.y = (float)xb[1] + (float)cb[1];
        v.z = (float)xb[2] + (float)cb[2];
        v.w = (float)xb[3] + (float)cb[3];
        float s  = v.x + v.y + v.z + v.w;
        float sq = v.x * v.x + v.y * v.y + v.z * v.z + v.w * v.w;
#pragma unroll
        for (int off = 32; off > 0; off >>= 1) {
            s  += __shfl_xor(s,  off);
            sq += __shfl_xor(sq, off);
        }
        float mean = s * (1.f / 256.f);
        float var  = sq * (1.f / 256.f) - mean * mean;
        float rstd = rsqrtf(var + 1e-5f);
        bf16x4 ob;
        ob[0] = f2bf((v.x - mean) * rstd * gw.x + bw.x);
        ob[1] = f2bf((v.y - mean) * rstd * gw.y + bw.y);
        ob[2] = f2bf((v.z - mean) * rstd * gw.z + bw.z);
        ob[3] = f2bf((v.w - mean) * rstd * gw.w + bw.w);
        *(bf16x4*)(Xb + gidx) = ob;
    }
}

// ---------------------------------------------------------------------------
// Fused attention + O-proj + residual + LN1, v2: 64-token blocks, grid 512.
// Pool 49920 B -> 2 blocks/CU (was 133 KB -> 1). Wo read DIRECT from global
// (L2-resident, fragments are contiguous 16B in Wt[N][K]) - no phase-2
// staging or barriers. Math bit-identical to R3 version.
// ---------------------------------------------------------------------------
__global__ __launch_bounds__(512) void attn_oln(const bf16* __restrict__ Qb,
                                                const float* __restrict__ KV,
                                                const float* __restrict__ Ksum,
                                                const bf16* __restrict__ Wt,
                                                const float* __restrict__ bias,
                                                bf16* __restrict__ Xb,
                                                const float* __restrict__ g,
                                                const float* __restrict__ b) {
    // [0,16640): Qs f32[16][260] | phase-3 Cls bf16[64][260] (33280)
    // [16640,17152): Zs f32[16][8]
    // [17152,49920): Bt bf16 [4][64][64] swizzled
    __shared__ __align__(16) char smem[49920];
    float* Qs  = (float*)smem;
    float* Zs  = (float*)(smem + 16640);
    bf16*  Bt  = (bf16*)(smem + 17152);
    bf16*  Cls = (bf16*)smem;

    int tid = threadIdx.x;
    int r0 = blockIdx.x * 64;                // global row (= n*4096 + token)
    int n = r0 >> 12;

    // per-thread KV row (f32): col c -> head h, m
    int c = tid & 255, tg = tid >> 8;
    int h = c >> 5, m = c & 31;
    float kvr[32];
    const float* kvp = KV + (size_t)(n * 8 + h) * 1024 + m * 32;
#pragma unroll
    for (int q4 = 0; q4 < 8; ++q4) *(float4*)&kvr[q4 * 4] = *(const float4*)(kvp + q4 * 4);

    int col8 = (c >> 3) & 7, elem = c & 7, slice = c >> 6;

    for (int it = 0; it < 4; ++it) {
        int t0 = it * 16;
        const bf16* qsrc = Qb + (size_t)(r0 + t0) * 256;
        {
            int t = tid >> 5, c8 = tid & 31;
            bf16x8 v = *(const bf16x8*)(qsrc + (size_t)tid * 8);
#pragma unroll
            for (int u = 0; u < 8; ++u) Qs[t * 260 + c8 * 8 + u] = (float)v[u];
        }
        __syncthreads();
        if (tid < 128) {
            int tz = tid >> 3, hz = tid & 7;
            const float* ksp = Ksum + n * 256 + hz * 32;
            float z = 0.f;
#pragma unroll
            for (int q4 = 0; q4 < 8; ++q4) {
                float4 qv = *(float4*)&Qs[tz * 260 + hz * 32 + q4 * 4];
                float4 kq = *(const float4*)(ksp + q4 * 4);
                z += qv.x * kq.x + qv.y * kq.y + qv.z * kq.z + qv.w * kq.w;
            }
            Zs[tz * 8 + hz] = 1.f / (z + 1e-6f);
        }
        __syncthreads();
#pragma unroll 2
        for (int tt = 0; tt < 8; ++tt) {
            int t = tg * 8 + tt;
            float acc = 0.f;
#pragma unroll
            for (int q4 = 0; q4 < 8; ++q4) {
                float4 qv = *(float4*)&Qs[t * 260 + h * 32 + q4 * 4];
                acc += qv.x * kvr[q4 * 4 + 0] + qv.y * kvr[q4 * 4 + 1]
                     + qv.z * kvr[q4 * 4 + 2] + qv.w * kvr[q4 * 4 + 3];
            }
            int row = t0 + t;
            Bt[slice * 4096 + row * 64 + ((col8 ^ (row & 7)) * 8) + elem] =
                f2bf(acc * Zs[t * 8 + h]);
        }
        __syncthreads();
    }

    // Phase 2: C[64][256] = Bt @ Wo^T ; Wo fragments direct from global (L2).
    int wave = tid >> 6, lane = tid & 63;
    int wm = (wave >> 2) * 32, wn = (wave & 3) * 64;
    int l15 = lane & 15, gg = lane >> 4;
    f32x4 acc2[2][4] = {};

    for (int k0 = 0; k0 < 256; k0 += 64) {
        const bf16* Asl = Bt + (k0 >> 6) * 4096;
#pragma unroll
        for (int ks = 0; ks < 2; ++ks) {
            bf16x8 af[2], bfr[4];
#pragma unroll
            for (int i = 0; i < 2; ++i) {
                int row = wm + i * 16 + l15;
                int cc = ks * 4 + gg;
                af[i] = *(bf16x8*)&Asl[row * 64 + ((cc ^ (row & 7)) * 8)];
            }
#pragma unroll
            for (int j = 0; j < 4; ++j) {
                int row = wn + j * 16 + l15;
                bfr[j] = *(const bf16x8*)(Wt + (size_t)row * 256 + k0 + ks * 32 + gg * 8);
            }
#pragma unroll
            for (int i = 0; i < 2; ++i)
#pragma unroll
                for (int j = 0; j < 4; ++j)
                    acc2[i][j] = __builtin_amdgcn_mfma_f32_16x16x32_bf16(af[i], bfr[j], acc2[i][j], 0, 0, 0);
        }
    }
    __syncthreads();   // Bt/Qs dead; Cls reuses pool

    // Phase 3: C -> LDS, residual + LN into Xb
    int r4 = (lane >> 4) * 4;
#pragma unroll
    for (int j = 0; j < 4; ++j) {
        int col = wn + j * 16 + l15;
        float bvv = bias[col];
#pragma unroll
        for (int i = 0; i < 2; ++i)
#pragma unroll
            for (int r = 0; r < 4; ++r)
                Cls[(wm + i * 16 + r4 + r) * 260 + col] = f2bf(acc2[i][j][r] + bvv);
    }
    __syncthreads();

    int c4 = lane * 4;
    float4 gw = *(const float4*)&g[c4];
    float4 bw = *(const float4*)&b[c4];
#pragma unroll 2
    for (int rw = 0; rw < 8; ++rw) {
        int row = wave * 8 + rw;
        size_t gidx = (size_t)(r0 + row) * 256 + c4;
        bf16x4 xb = *(const bf16x4*)(Xb + gidx);
        bf16x4 cb = *(const bf16x4*)&Cls[row * 260 + c4];
        float4 v;
        v.x = (float)xb[0] + (float)cb[0];
        v.y = (float)xb[1] + (float)cb[1];
        v.z = (float)xb[2] + (float)cb[2];
        v.w = (float)xb[3] + (float)cb[3];
        float s  = v.x + v.y + v.z + v.w;
        float sq = v.x * v.x + v.y * v.y + v.z * v.z + v.w * v.w;
#pragma unroll
        for (int off = 32; off > 0; off >>= 1) {
            s  += __shfl_xor(s,  off);
            sq += __shfl_xor(sq, off);
        }
        float mean = s * (1.f / 256.f);
        float var  = sq * (1.f / 256.f) - mean * mean;
        float rstd = rsqrtf(var + 1e-5f);
        bf16x4 ob;
        ob[0] = f2bf((v.x - mean) * rstd * gw.x + bw.x);
        ob[1] = f2bf((v.y - mean) * rstd * gw.y + bw.y);
        ob[2] = f2bf((v.z - mean) * rstd * gw.z + bw.z);
        ob[3] = f2bf((v.w - mean) * rstd * gw.w + bw.w);
        *(bf16x4*)(Xb + gidx) = ob;
    }
}

// ---------------------------------------------------------------------------
// KV prep: grid (32 sp, 64 nh), 256 thr = 4 waves.
// ---------------------------------------------------------------------------
__global__ __launch_bounds__(256) void kv_prep_part(const bf16* __restrict__ Kb,
                                                    const bf16* __restrict__ Vb,
                                                    float* __restrict__ Pkv,
                                                    float* __restrict__ Pks) {
    __shared__ float Ks[128][32];
    __shared__ float Vs[128][32];
    int sp = blockIdx.x;
    int nh = blockIdx.y;
    int n = nh >> 3, h = nh & 7;
    int tid = threadIdx.x;
    int wave = tid >> 6, lane = tid & 63;
    int mg = lane >> 3;
    int dg = lane & 7;
    size_t base = ((size_t)n * 4096 + sp * 128) * 256 + h * 32;

#pragma unroll
    for (int p = 0; p < 2; ++p) {
        int r = p * 64 + (tid >> 2);
        int c = (tid & 3) * 8;
        bf16x8 k8 = *(const bf16x8*)(Kb + base + (size_t)r * 256 + c);
        bf16x8 v8 = *(const bf16x8*)(Vb + base + (size_t)r * 256 + c);
#pragma unroll
        for (int u = 0; u < 8; ++u) { Ks[r][c + u] = (float)k8[u]; Vs[r][c + u] = (float)v8[u]; }
    }
    __syncthreads();

    float acc[4][4] = {};
    float ks4[4] = {};
    int s0 = wave * 32;
    for (int s = s0; s < s0 + 32; ++s) {
        float4 kq = *(float4*)&Ks[s][dg * 4];
        float4 vq = *(float4*)&Vs[s][mg * 4];
        ks4[0] += kq.x; ks4[1] += kq.y; ks4[2] += kq.z; ks4[3] += kq.w;
        acc[0][0] += vq.x * kq.x; acc[0][1] += vq.x * kq.y; acc[0][2] += vq.x * kq.z; acc[0][3] += vq.x * kq.w;
        acc[1][0] += vq.y * kq.x; acc[1][1] += vq.y * kq.y; acc[1][2] += vq.y * kq.z; acc[1][3] += vq.y * kq.w;
        acc[2][0] += vq.z * kq.x; acc[2][1] += vq.z * kq.y; acc[2][2] += vq.z * kq.z; acc[2][3] += vq.z * kq.w;
        acc[3][0] += vq.w * kq.x; acc[3][1] += vq.w * kq.y; acc[3][2] += vq.w * kq.z; acc[3][3] += vq.w * kq.w;
    }
    __syncthreads();

    float* R  = &Ks[0][0];
    float* RS = &Vs[0][0];
#pragma unroll
    for (int mi = 0; mi < 4; ++mi)
#pragma unroll
        for (int dj = 0; dj < 4; ++dj)
            R[wave * 1024 + (mg * 4 + mi) * 32 + dg * 4 + dj] = acc[mi][dj];
    if (mg == 0)
#pragma unroll
        for (int dj = 0; dj < 4; ++dj) RS[wave * 32 + dg * 4 + dj] = ks4[dj];
    __syncthreads();

    int e = tid * 4;
    float4 o0 = *(float4*)&R[e];
    float4 o1 = *(float4*)&R[1024 + e];
    float4 o2 = *(float4*)&R[2048 + e];
    float4 o3 = *(float4*)&R[3072 + e];
    float4 o = make_float4(o0.x + o1.x + o2.x + o3.x, o0.y + o1.y + o2.y + o3.y,
                           o0.z + o1.z + o2.z + o3.z, o0.w + o1.w + o2.w + o3.w);
    *(float4*)&Pkv[((size_t)nh * 32 + sp) * 1024 + e] = o;
    if (tid < 32)
        Pks[((size_t)nh * 32 + sp) * 32 + tid] = RS[tid] + RS[32 + tid] + RS[64 + tid] + RS[96 + tid];
}

// grid (64 nh, 4 quarters), 64 threads (1 wave).
__global__ __launch_bounds__(64) void kv_reduce(const float* __restrict__ Pkv,
                                                const float* __restrict__ Pks,
                                                float* __restrict__ KV,
                                                float* __restrict__ Ksum) {
    int nh = blockIdx.x;
    int q = blockIdx.y;
    int e = (q * 64 + threadIdx.x) * 4;
    float4 s = make_float4(0.f, 0.f, 0.f, 0.f);
    for (int sp = 0; sp < 32; ++sp) {
        float4 p = *(const float4*)&Pkv[((size_t)nh * 32 + sp) * 1024 + e];
        s.x += p.x; s.y += p.y; s.z += p.z; s.w += p.w;
    }
    *(float4*)&KV[(size_t)nh * 1024 + e] = s;
    if (q == 0 && threadIdx.x < 32) {
        float ss = 0.f;
        for (int sp = 0; sp < 32; ++sp) ss += Pks[((size_t)nh * 32 + sp) * 32 + threadIdx.x];
        Ksum[nh * 32 + threadIdx.x] = ss;
    }
}

// ---------------------------------------------------------------------------
// Store: Xb[b,t,c] bf16 -> out[b,c,t] f32
// ---------------------------------------------------------------------------
__global__ __launch_bounds__(1024) void store_kernel(const bf16* __restrict__ Xb,
                                                     float* __restrict__ out) {
    __shared__ float tile[32][33];
    int b = blockIdx.z;
    int t0 = blockIdx.x * 32, c0 = blockIdx.y * 32;
    tile[threadIdx.y][threadIdx.x] =
        (float)Xb[((size_t)b * 4096 + t0 + threadIdx.y) * 256 + c0 + threadIdx.x];
    __syncthreads();
    out[((size_t)b * 256 + c0 + threadIdx.y) * 4096 + t0 + threadIdx.x] =
        tile[threadIdx.x][threadIdx.y];
}

// ---------------------------------------------------------------------------
extern "C" void kernel_launch(void* const* d_in, const int* in_sizes, int n_in,
                              void* d_out, int out_size, void* d_ws, size_t ws_size,
                              hipStream_t stream) {
    const float* ref  = (const float*)d_in[0];
    const float* srcf = (const float*)d_in[1];
    const float* Wq = (const float*)d_in[2];
    const float* bq = (const float*)d_in[3];
    const float* Wk = (const float*)d_in[4];
    const float* bk = (const float*)d_in[5];
    const float* Wv = (const float*)d_in[6];
    const float* bv = (const float*)d_in[7];
    const float* Wo = (const float*)d_in[8];
    const float* bo = (const float*)d_in[9];
    const float* W1 = (const float*)d_in[10];
    const float* b1 = (const float*)d_in[11];
    const float* W2 = (const float*)d_in[12];
    const float* b2 = (const float*)d_in[13];
    const float* g1 = (const float*)d_in[14];
    const float* be1 = (const float*)d_in[15];
    const float* g2 = (const float*)d_in[16];
    const float* be2 = (const float*)d_in[17];

    const size_t SZ = (size_t)8 * 4096 * 256;
    float* ws  = (float*)d_ws;
    float* KVb = ws;                          // 65536 f32
    float* Ksb = KVb + 65536;                 // 2048 f32
    float* Pkv = Ksb + 2048;                  // 2,097,152 f32
    float* Pks = Pkv + 2097152;               // 65536 f32
    bf16*  Wt  = (bf16*)(Pks + 65536);        // 2,097,152 bf16
    bf16*  Xb  = Wt + 2097152;                // SZ bf16 (residual stream)
    bf16*  P2b = Xb + SZ;                     // SZ bf16
    bf16*  Qb  = P2b + SZ;                    // SZ bf16
    // K/V live in d_out (exact 2*SZ bf16 fit); dead before store_kernel runs.
    bf16*  Kb  = (bf16*)d_out;
    bf16*  Vb  = Kb + SZ;
    bf16*  Hb  = Kb;                          // alias: FFN hidden spans Kb+Vb

    wt_conv<<<dim3(16, 16, 24), dim3(32, 32), 0, stream>>>(Wq, Wk, Wv, Wo, W1, W2, Wt);
    encode_kernel<<<dim3(128, 8, 8), dim3(32, 32), 0, stream>>>(ref, srcf, Xb, P2b);

    for (int L = 0; L < 4; ++L) {
        const bf16* WtL = Wt + (size_t)L * 524288;
        const bf16* Akv = (L & 1) ? P2b : Xb;
        gemm_qkv<<<dim3(6, 256), 256, 0, stream>>>(Xb, Akv, WtL,
                                                   bq + L * 256, bk + L * 256, bv + L * 256,
                                                   Qb, Kb, Vb);
        kv_prep_part<<<dim3(32, 64), 256, 0, stream>>>(Kb, Vb, Pkv, Pks);
        kv_reduce<<<dim3(64, 4), 64, 0, stream>>>(Pkv, Pks, KVb, Ksb);
        // attention + O-proj + residual + LN1 fused, v2 (64-token blocks)
        attn_oln<<<512, 512, 0, stream>>>(Qb, KVb, Ksb, WtL + 196608, bo + L * 256,
                                          Xb, g1 + L * 256, be1 + L * 256);
        // FFN1 (relu) -> Hb
        gemm_mfma<1><<<dim3(4, 256), 256, 0, stream>>>(Xb, WtL + 262144, b1 + L * 512, Hb, 512, 256);
        // FFN2 + residual + LN2 fused
        gemm_ln<<<256, 512, 0, stream>>>(Hb, WtL + 393216, b2 + L * 256, Xb,
                                         g2 + L * 256, be2 + L * 256, 512);
    }

    store_kernel<<<dim3(128, 8, 8), dim3(32, 32), 0, stream>>>(Xb, (float*)d_out);
}

// Round 7
// 683.625 us; speedup vs baseline: 1.0913x; 1.0906x over previous
//
#include <hip/hip_runtime.h>
#include <hip/hip_bf16.h>

typedef __bf16 bf16;
typedef __attribute__((ext_vector_type(8))) __bf16 bf16x8;
typedef __attribute__((ext_vector_type(4))) __bf16 bf16x4;
typedef __attribute__((ext_vector_type(4))) float f32x4;

__device__ __forceinline__ bf16 f2bf(float f) { return (bf16)f; }

// async global->LDS, 16B per lane. LDS dest must be uniform-base + lane*16.
__device__ __forceinline__ void async_cp16(const void* g, void* l) {
    __builtin_amdgcn_global_load_lds(
        (const __attribute__((address_space(1))) unsigned int*)g,
        (__attribute__((address_space(3))) unsigned int*)l, 16, 0, 0);
}

// ---------------------------------------------------------------------------
// Positional encoding value for channel c, token t (t = h*64 + w)
// ---------------------------------------------------------------------------
__device__ __forceinline__ float pe_val(int c, int t) {
    int h = t >> 6, w = t & 63;
    int i = c >> 2, j = c & 3;
    float div = expf(-0.14391156831212787f * (float)i);
    float arg = ((j < 2) ? (float)w : (float)h) * div;
    return (j & 1) ? cosf(arg) : sinf(arg);
}

// ---------------------------------------------------------------------------
// Encode: feat (4,256,4096) f32 -> Xb[b,t,c] bf16, P2b bf16 (PE added).
// ---------------------------------------------------------------------------
__global__ __launch_bounds__(1024) void encode_kernel(const float* __restrict__ ref,
                                                      const float* __restrict__ src,
                                                      bf16* __restrict__ Xb,
                                                      bf16* __restrict__ P2b) {
    __shared__ float tile[32][33];
    int n = blockIdx.z >> 1, sel = blockIdx.z & 1;
    const float* f = sel ? src : ref;
    int t = blockIdx.x * 32 + threadIdx.x;
    int c = blockIdx.y * 32 + threadIdx.y;
    float v = f[((size_t)n * 256 + c) * 4096 + t] + pe_val(c, t);
    tile[threadIdx.y][threadIdx.x] = v;
    __syncthreads();
    int tt = blockIdx.x * 32 + threadIdx.y;
    int cc = blockIdx.y * 32 + threadIdx.x;
    float o = tile[threadIdx.x][threadIdx.y];
    int bx = sel ? 4 + n : n;
    int bp = sel ? n : 4 + n;
    Xb [((size_t)bx * 4096 + tt) * 256 + cc] = f2bf(o);
    P2b[((size_t)bp * 4096 + tt) * 256 + cc] = f2bf(o);
}

// ---------------------------------------------------------------------------
// Weight transpose+convert: W[K,N] f32 -> Wt[N,K] bf16, all 24 mats, 1 launch
// ---------------------------------------------------------------------------
__global__ __launch_bounds__(1024) void wt_conv(const float* __restrict__ Wq, const float* __restrict__ Wk,
                                                const float* __restrict__ Wv, const float* __restrict__ Wo,
                                                const float* __restrict__ W1, const float* __restrict__ W2,
                                                bf16* __restrict__ Wt) {
    __shared__ float t[32][33];
    int z = blockIdx.z, L = z / 6, m = z - L * 6;
    const float* src; int K, N, doff;
    if      (m == 0) { src = Wq + L * 65536;  K = 256; N = 256; doff = 0; }
    else if (m == 1) { src = Wk + L * 65536;  K = 256; N = 256; doff = 65536; }
    else if (m == 2) { src = Wv + L * 65536;  K = 256; N = 256; doff = 131072; }
    else if (m == 3) { src = Wo + L * 65536;  K = 256; N = 256; doff = 196608; }
    else if (m == 4) { src = W1 + L * 131072; K = 256; N = 512; doff = 262144; }
    else             { src = W2 + L * 131072; K = 512; N = 256; doff = 393216; }
    int n0 = blockIdx.x * 32, k0 = blockIdx.y * 32;
    if (n0 >= N || k0 >= K) return;
    t[threadIdx.y][threadIdx.x] = src[(size_t)(k0 + threadIdx.y) * N + n0 + threadIdx.x];
    __syncthreads();
    bf16* dst = Wt + (size_t)L * 524288 + doff;
    dst[(size_t)(n0 + threadIdx.y) * K + k0 + threadIdx.x] = f2bf(t[threadIdx.x][threadIdx.y]);
}

// ---------------------------------------------------------------------------
// Fused QKV GEMM (R3 version, scalar-store epilogue).
// ---------------------------------------------------------------------------
__global__ __launch_bounds__(256) void gemm_qkv(const bf16* __restrict__ Aq,
                                                const bf16* __restrict__ Akv,
                                                const bf16* __restrict__ Wt,
                                                const float* __restrict__ bq,
                                                const float* __restrict__ bk,
                                                const float* __restrict__ bv,
                                                bf16* __restrict__ Q,
                                                bf16* __restrict__ Ko,
                                                bf16* __restrict__ V) {
    __shared__ bf16 Als[128 * 64];
    __shared__ bf16 Bls[128 * 64];
    int tid = threadIdx.x;
    int wave = tid >> 6, lane = tid & 63;
    int bm = blockIdx.y * 128, bn = blockIdx.x * 128;
    int wm = (wave >> 1) * 64, wn = (wave & 1) * 64;
    int l15 = lane & 15, g = lane >> 4;
    const int K = 256;

    int seg = bn >> 8, cloc = bn & 255;
    const bf16* A = seg == 0 ? Aq : Akv;
    const float* bias = seg == 0 ? bq : (seg == 1 ? bk : bv);
    bf16* Out = seg == 0 ? Q : (seg == 1 ? Ko : V);
    bool do_elu = seg < 2;

    f32x4 acc[4][4] = {};

    for (int k0 = 0; k0 < K; k0 += 64) {
#pragma unroll
        for (int r = 0; r < 4; ++r) {
            int Lc = r * 256 + tid;
            int row = Lc >> 3, cs = Lc & 7;
            int gc = cs ^ (row & 7);
            async_cp16(A  + (size_t)(bm + row) * K + k0 + gc * 8, &Als[Lc * 8]);
            async_cp16(Wt + (size_t)(bn + row) * K + k0 + gc * 8, &Bls[Lc * 8]);
        }
        __syncthreads();
#pragma unroll
        for (int ks = 0; ks < 2; ++ks) {
            bf16x8 af[4], bfr[4];
#pragma unroll
            for (int i = 0; i < 4; ++i) {
                int row = wm + i * 16 + l15;
                int c = ks * 4 + g;
                af[i] = *(bf16x8*)&Als[row * 64 + ((c ^ (row & 7)) * 8)];
            }
#pragma unroll
            for (int j = 0; j < 4; ++j) {
                int row = wn + j * 16 + l15;
                int c = ks * 4 + g;
                bfr[j] = *(bf16x8*)&Bls[row * 64 + ((c ^ (row & 7)) * 8)];
            }
#pragma unroll
            for (int i = 0; i < 4; ++i)
#pragma unroll
                for (int j = 0; j < 4; ++j)
                    acc[i][j] = __builtin_amdgcn_mfma_f32_16x16x32_bf16(af[i], bfr[j], acc[i][j], 0, 0, 0);
        }
        __syncthreads();
    }

    int r4 = (lane >> 4) * 4;
#pragma unroll
    for (int i = 0; i < 4; ++i) {
#pragma unroll
        for (int j = 0; j < 4; ++j) {
            int cj = cloc + wn + j * 16 + l15;
            float bvv = bias[cj];
#pragma unroll
            for (int r = 0; r < 4; ++r) {
                int row = bm + wm + i * 16 + r4 + r;
                float v = acc[i][j][r] + bvv;
                if (do_elu) v = v > 0.f ? v + 1.f : expf(v);
                Out[(size_t)row * 256 + cj] = f2bf(v);
            }
        }
    }
}

// ---------------------------------------------------------------------------
// MFMA GEMM (FFN1, R3 version, scalar-store epilogue).
// ---------------------------------------------------------------------------
template <int RELU>
__global__ __launch_bounds__(256) void gemm_mfma(const bf16* __restrict__ A,
                                                 const bf16* __restrict__ Wt,
                                                 const float* __restrict__ bias,
                                                 bf16* __restrict__ C,
                                                 int N, int K) {
    __shared__ bf16 Als[128 * 64];
    __shared__ bf16 Bls[128 * 64];
    int tid = threadIdx.x;
    int wave = tid >> 6, lane = tid & 63;
    int bm = blockIdx.y * 128, bn = blockIdx.x * 128;
    int wm = (wave >> 1) * 64, wn = (wave & 1) * 64;
    int l15 = lane & 15, g = lane >> 4;

    f32x4 acc[4][4] = {};

    for (int k0 = 0; k0 < K; k0 += 64) {
#pragma unroll
        for (int r = 0; r < 4; ++r) {
            int Lc = r * 256 + tid;
            int row = Lc >> 3, cs = Lc & 7;
            int gc = cs ^ (row & 7);
            async_cp16(A  + (size_t)(bm + row) * K + k0 + gc * 8, &Als[Lc * 8]);
            async_cp16(Wt + (size_t)(bn + row) * K + k0 + gc * 8, &Bls[Lc * 8]);
        }
        __syncthreads();
#pragma unroll
        for (int ks = 0; ks < 2; ++ks) {
            bf16x8 af[4], bfr[4];
#pragma unroll
            for (int i = 0; i < 4; ++i) {
                int row = wm + i * 16 + l15;
                int c = ks * 4 + g;
                af[i] = *(bf16x8*)&Als[row * 64 + ((c ^ (row & 7)) * 8)];
            }
#pragma unroll
            for (int j = 0; j < 4; ++j) {
                int row = wn + j * 16 + l15;
                int c = ks * 4 + g;
                bfr[j] = *(bf16x8*)&Bls[row * 64 + ((c ^ (row & 7)) * 8)];
            }
#pragma unroll
            for (int i = 0; i < 4; ++i)
#pragma unroll
                for (int j = 0; j < 4; ++j)
                    acc[i][j] = __builtin_amdgcn_mfma_f32_16x16x32_bf16(af[i], bfr[j], acc[i][j], 0, 0, 0);
        }
        __syncthreads();
    }

    int r4 = (lane >> 4) * 4;
#pragma unroll
    for (int i = 0; i < 4; ++i) {
#pragma unroll
        for (int j = 0; j < 4; ++j) {
            int col = bn + wn + j * 16 + l15;
            float bvv = bias[col];
#pragma unroll
            for (int r = 0; r < 4; ++r) {
                int row = bm + wm + i * 16 + r4 + r;
                float v = acc[i][j][r] + bvv;
                if (RELU) v = fmaxf(v, 0.f);
                C[(size_t)row * N + col] = f2bf(v);
            }
        }
    }
}

// ---------------------------------------------------------------------------
// Fused GEMM (N=256) + residual + LayerNorm epilogue (FFN2 path, R3 version)
// ---------------------------------------------------------------------------
__global__ __launch_bounds__(512) void gemm_ln(const bf16* __restrict__ A,
                                               const bf16* __restrict__ Wt,
                                               const float* __restrict__ bias,
                                               bf16* __restrict__ Xb,
                                               const float* __restrict__ g,
                                               const float* __restrict__ b,
                                               int K) {
    __shared__ __align__(16) char smem[128 * 260 * 2];  // 66560 B
    bf16* Als = (bf16*)smem;            // [128][64]  16 KB (during K loop)
    bf16* Bls = (bf16*)(smem + 16384);  // [256][64]  32 KB (during K loop)
    bf16* Cls = (bf16*)smem;            // [128][260] after K loop

    int tid = threadIdx.x;
    int wave = tid >> 6, lane = tid & 63;
    int bm = blockIdx.x * 128;
    int wm = (wave >> 2) * 64, wn = (wave & 3) * 64;
    int l15 = lane & 15, gg = lane >> 4;

    f32x4 acc[4][4] = {};

    for (int k0 = 0; k0 < K; k0 += 64) {
#pragma unroll
        for (int r = 0; r < 2; ++r) {   // A tile: 128x64
            int Lc = r * 512 + tid;
            int row = Lc >> 3, cs = Lc & 7;
            int gc = cs ^ (row & 7);
            async_cp16(A + (size_t)(bm + row) * K + k0 + gc * 8, &Als[Lc * 8]);
        }
#pragma unroll
        for (int r = 0; r < 4; ++r) {   // B tile: 256x64
            int Lc = r * 512 + tid;
            int row = Lc >> 3, cs = Lc & 7;
            int gc = cs ^ (row & 7);
            async_cp16(Wt + (size_t)row * K + k0 + gc * 8, &Bls[Lc * 8]);
        }
        __syncthreads();
#pragma unroll
        for (int ks = 0; ks < 2; ++ks) {
            bf16x8 af[4], bfr[4];
#pragma unroll
            for (int i = 0; i < 4; ++i) {
                int row = wm + i * 16 + l15;
                int c = ks * 4 + gg;
                af[i] = *(bf16x8*)&Als[row * 64 + ((c ^ (row & 7)) * 8)];
            }
#pragma unroll
            for (int j = 0; j < 4; ++j) {
                int row = wn + j * 16 + l15;
                int c = ks * 4 + gg;
                bfr[j] = *(bf16x8*)&Bls[row * 64 + ((c ^ (row & 7)) * 8)];
            }
#pragma unroll
            for (int i = 0; i < 4; ++i)
#pragma unroll
                for (int j = 0; j < 4; ++j)
                    acc[i][j] = __builtin_amdgcn_mfma_f32_16x16x32_bf16(af[i], bfr[j], acc[i][j], 0, 0, 0);
        }
        __syncthreads();
    }

    int r4 = (lane >> 4) * 4;
#pragma unroll
    for (int j = 0; j < 4; ++j) {
        int col = wn + j * 16 + l15;
        float bvv = bias[col];
#pragma unroll
        for (int i = 0; i < 4; ++i)
#pragma unroll
            for (int r = 0; r < 4; ++r)
                Cls[(wm + i * 16 + r4 + r) * 260 + col] = f2bf(acc[i][j][r] + bvv);
    }
    __syncthreads();

    int c4 = lane * 4;
    float4 gw = *(const float4*)&g[c4];
    float4 bw = *(const float4*)&b[c4];
#pragma unroll 2
    for (int rw = 0; rw < 16; ++rw) {
        int row = wave * 16 + rw;
        size_t gidx = (size_t)(bm + row) * 256 + c4;
        bf16x4 xb = *(const bf16x4*)(Xb + gidx);
        bf16x4 cb = *(const bf16x4*)&Cls[row * 260 + c4];
        float4 v;
        v.x = (float)xb[0] + (float)cb[0];
        v.y = (float)xb[1] + (float)cb[1];
        v.z = (float)xb[2] + (float)cb[2];
        v.w = (float)xb[3] + (float)cb[3];
        float s  = v.x + v.y + v.z + v.w;
        float sq = v.x * v.x + v.y * v.y + v.z * v.z + v.w * v.w;
#pragma unroll
        for (int off = 32; off > 0; off >>= 1) {
            s  += __shfl_xor(s,  off);
            sq += __shfl_xor(sq, off);
        }
        float mean = s * (1.f / 256.f);
        float var  = sq * (1.f / 256.f) - mean * mean;
        float rstd = rsqrtf(var + 1e-5f);
        bf16x4 ob;
        ob[0] = f2bf((v.x - mean) * rstd * gw.x + bw.x);
        ob[1] = f2bf((v.y - mean) * rstd * gw.y + bw.y);
        ob[2] = f2bf((v.z - mean) * rstd * gw.z + bw.z);
        ob[3] = f2bf((v.w - mean) * rstd * gw.w + bw.w);
        *(bf16x4*)(Xb + gidx) = ob;
    }
}

// ---------------------------------------------------------------------------
// Attention as a GEMM: Xb = LN(Xb + (Z.Q) @ Weff[n]^T + bo).
// Same structure as gemm_ln (tile 128x256, 512 thr, K=256), but:
//  - B operand = per-batch Weff (Wt layout [256][256] per n)
//  - A staging is reg-staged with on-the-fly Z scale: each 16B Q-chunk lies
//    within one head (8 | 32), scaled by Zt[row][head], rounded to bf16.
// Math identical to R4's zscale+gemm_lnW path (verified, absmax 0.0390625).
// ---------------------------------------------------------------------------
__global__ __launch_bounds__(512) void gemm_attn_ln(const bf16* __restrict__ A,
                                                    const float* __restrict__ Zt,
                                                    const bf16* __restrict__ Weff,
                                                    const float* __restrict__ bias,
                                                    bf16* __restrict__ Xb,
                                                    const float* __restrict__ g,
                                                    const float* __restrict__ b) {
    __shared__ __align__(16) char smem[128 * 260 * 2];  // 66560 B
    bf16* Als = (bf16*)smem;            // [128][64]
    bf16* Bls = (bf16*)(smem + 16384);  // [256][64]
    bf16* Cls = (bf16*)smem;            // [128][260] after K loop

    int tid = threadIdx.x;
    int wave = tid >> 6, lane = tid & 63;
    int bm = blockIdx.x * 128;
    const bf16* Wt = Weff + (size_t)(bm >> 12) * 65536;   // per-batch
    int wm = (wave >> 2) * 64, wn = (wave & 3) * 64;
    int l15 = lane & 15, gg = lane >> 4;

    f32x4 acc[4][4] = {};

    for (int k0 = 0; k0 < 256; k0 += 64) {
#pragma unroll
        for (int r = 0; r < 4; ++r) {   // B tile: 256x64 (async, overlaps A work)
            int Lc = r * 512 + tid;
            int row = Lc >> 3, cs = Lc & 7;
            int gc = cs ^ (row & 7);
            async_cp16(Wt + (size_t)row * 256 + k0 + gc * 8, &Bls[Lc * 8]);
        }
#pragma unroll
        for (int r = 0; r < 2; ++r) {   // A tile: 128x64, reg-staged with Z scale
            int Lc = r * 512 + tid;
            int row = Lc >> 3, cs = Lc & 7;
            int gc = cs ^ (row & 7);
            int gcol = k0 + gc * 8;
            bf16x8 q8 = *(const bf16x8*)(A + (size_t)(bm + row) * 256 + gcol);
            float z = Zt[(size_t)(bm + row) * 8 + (gcol >> 5)];
            bf16x8 a8;
#pragma unroll
            for (int u = 0; u < 8; ++u) a8[u] = f2bf((float)q8[u] * z);
            *(bf16x8*)&Als[Lc * 8] = a8;
        }
        __syncthreads();
#pragma unroll
        for (int ks = 0; ks < 2; ++ks) {
            bf16x8 af[4], bfr[4];
#pragma unroll
            for (int i = 0; i < 4; ++i) {
                int row = wm + i * 16 + l15;
                int c = ks * 4 + gg;
                af[i] = *(bf16x8*)&Als[row * 64 + ((c ^ (row & 7)) * 8)];
            }
#pragma unroll
            for (int j = 0; j < 4; ++j) {
                int row = wn + j * 16 + l15;
                int c = ks * 4 + gg;
                bfr[j] = *(bf16x8*)&Bls[row * 64 + ((c ^ (row & 7)) * 8)];
            }
#pragma unroll
            for (int i = 0; i < 4; ++i)
#pragma unroll
                for (int j = 0; j < 4; ++j)
                    acc[i][j] = __builtin_amdgcn_mfma_f32_16x16x32_bf16(af[i], bfr[j], acc[i][j], 0, 0, 0);
        }
        __syncthreads();
    }

    int r4 = (lane >> 4) * 4;
#pragma unroll
    for (int j = 0; j < 4; ++j) {
        int col = wn + j * 16 + l15;
        float bvv = bias[col];
#pragma unroll
        for (int i = 0; i < 4; ++i)
#pragma unroll
            for (int r = 0; r < 4; ++r)
                Cls[(wm + i * 16 + r4 + r) * 260 + col] = f2bf(acc[i][j][r] + bvv);
    }
    __syncthreads();

    int c4 = lane * 4;
    float4 gw = *(const float4*)&g[c4];
    float4 bw = *(const float4*)&b[c4];
#pragma unroll 2
    for (int rw = 0; rw < 16; ++rw) {
        int row = wave * 16 + rw;
        size_t gidx = (size_t)(bm + row) * 256 + c4;
        bf16x4 xb = *(const bf16x4*)(Xb + gidx);
        bf16x4 cb = *(const bf16x4*)&Cls[row * 260 + c4];
        float4 v;
        v.x = (float)xb[0] + (float)cb[0];
        v.y = (float)xb[1] + (float)cb[1];
        v.z = (float)xb[2] + (float)cb[2];
        v.w = (float)xb[3] + (float)cb[3];
        float s  = v.x + v.y + v.z + v.w;
        float sq = v.x * v.x + v.y * v.y + v.z * v.z + v.w * v.w;
#pragma unroll
        for (int off = 32; off > 0; off >>= 1) {
            s  += __shfl_xor(s,  off);
            sq += __shfl_xor(sq, off);
        }
        float mean = s * (1.f / 256.f);
        float var  = sq * (1.f / 256.f) - mean * mean;
        float rstd = rsqrtf(var + 1e-5f);
        bf16x4 ob;
        ob[0] = f2bf((v.x - mean) * rstd * gw.x + bw.x);
        ob[1] = f2bf((v.y - mean) * rstd * gw.y + bw.y);
        ob[2] = f2bf((v.z - mean) * rstd * gw.z + bw.z);
        ob[3] = f2bf((v.w - mean) * rstd * gw.w + bw.w);
        *(bf16x4*)(Xb + gidx) = ob;
    }
}

// ---------------------------------------------------------------------------
// KV prep: grid (32 sp, 64 nh), 256 thr = 4 waves.
// ---------------------------------------------------------------------------
__global__ __launch_bounds__(256) void kv_prep_part(const bf16* __restrict__ Kb,
                                                    const bf16* __restrict__ Vb,
                                                    float* __restrict__ Pkv,
                                                    float* __restrict__ Pks) {
    __shared__ float Ks[128][32];
    __shared__ float Vs[128][32];
    int sp = blockIdx.x;
    int nh = blockIdx.y;
    int n = nh >> 3, h = nh & 7;
    int tid = threadIdx.x;
    int wave = tid >> 6, lane = tid & 63;
    int mg = lane >> 3;
    int dg = lane & 7;
    size_t base = ((size_t)n * 4096 + sp * 128) * 256 + h * 32;

#pragma unroll
    for (int p = 0; p < 2; ++p) {
        int r = p * 64 + (tid >> 2);
        int c = (tid & 3) * 8;
        bf16x8 k8 = *(const bf16x8*)(Kb + base + (size_t)r * 256 + c);
        bf16x8 v8 = *(const bf16x8*)(Vb + base + (size_t)r * 256 + c);
#pragma unroll
        for (int u = 0; u < 8; ++u) { Ks[r][c + u] = (float)k8[u]; Vs[r][c + u] = (float)v8[u]; }
    }
    __syncthreads();

    float acc[4][4] = {};
    float ks4[4] = {};
    int s0 = wave * 32;
    for (int s = s0; s < s0 + 32; ++s) {
        float4 kq = *(float4*)&Ks[s][dg * 4];
        float4 vq = *(float4*)&Vs[s][mg * 4];
        ks4[0] += kq.x; ks4[1] += kq.y; ks4[2] += kq.z; ks4[3] += kq.w;
        acc[0][0] += vq.x * kq.x; acc[0][1] += vq.x * kq.y; acc[0][2] += vq.x * kq.z; acc[0][3] += vq.x * kq.w;
        acc[1][0] += vq.y * kq.x; acc[1][1] += vq.y * kq.y; acc[1][2] += vq.y * kq.z; acc[1][3] += vq.y * kq.w;
        acc[2][0] += vq.z * kq.x; acc[2][1] += vq.z * kq.y; acc[2][2] += vq.z * kq.z; acc[2][3] += vq.z * kq.w;
        acc[3][0] += vq.w * kq.x; acc[3][1] += vq.w * kq.y; acc[3][2] += vq.w * kq.z; acc[3][3] += vq.w * kq.w;
    }
    __syncthreads();

    float* R  = &Ks[0][0];
    float* RS = &Vs[0][0];
#pragma unroll
    for (int mi = 0; mi < 4; ++mi)
#pragma unroll
        for (int dj = 0; dj < 4; ++dj)
            R[wave * 1024 + (mg * 4 + mi) * 32 + dg * 4 + dj] = acc[mi][dj];
    if (mg == 0)
#pragma unroll
        for (int dj = 0; dj < 4; ++dj) RS[wave * 32 + dg * 4 + dj] = ks4[dj];
    __syncthreads();

    int e = tid * 4;
    float4 o0 = *(float4*)&R[e];
    float4 o1 = *(float4*)&R[1024 + e];
    float4 o2 = *(float4*)&R[2048 + e];
    float4 o3 = *(float4*)&R[3072 + e];
    float4 o = make_float4(o0.x + o1.x + o2.x + o3.x, o0.y + o1.y + o2.y + o3.y,
                           o0.z + o1.z + o2.z + o3.z, o0.w + o1.w + o2.w + o3.w);
    *(float4*)&Pkv[((size_t)nh * 32 + sp) * 1024 + e] = o;
    if (tid < 32)
        Pks[((size_t)nh * 32 + sp) * 32 + tid] = RS[tid] + RS[32 + tid] + RS[64 + tid] + RS[96 + tid];
}

// grid (64 nh, 4 quarters), 64 threads (1 wave).
__global__ __launch_bounds__(64) void kv_reduce(const float* __restrict__ Pkv,
                                                const float* __restrict__ Pks,
                                                float* __restrict__ KV,
                                                float* __restrict__ Ksum) {
    int nh = blockIdx.x;
    int q = blockIdx.y;
    int e = (q * 64 + threadIdx.x) * 4;
    float4 s = make_float4(0.f, 0.f, 0.f, 0.f);
    for (int sp = 0; sp < 32; ++sp) {
        float4 p = *(const float4*)&Pkv[((size_t)nh * 32 + sp) * 1024 + e];
        s.x += p.x; s.y += p.y; s.z += p.z; s.w += p.w;
    }
    *(float4*)&KV[(size_t)nh * 1024 + e] = s;
    if (q == 0 && threadIdx.x < 32) {
        float ss = 0.f;
        for (int sp = 0; sp < 32; ++sp) ss += Pks[((size_t)nh * 32 + sp) * 32 + threadIdx.x];
        Ksum[nh * 32 + threadIdx.x] = ss;
    }
}

// ---------------------------------------------------------------------------
// Weff[n][c][h*32+d] = sum_m KV[n,h,m,d] * Wo[(h,m),c]   (bf16, Wt layout)
// grid (4 ctiles of 64, 8 n), 256 thr. (R4 component, verified)
// ---------------------------------------------------------------------------
__global__ __launch_bounds__(256) void weff_kernel(const float* __restrict__ KV,
                                                   const bf16* __restrict__ WtO,
                                                   bf16* __restrict__ Weff) {
    __shared__ float KVs[8][1024];   // [h][m*32+d]
    int n = blockIdx.y, c0 = blockIdx.x * 64;
    int tid = threadIdx.x;
    const float* src = KV + (size_t)n * 8192;
    for (int i = tid; i < 2048; i += 256)
        *(float4*)&((float*)KVs)[i * 4] = *(const float4*)&src[i * 4];
    __syncthreads();

    int c = c0 + (tid & 63);
    int hb = tid >> 6;               // wave id: h in {2hb, 2hb+1}
    const bf16* wrow = WtO + (size_t)c * 256 + hb * 64;
    bf16* dst = Weff + (size_t)n * 65536 + (size_t)c * 256 + hb * 64;

#pragma unroll
    for (int hh = 0; hh < 2; ++hh) {
        int h = hb * 2 + hh;
        float wo[32];
#pragma unroll
        for (int u = 0; u < 4; ++u) {
            bf16x8 w8 = *(const bf16x8*)(wrow + hh * 32 + u * 8);
#pragma unroll
            for (int v = 0; v < 8; ++v) wo[u * 8 + v] = (float)w8[v];
        }
        float s[32] = {};
        for (int m = 0; m < 32; ++m) {
            float wm = wo[m];
#pragma unroll
            for (int d4 = 0; d4 < 8; ++d4) {
                float4 kv4 = *(float4*)&KVs[h][m * 32 + d4 * 4];
                s[d4 * 4 + 0] += wm * kv4.x;
                s[d4 * 4 + 1] += wm * kv4.y;
                s[d4 * 4 + 2] += wm * kv4.z;
                s[d4 * 4 + 3] += wm * kv4.w;
            }
        }
#pragma unroll
        for (int u = 0; u < 4; ++u) {
            bf16x8 o8;
#pragma unroll
            for (int v = 0; v < 8; ++v) o8[v] = f2bf(s[u * 8 + v]);
            *(bf16x8*)(dst + hh * 32 + u * 8) = o8;
        }
    }
}

// ---------------------------------------------------------------------------
// zcalc: Zt[row][h] = 1/(dot(Q[row,h,:], Ksum[n,h,:]) + eps). 4 rows/block.
// Reads Qb once (no RMW); 1 MB output.
// ---------------------------------------------------------------------------
__global__ __launch_bounds__(256) void zcalc(const bf16* __restrict__ Qb,
                                             const float* __restrict__ Ksum,
                                             float* __restrict__ Zt) {
    int row = blockIdx.x * 4 + (threadIdx.x >> 6);
    int lane = threadIdx.x & 63;
    int n = row >> 12;
    int c = lane * 4;
    bf16x4 q = *(const bf16x4*)(Qb + (size_t)row * 256 + c);
    float4 k = *(const float4*)&Ksum[n * 256 + c];
    float s = (float)q[0] * k.x + (float)q[1] * k.y + (float)q[2] * k.z + (float)q[3] * k.w;
    s += __shfl_xor(s, 1); s += __shfl_xor(s, 2); s += __shfl_xor(s, 4);
    if ((lane & 7) == 0)
        Zt[(size_t)row * 8 + (lane >> 3)] = 1.f / (s + 1e-6f);
}

// ---------------------------------------------------------------------------
// Store: Xb[b,t,c] bf16 -> out[b,c,t] f32
// ---------------------------------------------------------------------------
__global__ __launch_bounds__(1024) void store_kernel(const bf16* __restrict__ Xb,
                                                     float* __restrict__ out) {
    __shared__ float tile[32][33];
    int b = blockIdx.z;
    int t0 = blockIdx.x * 32, c0 = blockIdx.y * 32;
    tile[threadIdx.y][threadIdx.x] =
        (float)Xb[((size_t)b * 4096 + t0 + threadIdx.y) * 256 + c0 + threadIdx.x];
    __syncthreads();
    out[((size_t)b * 256 + c0 + threadIdx.y) * 4096 + t0 + threadIdx.x] =
        tile[threadIdx.x][threadIdx.y];
}

// ---------------------------------------------------------------------------
extern "C" void kernel_launch(void* const* d_in, const int* in_sizes, int n_in,
                              void* d_out, int out_size, void* d_ws, size_t ws_size,
                              hipStream_t stream) {
    const float* ref  = (const float*)d_in[0];
    const float* srcf = (const float*)d_in[1];
    const float* Wq = (const float*)d_in[2];
    const float* bq = (const float*)d_in[3];
    const float* Wk = (const float*)d_in[4];
    const float* bk = (const float*)d_in[5];
    const float* Wv = (const float*)d_in[6];
    const float* bv = (const float*)d_in[7];
    const float* Wo = (const float*)d_in[8];
    const float* bo = (const float*)d_in[9];
    const float* W1 = (const float*)d_in[10];
    const float* b1 = (const float*)d_in[11];
    const float* W2 = (const float*)d_in[12];
    const float* b2 = (const float*)d_in[13];
    const float* g1 = (const float*)d_in[14];
    const float* be1 = (const float*)d_in[15];
    const float* g2 = (const float*)d_in[16];
    const float* be2 = (const float*)d_in[17];

    const size_t SZ = (size_t)8 * 4096 * 256;
    float* ws  = (float*)d_ws;
    float* KVb = ws;                          // 65536 f32
    float* Ksb = KVb + 65536;                 // 2048 f32
    float* Pkv = Ksb + 2048;                  // 2,097,152 f32
    float* Pks = Pkv + 2097152;               // 65536 f32
    bf16*  Wt  = (bf16*)(Pks + 65536);        // 2,097,152 bf16
    bf16*  Xb  = Wt + 2097152;                // SZ bf16 (residual stream)
    bf16*  P2b = Xb + SZ;                     // SZ bf16
    bf16*  Qb  = P2b + SZ;                    // SZ bf16
    // Weff (1 MB bf16) + Zt (1 MB f32) alias the Pkv head: both written after
    // kv_reduce has consumed Pkv, consumed before next layer's kv_prep rewrite.
    bf16*  Weffb = (bf16*)Pkv;                // 524288 bf16 = 1 MB
    float* Ztb   = Pkv + 262144;              // 262144 f32  = 1 MB
    // K/V live in d_out (exact 2*SZ bf16 fit); dead before store_kernel runs.
    bf16*  Kb  = (bf16*)d_out;
    bf16*  Vb  = Kb + SZ;
    bf16*  Hb  = Kb;                          // alias: FFN hidden spans Kb+Vb

    wt_conv<<<dim3(16, 16, 24), dim3(32, 32), 0, stream>>>(Wq, Wk, Wv, Wo, W1, W2, Wt);
    encode_kernel<<<dim3(128, 8, 8), dim3(32, 32), 0, stream>>>(ref, srcf, Xb, P2b);

    for (int L = 0; L < 4; ++L) {
        const bf16* WtL = Wt + (size_t)L * 524288;
        const bf16* Akv = (L & 1) ? P2b : Xb;
        gemm_qkv<<<dim3(6, 256), 256, 0, stream>>>(Xb, Akv, WtL,
                                                   bq + L * 256, bk + L * 256, bv + L * 256,
                                                   Qb, Kb, Vb);
        kv_prep_part<<<dim3(32, 64), 256, 0, stream>>>(Kb, Vb, Pkv, Pks);
        kv_reduce<<<dim3(64, 4), 64, 0, stream>>>(Pkv, Pks, KVb, Ksb);
        weff_kernel<<<dim3(4, 8), 256, 0, stream>>>(KVb, WtL + 196608, Weffb);
        zcalc<<<8192, 256, 0, stream>>>(Qb, Ksb, Ztb);
        // attention + O-proj + residual + LN1 as one standard GEMM
        gemm_attn_ln<<<256, 512, 0, stream>>>(Qb, Ztb, Weffb, bo + L * 256, Xb,
                                              g1 + L * 256, be1 + L * 256);
        // FFN1 (relu) -> Hb
        gemm_mfma<1><<<dim3(4, 256), 256, 0, stream>>>(Xb, WtL + 262144, b1 + L * 512, Hb, 512, 256);
        // FFN2 + residual + LN2 fused
        gemm_ln<<<256, 512, 0, stream>>>(Hb, WtL + 393216, b2 + L * 256, Xb,
                                         g2 + L * 256, be2 + L * 256, 512);
    }

    store_kernel<<<dim3(128, 8, 8), dim3(32, 32), 0, stream>>>(Xb, (float*)d_out);
}

// Round 8
// 674.553 us; speedup vs baseline: 1.1060x; 1.0134x over previous
//
#include <hip/hip_runtime.h>
#include <hip/hip_bf16.h>

typedef __bf16 bf16;
typedef __attribute__((ext_vector_type(8))) __bf16 bf16x8;
typedef __attribute__((ext_vector_type(4))) __bf16 bf16x4;
typedef __attribute__((ext_vector_type(4))) float f32x4;

__device__ __forceinline__ bf16 f2bf(float f) { return (bf16)f; }

// async global->LDS, 16B per lane. LDS dest must be uniform-base + lane*16.
__device__ __forceinline__ void async_cp16(const void* g, void* l) {
    __builtin_amdgcn_global_load_lds(
        (const __attribute__((address_space(1))) unsigned int*)g,
        (__attribute__((address_space(3))) unsigned int*)l, 16, 0, 0);
}

// ---------------------------------------------------------------------------
// Positional encoding value for channel c, token t (t = h*64 + w)
// ---------------------------------------------------------------------------
__device__ __forceinline__ float pe_val(int c, int t) {
    int h = t >> 6, w = t & 63;
    int i = c >> 2, j = c & 3;
    float div = expf(-0.14391156831212787f * (float)i);
    float arg = ((j < 2) ? (float)w : (float)h) * div;
    return (j & 1) ? cosf(arg) : sinf(arg);
}

// ---------------------------------------------------------------------------
// Encode: feat (4,256,4096) f32 -> Xb[b,t,c] bf16, P2b bf16 (PE added).
// ---------------------------------------------------------------------------
__global__ __launch_bounds__(1024) void encode_kernel(const float* __restrict__ ref,
                                                      const float* __restrict__ src,
                                                      bf16* __restrict__ Xb,
                                                      bf16* __restrict__ P2b) {
    __shared__ float tile[32][33];
    int n = blockIdx.z >> 1, sel = blockIdx.z & 1;
    const float* f = sel ? src : ref;
    int t = blockIdx.x * 32 + threadIdx.x;
    int c = blockIdx.y * 32 + threadIdx.y;
    float v = f[((size_t)n * 256 + c) * 4096 + t] + pe_val(c, t);
    tile[threadIdx.y][threadIdx.x] = v;
    __syncthreads();
    int tt = blockIdx.x * 32 + threadIdx.y;
    int cc = blockIdx.y * 32 + threadIdx.x;
    float o = tile[threadIdx.x][threadIdx.y];
    int bx = sel ? 4 + n : n;
    int bp = sel ? n : 4 + n;
    Xb [((size_t)bx * 4096 + tt) * 256 + cc] = f2bf(o);
    P2b[((size_t)bp * 4096 + tt) * 256 + cc] = f2bf(o);
}

// ---------------------------------------------------------------------------
// Weight transpose+convert: W[K,N] f32 -> Wt[N,K] bf16, all 24 mats, 1 launch
// ---------------------------------------------------------------------------
__global__ __launch_bounds__(1024) void wt_conv(const float* __restrict__ Wq, const float* __restrict__ Wk,
                                                const float* __restrict__ Wv, const float* __restrict__ Wo,
                                                const float* __restrict__ W1, const float* __restrict__ W2,
                                                bf16* __restrict__ Wt) {
    __shared__ float t[32][33];
    int z = blockIdx.z, L = z / 6, m = z - L * 6;
    const float* src; int K, N, doff;
    if      (m == 0) { src = Wq + L * 65536;  K = 256; N = 256; doff = 0; }
    else if (m == 1) { src = Wk + L * 65536;  K = 256; N = 256; doff = 65536; }
    else if (m == 2) { src = Wv + L * 65536;  K = 256; N = 256; doff = 131072; }
    else if (m == 3) { src = Wo + L * 65536;  K = 256; N = 256; doff = 196608; }
    else if (m == 4) { src = W1 + L * 131072; K = 256; N = 512; doff = 262144; }
    else             { src = W2 + L * 131072; K = 512; N = 256; doff = 393216; }
    int n0 = blockIdx.x * 32, k0 = blockIdx.y * 32;
    if (n0 >= N || k0 >= K) return;
    t[threadIdx.y][threadIdx.x] = src[(size_t)(k0 + threadIdx.y) * N + n0 + threadIdx.x];
    __syncthreads();
    bf16* dst = Wt + (size_t)L * 524288 + doff;
    dst[(size_t)(n0 + threadIdx.y) * K + k0 + threadIdx.x] = f2bf(t[threadIdx.x][threadIdx.y]);
}

// ---------------------------------------------------------------------------
// Fused QKV GEMM, v2: 2-phase prefetch double-buffer + XCD-chunked swizzle.
// Grid 1536 1D. swz=(id%8)*192+id/8, bm-major decompose: blocks sharing an
// A-panel land in one XCD chunk (FETCH was 3x input = cross-XCD refetch).
// Prefetch: stage tile t+1 into alt buffer BEFORE computing tile t; one
// barrier per tile (was 2). Math/epilogue identical to R3/R7.
// ---------------------------------------------------------------------------
__global__ __launch_bounds__(256) void gemm_qkv(const bf16* __restrict__ Aq,
                                                const bf16* __restrict__ Akv,
                                                const bf16* __restrict__ Wt,
                                                const float* __restrict__ bq,
                                                const float* __restrict__ bk,
                                                const float* __restrict__ bv,
                                                bf16* __restrict__ Q,
                                                bf16* __restrict__ Ko,
                                                bf16* __restrict__ V) {
    __shared__ bf16 Als[2][128 * 64];
    __shared__ bf16 Bls[2][128 * 64];
    int tid = threadIdx.x;
    int wave = tid >> 6, lane = tid & 63;
    int id = blockIdx.x;
    int swz = (id & 7) * 192 + (id >> 3);     // XCD chunk, nwg=1536
    int bm = (swz / 6) * 128, bn = (swz % 6) * 128;
    int wm = (wave >> 1) * 64, wn = (wave & 1) * 64;
    int l15 = lane & 15, g = lane >> 4;
    const int K = 256;

    int seg = bn >> 8, cloc = bn & 255;
    const bf16* A = seg == 0 ? Aq : Akv;
    const float* bias = seg == 0 ? bq : (seg == 1 ? bk : bv);
    bf16* Out = seg == 0 ? Q : (seg == 1 ? Ko : V);
    bool do_elu = seg < 2;

    f32x4 acc[4][4] = {};

#define QKV_STAGE(buf, k0)                                                      \
    {                                                                           \
        _Pragma("unroll")                                                       \
        for (int r = 0; r < 4; ++r) {                                           \
            int Lc = r * 256 + tid;                                             \
            int row = Lc >> 3, cs = Lc & 7;                                     \
            int gc = cs ^ (row & 7);                                            \
            async_cp16(A  + (size_t)(bm + row) * K + (k0) + gc * 8, &Als[buf][Lc * 8]); \
            async_cp16(Wt + (size_t)(bn + row) * K + (k0) + gc * 8, &Bls[buf][Lc * 8]); \
        }                                                                       \
    }

    QKV_STAGE(0, 0);
    __syncthreads();
    int cur = 0;
    for (int t = 0; t < 4; ++t) {
        if (t < 3) QKV_STAGE(cur ^ 1, (t + 1) * 64);
#pragma unroll
        for (int ks = 0; ks < 2; ++ks) {
            bf16x8 af[4], bfr[4];
#pragma unroll
            for (int i = 0; i < 4; ++i) {
                int row = wm + i * 16 + l15;
                int c = ks * 4 + g;
                af[i] = *(bf16x8*)&Als[cur][row * 64 + ((c ^ (row & 7)) * 8)];
            }
#pragma unroll
            for (int j = 0; j < 4; ++j) {
                int row = wn + j * 16 + l15;
                int c = ks * 4 + g;
                bfr[j] = *(bf16x8*)&Bls[cur][row * 64 + ((c ^ (row & 7)) * 8)];
            }
#pragma unroll
            for (int i = 0; i < 4; ++i)
#pragma unroll
                for (int j = 0; j < 4; ++j)
                    acc[i][j] = __builtin_amdgcn_mfma_f32_16x16x32_bf16(af[i], bfr[j], acc[i][j], 0, 0, 0);
        }
        __syncthreads();
        cur ^= 1;
    }
#undef QKV_STAGE

    int r4 = (lane >> 4) * 4;
#pragma unroll
    for (int i = 0; i < 4; ++i) {
#pragma unroll
        for (int j = 0; j < 4; ++j) {
            int cj = cloc + wn + j * 16 + l15;
            float bvv = bias[cj];
#pragma unroll
            for (int r = 0; r < 4; ++r) {
                int row = bm + wm + i * 16 + r4 + r;
                float v = acc[i][j][r] + bvv;
                if (do_elu) v = v > 0.f ? v + 1.f : expf(v);
                Out[(size_t)row * 256 + cj] = f2bf(v);
            }
        }
    }
}

// ---------------------------------------------------------------------------
// MFMA GEMM (FFN1), v2: same 2-phase prefetch + XCD swizzle (grid 1024 1D).
// ---------------------------------------------------------------------------
template <int RELU>
__global__ __launch_bounds__(256) void gemm_mfma(const bf16* __restrict__ A,
                                                 const bf16* __restrict__ Wt,
                                                 const float* __restrict__ bias,
                                                 bf16* __restrict__ C,
                                                 int N, int K, int nbn) {
    __shared__ bf16 Als[2][128 * 64];
    __shared__ bf16 Bls[2][128 * 64];
    int tid = threadIdx.x;
    int wave = tid >> 6, lane = tid & 63;
    int id = blockIdx.x;
    int nwg = gridDim.x;
    int cpx = nwg >> 3;                       // nwg % 8 == 0
    int swz = (id & 7) * cpx + (id >> 3);
    int bm = (swz / nbn) * 128, bn = (swz % nbn) * 128;
    int wm = (wave >> 1) * 64, wn = (wave & 1) * 64;
    int l15 = lane & 15, g = lane >> 4;

    f32x4 acc[4][4] = {};

#define MF_STAGE(buf, k0)                                                       \
    {                                                                           \
        _Pragma("unroll")                                                       \
        for (int r = 0; r < 4; ++r) {                                           \
            int Lc = r * 256 + tid;                                             \
            int row = Lc >> 3, cs = Lc & 7;                                     \
            int gc = cs ^ (row & 7);                                            \
            async_cp16(A  + (size_t)(bm + row) * K + (k0) + gc * 8, &Als[buf][Lc * 8]); \
            async_cp16(Wt + (size_t)(bn + row) * K + (k0) + gc * 8, &Bls[buf][Lc * 8]); \
        }                                                                       \
    }

    int nt = K >> 6;
    MF_STAGE(0, 0);
    __syncthreads();
    int cur = 0;
    for (int t = 0; t < nt; ++t) {
        if (t < nt - 1) MF_STAGE(cur ^ 1, (t + 1) * 64);
#pragma unroll
        for (int ks = 0; ks < 2; ++ks) {
            bf16x8 af[4], bfr[4];
#pragma unroll
            for (int i = 0; i < 4; ++i) {
                int row = wm + i * 16 + l15;
                int c = ks * 4 + g;
                af[i] = *(bf16x8*)&Als[cur][row * 64 + ((c ^ (row & 7)) * 8)];
            }
#pragma unroll
            for (int j = 0; j < 4; ++j) {
                int row = wn + j * 16 + l15;
                int c = ks * 4 + g;
                bfr[j] = *(bf16x8*)&Bls[cur][row * 64 + ((c ^ (row & 7)) * 8)];
            }
#pragma unroll
            for (int i = 0; i < 4; ++i)
#pragma unroll
                for (int j = 0; j < 4; ++j)
                    acc[i][j] = __builtin_amdgcn_mfma_f32_16x16x32_bf16(af[i], bfr[j], acc[i][j], 0, 0, 0);
        }
        __syncthreads();
        cur ^= 1;
    }
#undef MF_STAGE

    int r4 = (lane >> 4) * 4;
#pragma unroll
    for (int i = 0; i < 4; ++i) {
#pragma unroll
        for (int j = 0; j < 4; ++j) {
            int col = bn + wn + j * 16 + l15;
            float bvv = bias[col];
#pragma unroll
            for (int r = 0; r < 4; ++r) {
                int row = bm + wm + i * 16 + r4 + r;
                float v = acc[i][j][r] + bvv;
                if (RELU) v = fmaxf(v, 0.f);
                C[(size_t)row * N + col] = f2bf(v);
            }
        }
    }
}

// ---------------------------------------------------------------------------
// Fused GEMM (N=256) + residual + LayerNorm epilogue (FFN2 path, R3 version)
// ---------------------------------------------------------------------------
__global__ __launch_bounds__(512) void gemm_ln(const bf16* __restrict__ A,
                                               const bf16* __restrict__ Wt,
                                               const float* __restrict__ bias,
                                               bf16* __restrict__ Xb,
                                               const float* __restrict__ g,
                                               const float* __restrict__ b,
                                               int K) {
    __shared__ __align__(16) char smem[128 * 260 * 2];  // 66560 B
    bf16* Als = (bf16*)smem;            // [128][64]  16 KB (during K loop)
    bf16* Bls = (bf16*)(smem + 16384);  // [256][64]  32 KB (during K loop)
    bf16* Cls = (bf16*)smem;            // [128][260] after K loop

    int tid = threadIdx.x;
    int wave = tid >> 6, lane = tid & 63;
    int bm = blockIdx.x * 128;
    int wm = (wave >> 2) * 64, wn = (wave & 3) * 64;
    int l15 = lane & 15, gg = lane >> 4;

    f32x4 acc[4][4] = {};

    for (int k0 = 0; k0 < K; k0 += 64) {
#pragma unroll
        for (int r = 0; r < 2; ++r) {   // A tile: 128x64
            int Lc = r * 512 + tid;
            int row = Lc >> 3, cs = Lc & 7;
            int gc = cs ^ (row & 7);
            async_cp16(A + (size_t)(bm + row) * K + k0 + gc * 8, &Als[Lc * 8]);
        }
#pragma unroll
        for (int r = 0; r < 4; ++r) {   // B tile: 256x64
            int Lc = r * 512 + tid;
            int row = Lc >> 3, cs = Lc & 7;
            int gc = cs ^ (row & 7);
            async_cp16(Wt + (size_t)row * K + k0 + gc * 8, &Bls[Lc * 8]);
        }
        __syncthreads();
#pragma unroll
        for (int ks = 0; ks < 2; ++ks) {
            bf16x8 af[4], bfr[4];
#pragma unroll
            for (int i = 0; i < 4; ++i) {
                int row = wm + i * 16 + l15;
                int c = ks * 4 + gg;
                af[i] = *(bf16x8*)&Als[row * 64 + ((c ^ (row & 7)) * 8)];
            }
#pragma unroll
            for (int j = 0; j < 4; ++j) {
                int row = wn + j * 16 + l15;
                int c = ks * 4 + gg;
                bfr[j] = *(bf16x8*)&Bls[row * 64 + ((c ^ (row & 7)) * 8)];
            }
#pragma unroll
            for (int i = 0; i < 4; ++i)
#pragma unroll
                for (int j = 0; j < 4; ++j)
                    acc[i][j] = __builtin_amdgcn_mfma_f32_16x16x32_bf16(af[i], bfr[j], acc[i][j], 0, 0, 0);
        }
        __syncthreads();
    }

    int r4 = (lane >> 4) * 4;
#pragma unroll
    for (int j = 0; j < 4; ++j) {
        int col = wn + j * 16 + l15;
        float bvv = bias[col];
#pragma unroll
        for (int i = 0; i < 4; ++i)
#pragma unroll
            for (int r = 0; r < 4; ++r)
                Cls[(wm + i * 16 + r4 + r) * 260 + col] = f2bf(acc[i][j][r] + bvv);
    }
    __syncthreads();

    int c4 = lane * 4;
    float4 gw = *(const float4*)&g[c4];
    float4 bw = *(const float4*)&b[c4];
#pragma unroll 2
    for (int rw = 0; rw < 16; ++rw) {
        int row = wave * 16 + rw;
        size_t gidx = (size_t)(bm + row) * 256 + c4;
        bf16x4 xb = *(const bf16x4*)(Xb + gidx);
        bf16x4 cb = *(const bf16x4*)&Cls[row * 260 + c4];
        float4 v;
        v.x = (float)xb[0] + (float)cb[0];
        v.y = (float)xb[1] + (float)cb[1];
        v.z = (float)xb[2] + (float)cb[2];
        v.w = (float)xb[3] + (float)cb[3];
        float s  = v.x + v.y + v.z + v.w;
        float sq = v.x * v.x + v.y * v.y + v.z * v.z + v.w * v.w;
#pragma unroll
        for (int off = 32; off > 0; off >>= 1) {
            s  += __shfl_xor(s,  off);
            sq += __shfl_xor(sq, off);
        }
        float mean = s * (1.f / 256.f);
        float var  = sq * (1.f / 256.f) - mean * mean;
        float rstd = rsqrtf(var + 1e-5f);
        bf16x4 ob;
        ob[0] = f2bf((v.x - mean) * rstd * gw.x + bw.x);
        ob[1] = f2bf((v.y - mean) * rstd * gw.y + bw.y);
        ob[2] = f2bf((v.z - mean) * rstd * gw.z + bw.z);
        ob[3] = f2bf((v.w - mean) * rstd * gw.w + bw.w);
        *(bf16x4*)(Xb + gidx) = ob;
    }
}

// ---------------------------------------------------------------------------
// Attention as a GEMM: Xb = LN(Xb + (Z.Q) @ Weff[n]^T + bo). (R7 version)
// ---------------------------------------------------------------------------
__global__ __launch_bounds__(512) void gemm_attn_ln(const bf16* __restrict__ A,
                                                    const float* __restrict__ Zt,
                                                    const bf16* __restrict__ Weff,
                                                    const float* __restrict__ bias,
                                                    bf16* __restrict__ Xb,
                                                    const float* __restrict__ g,
                                                    const float* __restrict__ b) {
    __shared__ __align__(16) char smem[128 * 260 * 2];  // 66560 B
    bf16* Als = (bf16*)smem;            // [128][64]
    bf16* Bls = (bf16*)(smem + 16384);  // [256][64]
    bf16* Cls = (bf16*)smem;            // [128][260] after K loop

    int tid = threadIdx.x;
    int wave = tid >> 6, lane = tid & 63;
    int bm = blockIdx.x * 128;
    const bf16* Wt = Weff + (size_t)(bm >> 12) * 65536;   // per-batch
    int wm = (wave >> 2) * 64, wn = (wave & 3) * 64;
    int l15 = lane & 15, gg = lane >> 4;

    f32x4 acc[4][4] = {};

    for (int k0 = 0; k0 < 256; k0 += 64) {
#pragma unroll
        for (int r = 0; r < 4; ++r) {   // B tile: 256x64 (async, overlaps A work)
            int Lc = r * 512 + tid;
            int row = Lc >> 3, cs = Lc & 7;
            int gc = cs ^ (row & 7);
            async_cp16(Wt + (size_t)row * 256 + k0 + gc * 8, &Bls[Lc * 8]);
        }
#pragma unroll
        for (int r = 0; r < 2; ++r) {   // A tile: 128x64, reg-staged with Z scale
            int Lc = r * 512 + tid;
            int row = Lc >> 3, cs = Lc & 7;
            int gc = cs ^ (row & 7);
            int gcol = k0 + gc * 8;
            bf16x8 q8 = *(const bf16x8*)(A + (size_t)(bm + row) * 256 + gcol);
            float z = Zt[(size_t)(bm + row) * 8 + (gcol >> 5)];
            bf16x8 a8;
#pragma unroll
            for (int u = 0; u < 8; ++u) a8[u] = f2bf((float)q8[u] * z);
            *(bf16x8*)&Als[Lc * 8] = a8;
        }
        __syncthreads();
#pragma unroll
        for (int ks = 0; ks < 2; ++ks) {
            bf16x8 af[4], bfr[4];
#pragma unroll
            for (int i = 0; i < 4; ++i) {
                int row = wm + i * 16 + l15;
                int c = ks * 4 + gg;
                af[i] = *(bf16x8*)&Als[row * 64 + ((c ^ (row & 7)) * 8)];
            }
#pragma unroll
            for (int j = 0; j < 4; ++j) {
                int row = wn + j * 16 + l15;
                int c = ks * 4 + gg;
                bfr[j] = *(bf16x8*)&Bls[row * 64 + ((c ^ (row & 7)) * 8)];
            }
#pragma unroll
            for (int i = 0; i < 4; ++i)
#pragma unroll
                for (int j = 0; j < 4; ++j)
                    acc[i][j] = __builtin_amdgcn_mfma_f32_16x16x32_bf16(af[i], bfr[j], acc[i][j], 0, 0, 0);
        }
        __syncthreads();
    }

    int r4 = (lane >> 4) * 4;
#pragma unroll
    for (int j = 0; j < 4; ++j) {
        int col = wn + j * 16 + l15;
        float bvv = bias[col];
#pragma unroll
        for (int i = 0; i < 4; ++i)
#pragma unroll
            for (int r = 0; r < 4; ++r)
                Cls[(wm + i * 16 + r4 + r) * 260 + col] = f2bf(acc[i][j][r] + bvv);
    }
    __syncthreads();

    int c4 = lane * 4;
    float4 gw = *(const float4*)&g[c4];
    float4 bw = *(const float4*)&b[c4];
#pragma unroll 2
    for (int rw = 0; rw < 16; ++rw) {
        int row = wave * 16 + rw;
        size_t gidx = (size_t)(bm + row) * 256 + c4;
        bf16x4 xb = *(const bf16x4*)(Xb + gidx);
        bf16x4 cb = *(const bf16x4*)&Cls[row * 260 + c4];
        float4 v;
        v.x = (float)xb[0] + (float)cb[0];
        v.y = (float)xb[1] + (float)cb[1];
        v.z = (float)xb[2] + (float)cb[2];
        v.w = (float)xb[3] + (float)cb[3];
        float s  = v.x + v.y + v.z + v.w;
        float sq = v.x * v.x + v.y * v.y + v.z * v.z + v.w * v.w;
#pragma unroll
        for (int off = 32; off > 0; off >>= 1) {
            s  += __shfl_xor(s,  off);
            sq += __shfl_xor(sq, off);
        }
        float mean = s * (1.f / 256.f);
        float var  = sq * (1.f / 256.f) - mean * mean;
        float rstd = rsqrtf(var + 1e-5f);
        bf16x4 ob;
        ob[0] = f2bf((v.x - mean) * rstd * gw.x + bw.x);
        ob[1] = f2bf((v.y - mean) * rstd * gw.y + bw.y);
        ob[2] = f2bf((v.z - mean) * rstd * gw.z + bw.z);
        ob[3] = f2bf((v.w - mean) * rstd * gw.w + bw.w);
        *(bf16x4*)(Xb + gidx) = ob;
    }
}

// ---------------------------------------------------------------------------
// KV prep: grid (32 sp, 64 nh), 256 thr = 4 waves.
// ---------------------------------------------------------------------------
__global__ __launch_bounds__(256) void kv_prep_part(const bf16* __restrict__ Kb,
                                                    const bf16* __restrict__ Vb,
                                                    float* __restrict__ Pkv,
                                                    float* __restrict__ Pks) {
    __shared__ float Ks[128][32];
    __shared__ float Vs[128][32];
    int sp = blockIdx.x;
    int nh = blockIdx.y;
    int n = nh >> 3, h = nh & 7;
    int tid = threadIdx.x;
    int wave = tid >> 6, lane = tid & 63;
    int mg = lane >> 3;
    int dg = lane & 7;
    size_t base = ((size_t)n * 4096 + sp * 128) * 256 + h * 32;

#pragma unroll
    for (int p = 0; p < 2; ++p) {
        int r = p * 64 + (tid >> 2);
        int c = (tid & 3) * 8;
        bf16x8 k8 = *(const bf16x8*)(Kb + base + (size_t)r * 256 + c);
        bf16x8 v8 = *(const bf16x8*)(Vb + base + (size_t)r * 256 + c);
#pragma unroll
        for (int u = 0; u < 8; ++u) { Ks[r][c + u] = (float)k8[u]; Vs[r][c + u] = (float)v8[u]; }
    }
    __syncthreads();

    float acc[4][4] = {};
    float ks4[4] = {};
    int s0 = wave * 32;
    for (int s = s0; s < s0 + 32; ++s) {
        float4 kq = *(float4*)&Ks[s][dg * 4];
        float4 vq = *(float4*)&Vs[s][mg * 4];
        ks4[0] += kq.x; ks4[1] += kq.y; ks4[2] += kq.z; ks4[3] += kq.w;
        acc[0][0] += vq.x * kq.x; acc[0][1] += vq.x * kq.y; acc[0][2] += vq.x * kq.z; acc[0][3] += vq.x * kq.w;
        acc[1][0] += vq.y * kq.x; acc[1][1] += vq.y * kq.y; acc[1][2] += vq.y * kq.z; acc[1][3] += vq.y * kq.w;
        acc[2][0] += vq.z * kq.x; acc[2][1] += vq.z * kq.y; acc[2][2] += vq.z * kq.z; acc[2][3] += vq.z * kq.w;
        acc[3][0] += vq.w * kq.x; acc[3][1] += vq.w * kq.y; acc[3][2] += vq.w * kq.z; acc[3][3] += vq.w * kq.w;
    }
    __syncthreads();

    float* R  = &Ks[0][0];
    float* RS = &Vs[0][0];
#pragma unroll
    for (int mi = 0; mi < 4; ++mi)
#pragma unroll
        for (int dj = 0; dj < 4; ++dj)
            R[wave * 1024 + (mg * 4 + mi) * 32 + dg * 4 + dj] = acc[mi][dj];
    if (mg == 0)
#pragma unroll
        for (int dj = 0; dj < 4; ++dj) RS[wave * 32 + dg * 4 + dj] = ks4[dj];
    __syncthreads();

    int e = tid * 4;
    float4 o0 = *(float4*)&R[e];
    float4 o1 = *(float4*)&R[1024 + e];
    float4 o2 = *(float4*)&R[2048 + e];
    float4 o3 = *(float4*)&R[3072 + e];
    float4 o = make_float4(o0.x + o1.x + o2.x + o3.x, o0.y + o1.y + o2.y + o3.y,
                           o0.z + o1.z + o2.z + o3.z, o0.w + o1.w + o2.w + o3.w);
    *(float4*)&Pkv[((size_t)nh * 32 + sp) * 1024 + e] = o;
    if (tid < 32)
        Pks[((size_t)nh * 32 + sp) * 32 + tid] = RS[tid] + RS[32 + tid] + RS[64 + tid] + RS[96 + tid];
}

// grid (64 nh, 4 quarters), 64 threads (1 wave).
__global__ __launch_bounds__(64) void kv_reduce(const float* __restrict__ Pkv,
                                                const float* __restrict__ Pks,
                                                float* __restrict__ KV,
                                                float* __restrict__ Ksum) {
    int nh = blockIdx.x;
    int q = blockIdx.y;
    int e = (q * 64 + threadIdx.x) * 4;
    float4 s = make_float4(0.f, 0.f, 0.f, 0.f);
    for (int sp = 0; sp < 32; ++sp) {
        float4 p = *(const float4*)&Pkv[((size_t)nh * 32 + sp) * 1024 + e];
        s.x += p.x; s.y += p.y; s.z += p.z; s.w += p.w;
    }
    *(float4*)&KV[(size_t)nh * 1024 + e] = s;
    if (q == 0 && threadIdx.x < 32) {
        float ss = 0.f;
        for (int sp = 0; sp < 32; ++sp) ss += Pks[((size_t)nh * 32 + sp) * 32 + threadIdx.x];
        Ksum[nh * 32 + threadIdx.x] = ss;
    }
}

// ---------------------------------------------------------------------------
// Weff[n][c][h*32+d] = sum_m KV[n,h,m,d] * Wo[(h,m),c]   (bf16, Wt layout)
// ---------------------------------------------------------------------------
__global__ __launch_bounds__(256) void weff_kernel(const float* __restrict__ KV,
                                                   const bf16* __restrict__ WtO,
                                                   bf16* __restrict__ Weff) {
    __shared__ float KVs[8][1024];   // [h][m*32+d]
    int n = blockIdx.y, c0 = blockIdx.x * 64;
    int tid = threadIdx.x;
    const float* src = KV + (size_t)n * 8192;
    for (int i = tid; i < 2048; i += 256)
        *(float4*)&((float*)KVs)[i * 4] = *(const float4*)&src[i * 4];
    __syncthreads();

    int c = c0 + (tid & 63);
    int hb = tid >> 6;               // wave id: h in {2hb, 2hb+1}
    const bf16* wrow = WtO + (size_t)c * 256 + hb * 64;
    bf16* dst = Weff + (size_t)n * 65536 + (size_t)c * 256 + hb * 64;

#pragma unroll
    for (int hh = 0; hh < 2; ++hh) {
        int h = hb * 2 + hh;
        float wo[32];
#pragma unroll
        for (int u = 0; u < 4; ++u) {
            bf16x8 w8 = *(const bf16x8*)(wrow + hh * 32 + u * 8);
#pragma unroll
            for (int v = 0; v < 8; ++v) wo[u * 8 + v] = (float)w8[v];
        }
        float s[32] = {};
        for (int m = 0; m < 32; ++m) {
            float wm = wo[m];
#pragma unroll
            for (int d4 = 0; d4 < 8; ++d4) {
                float4 kv4 = *(float4*)&KVs[h][m * 32 + d4 * 4];
                s[d4 * 4 + 0] += wm * kv4.x;
                s[d4 * 4 + 1] += wm * kv4.y;
                s[d4 * 4 + 2] += wm * kv4.z;
                s[d4 * 4 + 3] += wm * kv4.w;
            }
        }
#pragma unroll
        for (int u = 0; u < 4; ++u) {
            bf16x8 o8;
#pragma unroll
            for (int v = 0; v < 8; ++v) o8[v] = f2bf(s[u * 8 + v]);
            *(bf16x8*)(dst + hh * 32 + u * 8) = o8;
        }
    }
}

// ---------------------------------------------------------------------------
// zcalc: Zt[row][h] = 1/(dot(Q[row,h,:], Ksum[n,h,:]) + eps). 4 rows/block.
// ---------------------------------------------------------------------------
__global__ __launch_bounds__(256) void zcalc(const bf16* __restrict__ Qb,
                                             const float* __restrict__ Ksum,
                                             float* __restrict__ Zt) {
    int row = blockIdx.x * 4 + (threadIdx.x >> 6);
    int lane = threadIdx.x & 63;
    int n = row >> 12;
    int c = lane * 4;
    bf16x4 q = *(const bf16x4*)(Qb + (size_t)row * 256 + c);
    float4 k = *(const float4*)&Ksum[n * 256 + c];
    float s = (float)q[0] * k.x + (float)q[1] * k.y + (float)q[2] * k.z + (float)q[3] * k.w;
    s += __shfl_xor(s, 1); s += __shfl_xor(s, 2); s += __shfl_xor(s, 4);
    if ((lane & 7) == 0)
        Zt[(size_t)row * 8 + (lane >> 3)] = 1.f / (s + 1e-6f);
}

// ---------------------------------------------------------------------------
// Store: Xb[b,t,c] bf16 -> out[b,c,t] f32
// ---------------------------------------------------------------------------
__global__ __launch_bounds__(1024) void store_kernel(const bf16* __restrict__ Xb,
                                                     float* __restrict__ out) {
    __shared__ float tile[32][33];
    int b = blockIdx.z;
    int t0 = blockIdx.x * 32, c0 = blockIdx.y * 32;
    tile[threadIdx.y][threadIdx.x] =
        (float)Xb[((size_t)b * 4096 + t0 + threadIdx.y) * 256 + c0 + threadIdx.x];
    __syncthreads();
    out[((size_t)b * 256 + c0 + threadIdx.y) * 4096 + t0 + threadIdx.x] =
        tile[threadIdx.x][threadIdx.y];
}

// ---------------------------------------------------------------------------
extern "C" void kernel_launch(void* const* d_in, const int* in_sizes, int n_in,
                              void* d_out, int out_size, void* d_ws, size_t ws_size,
                              hipStream_t stream) {
    const float* ref  = (const float*)d_in[0];
    const float* srcf = (const float*)d_in[1];
    const float* Wq = (const float*)d_in[2];
    const float* bq = (const float*)d_in[3];
    const float* Wk = (const float*)d_in[4];
    const float* bk = (const float*)d_in[5];
    const float* Wv = (const float*)d_in[6];
    const float* bv = (const float*)d_in[7];
    const float* Wo = (const float*)d_in[8];
    const float* bo = (const float*)d_in[9];
    const float* W1 = (const float*)d_in[10];
    const float* b1 = (const float*)d_in[11];
    const float* W2 = (const float*)d_in[12];
    const float* b2 = (const float*)d_in[13];
    const float* g1 = (const float*)d_in[14];
    const float* be1 = (const float*)d_in[15];
    const float* g2 = (const float*)d_in[16];
    const float* be2 = (const float*)d_in[17];

    const size_t SZ = (size_t)8 * 4096 * 256;
    float* ws  = (float*)d_ws;
    float* KVb = ws;                          // 65536 f32
    float* Ksb = KVb + 65536;                 // 2048 f32
    float* Pkv = Ksb + 2048;                  // 2,097,152 f32
    float* Pks = Pkv + 2097152;               // 65536 f32
    bf16*  Wt  = (bf16*)(Pks + 65536);        // 2,097,152 bf16
    bf16*  Xb  = Wt + 2097152;                // SZ bf16 (residual stream)
    bf16*  P2b = Xb + SZ;                     // SZ bf16
    bf16*  Qb  = P2b + SZ;                    // SZ bf16
    // Weff (1 MB bf16) + Zt (1 MB f32) alias the Pkv head.
    bf16*  Weffb = (bf16*)Pkv;                // 524288 bf16 = 1 MB
    float* Ztb   = Pkv + 262144;              // 262144 f32  = 1 MB
    // K/V live in d_out (exact 2*SZ bf16 fit); dead before store_kernel runs.
    bf16*  Kb  = (bf16*)d_out;
    bf16*  Vb  = Kb + SZ;
    bf16*  Hb  = Kb;                          // alias: FFN hidden spans Kb+Vb

    wt_conv<<<dim3(16, 16, 24), dim3(32, 32), 0, stream>>>(Wq, Wk, Wv, Wo, W1, W2, Wt);
    encode_kernel<<<dim3(128, 8, 8), dim3(32, 32), 0, stream>>>(ref, srcf, Xb, P2b);

    for (int L = 0; L < 4; ++L) {
        const bf16* WtL = Wt + (size_t)L * 524288;
        const bf16* Akv = (L & 1) ? P2b : Xb;
        gemm_qkv<<<1536, 256, 0, stream>>>(Xb, Akv, WtL,
                                           bq + L * 256, bk + L * 256, bv + L * 256,
                                           Qb, Kb, Vb);
        kv_prep_part<<<dim3(32, 64), 256, 0, stream>>>(Kb, Vb, Pkv, Pks);
        kv_reduce<<<dim3(64, 4), 64, 0, stream>>>(Pkv, Pks, KVb, Ksb);
        weff_kernel<<<dim3(4, 8), 256, 0, stream>>>(KVb, WtL + 196608, Weffb);
        zcalc<<<8192, 256, 0, stream>>>(Qb, Ksb, Ztb);
        // attention + O-proj + residual + LN1 as one standard GEMM
        gemm_attn_ln<<<256, 512, 0, stream>>>(Qb, Ztb, Weffb, bo + L * 256, Xb,
                                              g1 + L * 256, be1 + L * 256);
        // FFN1 (relu) -> Hb
        gemm_mfma<1><<<1024, 256, 0, stream>>>(Xb, WtL + 262144, b1 + L * 512, Hb, 512, 256, 4);
        // FFN2 + residual + LN2 fused
        gemm_ln<<<256, 512, 0, stream>>>(Hb, WtL + 393216, b2 + L * 256, Xb,
                                         g2 + L * 256, be2 + L * 256, 512);
    }

    store_kernel<<<dim3(128, 8, 8), dim3(32, 32), 0, stream>>>(Xb, (float*)d_out);
}

// Round 9
// 665.284 us; speedup vs baseline: 1.1214x; 1.0139x over previous
//
#include <hip/hip_runtime.h>
#include <hip/hip_bf16.h>

typedef __bf16 bf16;
typedef __attribute__((ext_vector_type(8))) __bf16 bf16x8;
typedef __attribute__((ext_vector_type(4))) __bf16 bf16x4;
typedef __attribute__((ext_vector_type(4))) float f32x4;

__device__ __forceinline__ bf16 f2bf(float f) { return (bf16)f; }

// async global->LDS, 16B per lane. LDS dest must be uniform-base + lane*16.
__device__ __forceinline__ void async_cp16(const void* g, void* l) {
    __builtin_amdgcn_global_load_lds(
        (const __attribute__((address_space(1))) unsigned int*)g,
        (__attribute__((address_space(3))) unsigned int*)l, 16, 0, 0);
}

// ---------------------------------------------------------------------------
// Positional encoding value for channel c, token t (t = h*64 + w)
// ---------------------------------------------------------------------------
__device__ __forceinline__ float pe_val(int c, int t) {
    int h = t >> 6, w = t & 63;
    int i = c >> 2, j = c & 3;
    float div = expf(-0.14391156831212787f * (float)i);
    float arg = ((j < 2) ? (float)w : (float)h) * div;
    return (j & 1) ? cosf(arg) : sinf(arg);
}

// ---------------------------------------------------------------------------
// Encode: feat (4,256,4096) f32 -> Xb[b,t,c] bf16, P2b bf16 (PE added).
// ---------------------------------------------------------------------------
__global__ __launch_bounds__(1024) void encode_kernel(const float* __restrict__ ref,
                                                      const float* __restrict__ src,
                                                      bf16* __restrict__ Xb,
                                                      bf16* __restrict__ P2b) {
    __shared__ float tile[32][33];
    int n = blockIdx.z >> 1, sel = blockIdx.z & 1;
    const float* f = sel ? src : ref;
    int t = blockIdx.x * 32 + threadIdx.x;
    int c = blockIdx.y * 32 + threadIdx.y;
    float v = f[((size_t)n * 256 + c) * 4096 + t] + pe_val(c, t);
    tile[threadIdx.y][threadIdx.x] = v;
    __syncthreads();
    int tt = blockIdx.x * 32 + threadIdx.y;
    int cc = blockIdx.y * 32 + threadIdx.x;
    float o = tile[threadIdx.x][threadIdx.y];
    int bx = sel ? 4 + n : n;
    int bp = sel ? n : 4 + n;
    Xb [((size_t)bx * 4096 + tt) * 256 + cc] = f2bf(o);
    P2b[((size_t)bp * 4096 + tt) * 256 + cc] = f2bf(o);
}

// ---------------------------------------------------------------------------
// Weight transpose+convert: W[K,N] f32 -> Wt[N,K] bf16, all 24 mats, 1 launch
// ---------------------------------------------------------------------------
__global__ __launch_bounds__(1024) void wt_conv(const float* __restrict__ Wq, const float* __restrict__ Wk,
                                                const float* __restrict__ Wv, const float* __restrict__ Wo,
                                                const float* __restrict__ W1, const float* __restrict__ W2,
                                                bf16* __restrict__ Wt) {
    __shared__ float t[32][33];
    int z = blockIdx.z, L = z / 6, m = z - L * 6;
    const float* src; int K, N, doff;
    if      (m == 0) { src = Wq + L * 65536;  K = 256; N = 256; doff = 0; }
    else if (m == 1) { src = Wk + L * 65536;  K = 256; N = 256; doff = 65536; }
    else if (m == 2) { src = Wv + L * 65536;  K = 256; N = 256; doff = 131072; }
    else if (m == 3) { src = Wo + L * 65536;  K = 256; N = 256; doff = 196608; }
    else if (m == 4) { src = W1 + L * 131072; K = 256; N = 512; doff = 262144; }
    else             { src = W2 + L * 131072; K = 512; N = 256; doff = 393216; }
    int n0 = blockIdx.x * 32, k0 = blockIdx.y * 32;
    if (n0 >= N || k0 >= K) return;
    t[threadIdx.y][threadIdx.x] = src[(size_t)(k0 + threadIdx.y) * N + n0 + threadIdx.x];
    __syncthreads();
    bf16* dst = Wt + (size_t)L * 524288 + doff;
    dst[(size_t)(n0 + threadIdx.y) * K + k0 + threadIdx.x] = f2bf(t[threadIdx.x][threadIdx.y]);
}

// ---------------------------------------------------------------------------
// Fused QKV GEMM, v2: 2-phase prefetch double-buffer + XCD-chunked swizzle.
// (R8 version, verified <41us vs 54.7 for single-buffer)
// ---------------------------------------------------------------------------
__global__ __launch_bounds__(256) void gemm_qkv(const bf16* __restrict__ Aq,
                                                const bf16* __restrict__ Akv,
                                                const bf16* __restrict__ Wt,
                                                const float* __restrict__ bq,
                                                const float* __restrict__ bk,
                                                const float* __restrict__ bv,
                                                bf16* __restrict__ Q,
                                                bf16* __restrict__ Ko,
                                                bf16* __restrict__ V) {
    __shared__ bf16 Als[2][128 * 64];
    __shared__ bf16 Bls[2][128 * 64];
    int tid = threadIdx.x;
    int wave = tid >> 6, lane = tid & 63;
    int id = blockIdx.x;
    int swz = (id & 7) * 192 + (id >> 3);     // XCD chunk, nwg=1536
    int bm = (swz / 6) * 128, bn = (swz % 6) * 128;
    int wm = (wave >> 1) * 64, wn = (wave & 1) * 64;
    int l15 = lane & 15, g = lane >> 4;
    const int K = 256;

    int seg = bn >> 8, cloc = bn & 255;
    const bf16* A = seg == 0 ? Aq : Akv;
    const float* bias = seg == 0 ? bq : (seg == 1 ? bk : bv);
    bf16* Out = seg == 0 ? Q : (seg == 1 ? Ko : V);
    bool do_elu = seg < 2;

    f32x4 acc[4][4] = {};

#define QKV_STAGE(buf, k0)                                                      \
    {                                                                           \
        _Pragma("unroll")                                                       \
        for (int r = 0; r < 4; ++r) {                                           \
            int Lc = r * 256 + tid;                                             \
            int row = Lc >> 3, cs = Lc & 7;                                     \
            int gc = cs ^ (row & 7);                                            \
            async_cp16(A  + (size_t)(bm + row) * K + (k0) + gc * 8, &Als[buf][Lc * 8]); \
            async_cp16(Wt + (size_t)(bn + row) * K + (k0) + gc * 8, &Bls[buf][Lc * 8]); \
        }                                                                       \
    }

    QKV_STAGE(0, 0);
    __syncthreads();
    int cur = 0;
    for (int t = 0; t < 4; ++t) {
        if (t < 3) QKV_STAGE(cur ^ 1, (t + 1) * 64);
#pragma unroll
        for (int ks = 0; ks < 2; ++ks) {
            bf16x8 af[4], bfr[4];
#pragma unroll
            for (int i = 0; i < 4; ++i) {
                int row = wm + i * 16 + l15;
                int c = ks * 4 + g;
                af[i] = *(bf16x8*)&Als[cur][row * 64 + ((c ^ (row & 7)) * 8)];
            }
#pragma unroll
            for (int j = 0; j < 4; ++j) {
                int row = wn + j * 16 + l15;
                int c = ks * 4 + g;
                bfr[j] = *(bf16x8*)&Bls[cur][row * 64 + ((c ^ (row & 7)) * 8)];
            }
#pragma unroll
            for (int i = 0; i < 4; ++i)
#pragma unroll
                for (int j = 0; j < 4; ++j)
                    acc[i][j] = __builtin_amdgcn_mfma_f32_16x16x32_bf16(af[i], bfr[j], acc[i][j], 0, 0, 0);
        }
        __syncthreads();
        cur ^= 1;
    }
#undef QKV_STAGE

    int r4 = (lane >> 4) * 4;
#pragma unroll
    for (int i = 0; i < 4; ++i) {
#pragma unroll
        for (int j = 0; j < 4; ++j) {
            int cj = cloc + wn + j * 16 + l15;
            float bvv = bias[cj];
#pragma unroll
            for (int r = 0; r < 4; ++r) {
                int row = bm + wm + i * 16 + r4 + r;
                float v = acc[i][j][r] + bvv;
                if (do_elu) v = v > 0.f ? v + 1.f : expf(v);
                Out[(size_t)row * 256 + cj] = f2bf(v);
            }
        }
    }
}

// ---------------------------------------------------------------------------
// MFMA GEMM (FFN1), v2: same 2-phase prefetch + XCD swizzle (grid 1024 1D).
// ---------------------------------------------------------------------------
template <int RELU>
__global__ __launch_bounds__(256) void gemm_mfma(const bf16* __restrict__ A,
                                                 const bf16* __restrict__ Wt,
                                                 const float* __restrict__ bias,
                                                 bf16* __restrict__ C,
                                                 int N, int K, int nbn) {
    __shared__ bf16 Als[2][128 * 64];
    __shared__ bf16 Bls[2][128 * 64];
    int tid = threadIdx.x;
    int wave = tid >> 6, lane = tid & 63;
    int id = blockIdx.x;
    int nwg = gridDim.x;
    int cpx = nwg >> 3;                       // nwg % 8 == 0
    int swz = (id & 7) * cpx + (id >> 3);
    int bm = (swz / nbn) * 128, bn = (swz % nbn) * 128;
    int wm = (wave >> 1) * 64, wn = (wave & 1) * 64;
    int l15 = lane & 15, g = lane >> 4;

    f32x4 acc[4][4] = {};

#define MF_STAGE(buf, k0)                                                       \
    {                                                                           \
        _Pragma("unroll")                                                       \
        for (int r = 0; r < 4; ++r) {                                           \
            int Lc = r * 256 + tid;                                             \
            int row = Lc >> 3, cs = Lc & 7;                                     \
            int gc = cs ^ (row & 7);                                            \
            async_cp16(A  + (size_t)(bm + row) * K + (k0) + gc * 8, &Als[buf][Lc * 8]); \
            async_cp16(Wt + (size_t)(bn + row) * K + (k0) + gc * 8, &Bls[buf][Lc * 8]); \
        }                                                                       \
    }

    int nt = K >> 6;
    MF_STAGE(0, 0);
    __syncthreads();
    int cur = 0;
    for (int t = 0; t < nt; ++t) {
        if (t < nt - 1) MF_STAGE(cur ^ 1, (t + 1) * 64);
#pragma unroll
        for (int ks = 0; ks < 2; ++ks) {
            bf16x8 af[4], bfr[4];
#pragma unroll
            for (int i = 0; i < 4; ++i) {
                int row = wm + i * 16 + l15;
                int c = ks * 4 + g;
                af[i] = *(bf16x8*)&Als[cur][row * 64 + ((c ^ (row & 7)) * 8)];
            }
#pragma unroll
            for (int j = 0; j < 4; ++j) {
                int row = wn + j * 16 + l15;
                int c = ks * 4 + g;
                bfr[j] = *(bf16x8*)&Bls[cur][row * 64 + ((c ^ (row & 7)) * 8)];
            }
#pragma unroll
            for (int i = 0; i < 4; ++i)
#pragma unroll
                for (int j = 0; j < 4; ++j)
                    acc[i][j] = __builtin_amdgcn_mfma_f32_16x16x32_bf16(af[i], bfr[j], acc[i][j], 0, 0, 0);
        }
        __syncthreads();
        cur ^= 1;
    }
#undef MF_STAGE

    int r4 = (lane >> 4) * 4;
#pragma unroll
    for (int i = 0; i < 4; ++i) {
#pragma unroll
        for (int j = 0; j < 4; ++j) {
            int col = bn + wn + j * 16 + l15;
            float bvv = bias[col];
#pragma unroll
            for (int r = 0; r < 4; ++r) {
                int row = bm + wm + i * 16 + r4 + r;
                float v = acc[i][j][r] + bvv;
                if (RELU) v = fmaxf(v, 0.f);
                C[(size_t)row * N + col] = f2bf(v);
            }
        }
    }
}

// ---------------------------------------------------------------------------
// Fused GEMM (N=256) + residual + LayerNorm epilogue (FFN2 path, R3 version)
// ---------------------------------------------------------------------------
__global__ __launch_bounds__(512) void gemm_ln(const bf16* __restrict__ A,
                                               const bf16* __restrict__ Wt,
                                               const float* __restrict__ bias,
                                               bf16* __restrict__ Xb,
                                               const float* __restrict__ g,
                                               const float* __restrict__ b,
                                               int K) {
    __shared__ __align__(16) char smem[128 * 260 * 2];  // 66560 B
    bf16* Als = (bf16*)smem;            // [128][64]  16 KB (during K loop)
    bf16* Bls = (bf16*)(smem + 16384);  // [256][64]  32 KB (during K loop)
    bf16* Cls = (bf16*)smem;            // [128][260] after K loop

    int tid = threadIdx.x;
    int wave = tid >> 6, lane = tid & 63;
    int bm = blockIdx.x * 128;
    int wm = (wave >> 2) * 64, wn = (wave & 3) * 64;
    int l15 = lane & 15, gg = lane >> 4;

    f32x4 acc[4][4] = {};

    for (int k0 = 0; k0 < K; k0 += 64) {
#pragma unroll
        for (int r = 0; r < 2; ++r) {   // A tile: 128x64
            int Lc = r * 512 + tid;
            int row = Lc >> 3, cs = Lc & 7;
            int gc = cs ^ (row & 7);
            async_cp16(A + (size_t)(bm + row) * K + k0 + gc * 8, &Als[Lc * 8]);
        }
#pragma unroll
        for (int r = 0; r < 4; ++r) {   // B tile: 256x64
            int Lc = r * 512 + tid;
            int row = Lc >> 3, cs = Lc & 7;
            int gc = cs ^ (row & 7);
            async_cp16(Wt + (size_t)row * K + k0 + gc * 8, &Bls[Lc * 8]);
        }
        __syncthreads();
#pragma unroll
        for (int ks = 0; ks < 2; ++ks) {
            bf16x8 af[4], bfr[4];
#pragma unroll
            for (int i = 0; i < 4; ++i) {
                int row = wm + i * 16 + l15;
                int c = ks * 4 + gg;
                af[i] = *(bf16x8*)&Als[row * 64 + ((c ^ (row & 7)) * 8)];
            }
#pragma unroll
            for (int j = 0; j < 4; ++j) {
                int row = wn + j * 16 + l15;
                int c = ks * 4 + gg;
                bfr[j] = *(bf16x8*)&Bls[row * 64 + ((c ^ (row & 7)) * 8)];
            }
#pragma unroll
            for (int i = 0; i < 4; ++i)
#pragma unroll
                for (int j = 0; j < 4; ++j)
                    acc[i][j] = __builtin_amdgcn_mfma_f32_16x16x32_bf16(af[i], bfr[j], acc[i][j], 0, 0, 0);
        }
        __syncthreads();
    }

    int r4 = (lane >> 4) * 4;
#pragma unroll
    for (int j = 0; j < 4; ++j) {
        int col = wn + j * 16 + l15;
        float bvv = bias[col];
#pragma unroll
        for (int i = 0; i < 4; ++i)
#pragma unroll
            for (int r = 0; r < 4; ++r)
                Cls[(wm + i * 16 + r4 + r) * 260 + col] = f2bf(acc[i][j][r] + bvv);
    }
    __syncthreads();

    int c4 = lane * 4;
    float4 gw = *(const float4*)&g[c4];
    float4 bw = *(const float4*)&b[c4];
#pragma unroll 2
    for (int rw = 0; rw < 16; ++rw) {
        int row = wave * 16 + rw;
        size_t gidx = (size_t)(bm + row) * 256 + c4;
        bf16x4 xb = *(const bf16x4*)(Xb + gidx);
        bf16x4 cb = *(const bf16x4*)&Cls[row * 260 + c4];
        float4 v;
        v.x = (float)xb[0] + (float)cb[0];
        v.y = (float)xb[1] + (float)cb[1];
        v.z = (float)xb[2] + (float)cb[2];
        v.w = (float)xb[3] + (float)cb[3];
        float s  = v.x + v.y + v.z + v.w;
        float sq = v.x * v.x + v.y * v.y + v.z * v.z + v.w * v.w;
#pragma unroll
        for (int off = 32; off > 0; off >>= 1) {
            s  += __shfl_xor(s,  off);
            sq += __shfl_xor(sq, off);
        }
        float mean = s * (1.f / 256.f);
        float var  = sq * (1.f / 256.f) - mean * mean;
        float rstd = rsqrtf(var + 1e-5f);
        bf16x4 ob;
        ob[0] = f2bf((v.x - mean) * rstd * gw.x + bw.x);
        ob[1] = f2bf((v.y - mean) * rstd * gw.y + bw.y);
        ob[2] = f2bf((v.z - mean) * rstd * gw.z + bw.z);
        ob[3] = f2bf((v.w - mean) * rstd * gw.w + bw.w);
        *(bf16x4*)(Xb + gidx) = ob;
    }
}

// ---------------------------------------------------------------------------
// Attention as a GEMM with in-kernel Z: Xb = LN(Xb + (Z.Q) @ Weff[n]^T + bo).
// Z prologue (replaces zcalc kernel): 4 threads/row, each owns 2 heads x 32
// contiguous cols; per-head dot vs Ksum with zcalc's EXACT pairwise tree
// ((p0+p1)+(p2+p3))+((p4+p5)+(p6+p7)) -> bit-identical Z. Stored in a 4KB
// LDS strip (time-shares Cls region; dead before Cls is written).
// ---------------------------------------------------------------------------
__global__ __launch_bounds__(512) void gemm_attn_ln(const bf16* __restrict__ A,
                                                    const float* __restrict__ Ksum,
                                                    const bf16* __restrict__ Weff,
                                                    const float* __restrict__ bias,
                                                    bf16* __restrict__ Xb,
                                                    const float* __restrict__ g,
                                                    const float* __restrict__ b) {
    __shared__ __align__(16) char smem[128 * 260 * 2];  // 66560 B
    bf16*  Als = (bf16*)smem;            // [128][64]
    bf16*  Bls = (bf16*)(smem + 16384);  // [256][64]
    float* Zs  = (float*)(smem + 49152); // [128][8] f32, K-loop lifetime
    bf16*  Cls = (bf16*)smem;            // [128][260] after K loop

    int tid = threadIdx.x;
    int wave = tid >> 6, lane = tid & 63;
    int bm = blockIdx.x * 128;
    int n = bm >> 12;
    const bf16* Wt = Weff + (size_t)n * 65536;   // per-batch

    // --- Z prologue: row = tid>>2, heads {2*(tid&3), 2*(tid&3)+1} ---
    {
        int row = tid >> 2, part = tid & 3;
        const bf16* qp = A + (size_t)(bm + row) * 256 + part * 64;
        const float* kp = Ksum + n * 256 + part * 64;
#pragma unroll
        for (int hh = 0; hh < 2; ++hh) {
            float p[8];
#pragma unroll
            for (int i = 0; i < 8; ++i) {
                bf16x4 q = *(const bf16x4*)(qp + hh * 32 + i * 4);
                float4 k = *(const float4*)(kp + hh * 32 + i * 4);
                p[i] = (float)q[0] * k.x + (float)q[1] * k.y
                     + (float)q[2] * k.z + (float)q[3] * k.w;
            }
            float z = ((p[0] + p[1]) + (p[2] + p[3])) + ((p[4] + p[5]) + (p[6] + p[7]));
            Zs[row * 8 + part * 2 + hh] = 1.f / (z + 1e-6f);
        }
    }
    __syncthreads();

    int wm = (wave >> 2) * 64, wn = (wave & 3) * 64;
    int l15 = lane & 15, gg = lane >> 4;

    f32x4 acc[4][4] = {};

    for (int k0 = 0; k0 < 256; k0 += 64) {
#pragma unroll
        for (int r = 0; r < 4; ++r) {   // B tile: 256x64 (async, overlaps A work)
            int Lc = r * 512 + tid;
            int row = Lc >> 3, cs = Lc & 7;
            int gc = cs ^ (row & 7);
            async_cp16(Wt + (size_t)row * 256 + k0 + gc * 8, &Bls[Lc * 8]);
        }
#pragma unroll
        for (int r = 0; r < 2; ++r) {   // A tile: 128x64, reg-staged with Z scale
            int Lc = r * 512 + tid;
            int row = Lc >> 3, cs = Lc & 7;
            int gc = cs ^ (row & 7);
            int gcol = k0 + gc * 8;
            bf16x8 q8 = *(const bf16x8*)(A + (size_t)(bm + row) * 256 + gcol);
            float z = Zs[row * 8 + (gcol >> 5)];
            bf16x8 a8;
#pragma unroll
            for (int u = 0; u < 8; ++u) a8[u] = f2bf((float)q8[u] * z);
            *(bf16x8*)&Als[Lc * 8] = a8;
        }
        __syncthreads();
#pragma unroll
        for (int ks = 0; ks < 2; ++ks) {
            bf16x8 af[4], bfr[4];
#pragma unroll
            for (int i = 0; i < 4; ++i) {
                int row = wm + i * 16 + l15;
                int c = ks * 4 + gg;
                af[i] = *(bf16x8*)&Als[row * 64 + ((c ^ (row & 7)) * 8)];
            }
#pragma unroll
            for (int j = 0; j < 4; ++j) {
                int row = wn + j * 16 + l15;
                int c = ks * 4 + gg;
                bfr[j] = *(bf16x8*)&Bls[row * 64 + ((c ^ (row & 7)) * 8)];
            }
#pragma unroll
            for (int i = 0; i < 4; ++i)
#pragma unroll
                for (int j = 0; j < 4; ++j)
                    acc[i][j] = __builtin_amdgcn_mfma_f32_16x16x32_bf16(af[i], bfr[j], acc[i][j], 0, 0, 0);
        }
        __syncthreads();
    }

    int r4 = (lane >> 4) * 4;
#pragma unroll
    for (int j = 0; j < 4; ++j) {
        int col = wn + j * 16 + l15;
        float bvv = bias[col];
#pragma unroll
        for (int i = 0; i < 4; ++i)
#pragma unroll
            for (int r = 0; r < 4; ++r)
                Cls[(wm + i * 16 + r4 + r) * 260 + col] = f2bf(acc[i][j][r] + bvv);
    }
    __syncthreads();

    int c4 = lane * 4;
    float4 gw = *(const float4*)&g[c4];
    float4 bw = *(const float4*)&b[c4];
#pragma unroll 2
    for (int rw = 0; rw < 16; ++rw) {
        int row = wave * 16 + rw;
        size_t gidx = (size_t)(bm + row) * 256 + c4;
        bf16x4 xb = *(const bf16x4*)(Xb + gidx);
        bf16x4 cb = *(const bf16x4*)&Cls[row * 260 + c4];
        float4 v;
        v.x = (float)xb[0] + (float)cb[0];
        v.y = (float)xb[1] + (float)cb[1];
        v.z = (float)xb[2] + (float)cb[2];
        v.w = (float)xb[3] + (float)cb[3];
        float s  = v.x + v.y + v.z + v.w;
        float sq = v.x * v.x + v.y * v.y + v.z * v.z + v.w * v.w;
#pragma unroll
        for (int off = 32; off > 0; off >>= 1) {
            s  += __shfl_xor(s,  off);
            sq += __shfl_xor(sq, off);
        }
        float mean = s * (1.f / 256.f);
        float var  = sq * (1.f / 256.f) - mean * mean;
        float rstd = rsqrtf(var + 1e-5f);
        bf16x4 ob;
        ob[0] = f2bf((v.x - mean) * rstd * gw.x + bw.x);
        ob[1] = f2bf((v.y - mean) * rstd * gw.y + bw.y);
        ob[2] = f2bf((v.z - mean) * rstd * gw.z + bw.z);
        ob[3] = f2bf((v.w - mean) * rstd * gw.w + bw.w);
        *(bf16x4*)(Xb + gidx) = ob;
    }
}

// ---------------------------------------------------------------------------
// KV prep: grid (32 sp, 64 nh), 256 thr = 4 waves.
// ---------------------------------------------------------------------------
__global__ __launch_bounds__(256) void kv_prep_part(const bf16* __restrict__ Kb,
                                                    const bf16* __restrict__ Vb,
                                                    float* __restrict__ Pkv,
                                                    float* __restrict__ Pks) {
    __shared__ float Ks[128][32];
    __shared__ float Vs[128][32];
    int sp = blockIdx.x;
    int nh = blockIdx.y;
    int n = nh >> 3, h = nh & 7;
    int tid = threadIdx.x;
    int wave = tid >> 6, lane = tid & 63;
    int mg = lane >> 3;
    int dg = lane & 7;
    size_t base = ((size_t)n * 4096 + sp * 128) * 256 + h * 32;

#pragma unroll
    for (int p = 0; p < 2; ++p) {
        int r = p * 64 + (tid >> 2);
        int c = (tid & 3) * 8;
        bf16x8 k8 = *(const bf16x8*)(Kb + base + (size_t)r * 256 + c);
        bf16x8 v8 = *(const bf16x8*)(Vb + base + (size_t)r * 256 + c);
#pragma unroll
        for (int u = 0; u < 8; ++u) { Ks[r][c + u] = (float)k8[u]; Vs[r][c + u] = (float)v8[u]; }
    }
    __syncthreads();

    float acc[4][4] = {};
    float ks4[4] = {};
    int s0 = wave * 32;
    for (int s = s0; s < s0 + 32; ++s) {
        float4 kq = *(float4*)&Ks[s][dg * 4];
        float4 vq = *(float4*)&Vs[s][mg * 4];
        ks4[0] += kq.x; ks4[1] += kq.y; ks4[2] += kq.z; ks4[3] += kq.w;
        acc[0][0] += vq.x * kq.x; acc[0][1] += vq.x * kq.y; acc[0][2] += vq.x * kq.z; acc[0][3] += vq.x * kq.w;
        acc[1][0] += vq.y * kq.x; acc[1][1] += vq.y * kq.y; acc[1][2] += vq.y * kq.z; acc[1][3] += vq.y * kq.w;
        acc[2][0] += vq.z * kq.x; acc[2][1] += vq.z * kq.y; acc[2][2] += vq.z * kq.z; acc[2][3] += vq.z * kq.w;
        acc[3][0] += vq.w * kq.x; acc[3][1] += vq.w * kq.y; acc[3][2] += vq.w * kq.z; acc[3][3] += vq.w * kq.w;
    }
    __syncthreads();

    float* R  = &Ks[0][0];
    float* RS = &Vs[0][0];
#pragma unroll
    for (int mi = 0; mi < 4; ++mi)
#pragma unroll
        for (int dj = 0; dj < 4; ++dj)
            R[wave * 1024 + (mg * 4 + mi) * 32 + dg * 4 + dj] = acc[mi][dj];
    if (mg == 0)
#pragma unroll
        for (int dj = 0; dj < 4; ++dj) RS[wave * 32 + dg * 4 + dj] = ks4[dj];
    __syncthreads();

    int e = tid * 4;
    float4 o0 = *(float4*)&R[e];
    float4 o1 = *(float4*)&R[1024 + e];
    float4 o2 = *(float4*)&R[2048 + e];
    float4 o3 = *(float4*)&R[3072 + e];
    float4 o = make_float4(o0.x + o1.x + o2.x + o3.x, o0.y + o1.y + o2.y + o3.y,
                           o0.z + o1.z + o2.z + o3.z, o0.w + o1.w + o2.w + o3.w);
    *(float4*)&Pkv[((size_t)nh * 32 + sp) * 1024 + e] = o;
    if (tid < 32)
        Pks[((size_t)nh * 32 + sp) * 32 + tid] = RS[tid] + RS[32 + tid] + RS[64 + tid] + RS[96 + tid];
}

// grid (64 nh, 4 quarters), 64 threads (1 wave).
__global__ __launch_bounds__(64) void kv_reduce(const float* __restrict__ Pkv,
                                                const float* __restrict__ Pks,
                                                float* __restrict__ KV,
                                                float* __restrict__ Ksum) {
    int nh = blockIdx.x;
    int q = blockIdx.y;
    int e = (q * 64 + threadIdx.x) * 4;
    float4 s = make_float4(0.f, 0.f, 0.f, 0.f);
    for (int sp = 0; sp < 32; ++sp) {
        float4 p = *(const float4*)&Pkv[((size_t)nh * 32 + sp) * 1024 + e];
        s.x += p.x; s.y += p.y; s.z += p.z; s.w += p.w;
    }
    *(float4*)&KV[(size_t)nh * 1024 + e] = s;
    if (q == 0 && threadIdx.x < 32) {
        float ss = 0.f;
        for (int sp = 0; sp < 32; ++sp) ss += Pks[((size_t)nh * 32 + sp) * 32 + threadIdx.x];
        Ksum[nh * 32 + threadIdx.x] = ss;
    }
}

// ---------------------------------------------------------------------------
// Weff[n][c][h*32+d] = sum_m KV[n,h,m,d] * Wo[(h,m),c]   (bf16, Wt layout)
// ---------------------------------------------------------------------------
__global__ __launch_bounds__(256) void weff_kernel(const float* __restrict__ KV,
                                                   const bf16* __restrict__ WtO,
                                                   bf16* __restrict__ Weff) {
    __shared__ float KVs[8][1024];   // [h][m*32+d]
    int n = blockIdx.y, c0 = blockIdx.x * 64;
    int tid = threadIdx.x;
    const float* src = KV + (size_t)n * 8192;
    for (int i = tid; i < 2048; i += 256)
        *(float4*)&((float*)KVs)[i * 4] = *(const float4*)&src[i * 4];
    __syncthreads();

    int c = c0 + (tid & 63);
    int hb = tid >> 6;               // wave id: h in {2hb, 2hb+1}
    const bf16* wrow = WtO + (size_t)c * 256 + hb * 64;
    bf16* dst = Weff + (size_t)n * 65536 + (size_t)c * 256 + hb * 64;

#pragma unroll
    for (int hh = 0; hh < 2; ++hh) {
        int h = hb * 2 + hh;
        float wo[32];
#pragma unroll
        for (int u = 0; u < 4; ++u) {
            bf16x8 w8 = *(const bf16x8*)(wrow + hh * 32 + u * 8);
#pragma unroll
            for (int v = 0; v < 8; ++v) wo[u * 8 + v] = (float)w8[v];
        }
        float s[32] = {};
        for (int m = 0; m < 32; ++m) {
            float wm = wo[m];
#pragma unroll
            for (int d4 = 0; d4 < 8; ++d4) {
                float4 kv4 = *(float4*)&KVs[h][m * 32 + d4 * 4];
                s[d4 * 4 + 0] += wm * kv4.x;
                s[d4 * 4 + 1] += wm * kv4.y;
                s[d4 * 4 + 2] += wm * kv4.z;
                s[d4 * 4 + 3] += wm * kv4.w;
            }
        }
#pragma unroll
        for (int u = 0; u < 4; ++u) {
            bf16x8 o8;
#pragma unroll
            for (int v = 0; v < 8; ++v) o8[v] = f2bf(s[u * 8 + v]);
            *(bf16x8*)(dst + hh * 32 + u * 8) = o8;
        }
    }
}

// ---------------------------------------------------------------------------
// Store: Xb[b,t,c] bf16 -> out[b,c,t] f32
// ---------------------------------------------------------------------------
__global__ __launch_bounds__(1024) void store_kernel(const bf16* __restrict__ Xb,
                                                     float* __restrict__ out) {
    __shared__ float tile[32][33];
    int b = blockIdx.z;
    int t0 = blockIdx.x * 32, c0 = blockIdx.y * 32;
    tile[threadIdx.y][threadIdx.x] =
        (float)Xb[((size_t)b * 4096 + t0 + threadIdx.y) * 256 + c0 + threadIdx.x];
    __syncthreads();
    out[((size_t)b * 256 + c0 + threadIdx.y) * 4096 + t0 + threadIdx.x] =
        tile[threadIdx.x][threadIdx.y];
}

// ---------------------------------------------------------------------------
extern "C" void kernel_launch(void* const* d_in, const int* in_sizes, int n_in,
                              void* d_out, int out_size, void* d_ws, size_t ws_size,
                              hipStream_t stream) {
    const float* ref  = (const float*)d_in[0];
    const float* srcf = (const float*)d_in[1];
    const float* Wq = (const float*)d_in[2];
    const float* bq = (const float*)d_in[3];
    const float* Wk = (const float*)d_in[4];
    const float* bk = (const float*)d_in[5];
    const float* Wv = (const float*)d_in[6];
    const float* bv = (const float*)d_in[7];
    const float* Wo = (const float*)d_in[8];
    const float* bo = (const float*)d_in[9];
    const float* W1 = (const float*)d_in[10];
    const float* b1 = (const float*)d_in[11];
    const float* W2 = (const float*)d_in[12];
    const float* b2 = (const float*)d_in[13];
    const float* g1 = (const float*)d_in[14];
    const float* be1 = (const float*)d_in[15];
    const float* g2 = (const float*)d_in[16];
    const float* be2 = (const float*)d_in[17];

    const size_t SZ = (size_t)8 * 4096 * 256;
    float* ws  = (float*)d_ws;
    float* KVb = ws;                          // 65536 f32
    float* Ksb = KVb + 65536;                 // 2048 f32
    float* Pkv = Ksb + 2048;                  // 2,097,152 f32
    float* Pks = Pkv + 2097152;               // 65536 f32
    bf16*  Wt  = (bf16*)(Pks + 65536);        // 2,097,152 bf16
    bf16*  Xb  = Wt + 2097152;                // SZ bf16 (residual stream)
    bf16*  P2b = Xb + SZ;                     // SZ bf16
    bf16*  Qb  = P2b + SZ;                    // SZ bf16
    // Weff (1 MB bf16) aliases the Pkv head (written after kv_reduce reads Pkv).
    bf16*  Weffb = (bf16*)Pkv;                // 524288 bf16 = 1 MB
    // K/V live in d_out (exact 2*SZ bf16 fit); dead before store_kernel runs.
    bf16*  Kb  = (bf16*)d_out;
    bf16*  Vb  = Kb + SZ;
    bf16*  Hb  = Kb;                          // alias: FFN hidden spans Kb+Vb

    wt_conv<<<dim3(16, 16, 24), dim3(32, 32), 0, stream>>>(Wq, Wk, Wv, Wo, W1, W2, Wt);
    encode_kernel<<<dim3(128, 8, 8), dim3(32, 32), 0, stream>>>(ref, srcf, Xb, P2b);

    for (int L = 0; L < 4; ++L) {
        const bf16* WtL = Wt + (size_t)L * 524288;
        const bf16* Akv = (L & 1) ? P2b : Xb;
        gemm_qkv<<<1536, 256, 0, stream>>>(Xb, Akv, WtL,
                                           bq + L * 256, bk + L * 256, bv + L * 256,
                                           Qb, Kb, Vb);
        kv_prep_part<<<dim3(32, 64), 256, 0, stream>>>(Kb, Vb, Pkv, Pks);
        kv_reduce<<<dim3(64, 4), 64, 0, stream>>>(Pkv, Pks, KVb, Ksb);
        weff_kernel<<<dim3(4, 8), 256, 0, stream>>>(KVb, WtL + 196608, Weffb);
        // attention + O-proj + residual + LN1 as one GEMM, Z computed in-kernel
        gemm_attn_ln<<<256, 512, 0, stream>>>(Qb, Ksb, Weffb, bo + L * 256, Xb,
                                              g1 + L * 256, be1 + L * 256);
        // FFN1 (relu) -> Hb
        gemm_mfma<1><<<1024, 256, 0, stream>>>(Xb, WtL + 262144, b1 + L * 512, Hb, 512, 256, 4);
        // FFN2 + residual + LN2 fused
        gemm_ln<<<256, 512, 0, stream>>>(Hb, WtL + 393216, b2 + L * 256, Xb,
                                         g2 + L * 256, be2 + L * 256, 512);
    }

    store_kernel<<<dim3(128, 8, 8), dim3(32, 32), 0, stream>>>(Xb, (float*)d_out);
}

// Round 10
// 647.570 us; speedup vs baseline: 1.1521x; 1.0274x over previous
//
#include <hip/hip_runtime.h>
#include <hip/hip_bf16.h>

typedef __bf16 bf16;
typedef __attribute__((ext_vector_type(8))) __bf16 bf16x8;
typedef __attribute__((ext_vector_type(4))) __bf16 bf16x4;
typedef __attribute__((ext_vector_type(4))) float f32x4;

__device__ __forceinline__ bf16 f2bf(float f) { return (bf16)f; }

// async global->LDS, 16B per lane. LDS dest must be uniform-base + lane*16.
__device__ __forceinline__ void async_cp16(const void* g, void* l) {
    __builtin_amdgcn_global_load_lds(
        (const __attribute__((address_space(1))) unsigned int*)g,
        (__attribute__((address_space(3))) unsigned int*)l, 16, 0, 0);
}

// ---------------------------------------------------------------------------
// Positional encoding value for channel c, token t (t = h*64 + w)
// ---------------------------------------------------------------------------
__device__ __forceinline__ float pe_val(int c, int t) {
    int h = t >> 6, w = t & 63;
    int i = c >> 2, j = c & 3;
    float div = expf(-0.14391156831212787f * (float)i);
    float arg = ((j < 2) ? (float)w : (float)h) * div;
    return (j & 1) ? cosf(arg) : sinf(arg);
}

// ---------------------------------------------------------------------------
// Encode: feat (4,256,4096) f32 -> Xb[b,t,c] bf16, P2b bf16 (PE added).
// ---------------------------------------------------------------------------
__global__ __launch_bounds__(1024) void encode_kernel(const float* __restrict__ ref,
                                                      const float* __restrict__ src,
                                                      bf16* __restrict__ Xb,
                                                      bf16* __restrict__ P2b) {
    __shared__ float tile[32][33];
    int n = blockIdx.z >> 1, sel = blockIdx.z & 1;
    const float* f = sel ? src : ref;
    int t = blockIdx.x * 32 + threadIdx.x;
    int c = blockIdx.y * 32 + threadIdx.y;
    float v = f[((size_t)n * 256 + c) * 4096 + t] + pe_val(c, t);
    tile[threadIdx.y][threadIdx.x] = v;
    __syncthreads();
    int tt = blockIdx.x * 32 + threadIdx.y;
    int cc = blockIdx.y * 32 + threadIdx.x;
    float o = tile[threadIdx.x][threadIdx.y];
    int bx = sel ? 4 + n : n;
    int bp = sel ? n : 4 + n;
    Xb [((size_t)bx * 4096 + tt) * 256 + cc] = f2bf(o);
    P2b[((size_t)bp * 4096 + tt) * 256 + cc] = f2bf(o);
}

// ---------------------------------------------------------------------------
// Weight transpose+convert: W[K,N] f32 -> Wt[N,K] bf16, all 24 mats, 1 launch
// ---------------------------------------------------------------------------
__global__ __launch_bounds__(1024) void wt_conv(const float* __restrict__ Wq, const float* __restrict__ Wk,
                                                const float* __restrict__ Wv, const float* __restrict__ Wo,
                                                const float* __restrict__ W1, const float* __restrict__ W2,
                                                bf16* __restrict__ Wt) {
    __shared__ float t[32][33];
    int z = blockIdx.z, L = z / 6, m = z - L * 6;
    const float* src; int K, N, doff;
    if      (m == 0) { src = Wq + L * 65536;  K = 256; N = 256; doff = 0; }
    else if (m == 1) { src = Wk + L * 65536;  K = 256; N = 256; doff = 65536; }
    else if (m == 2) { src = Wv + L * 65536;  K = 256; N = 256; doff = 131072; }
    else if (m == 3) { src = Wo + L * 65536;  K = 256; N = 256; doff = 196608; }
    else if (m == 4) { src = W1 + L * 131072; K = 256; N = 512; doff = 262144; }
    else             { src = W2 + L * 131072; K = 512; N = 256; doff = 393216; }
    int n0 = blockIdx.x * 32, k0 = blockIdx.y * 32;
    if (n0 >= N || k0 >= K) return;
    t[threadIdx.y][threadIdx.x] = src[(size_t)(k0 + threadIdx.y) * N + n0 + threadIdx.x];
    __syncthreads();
    bf16* dst = Wt + (size_t)L * 524288 + doff;
    dst[(size_t)(n0 + threadIdx.y) * K + k0 + threadIdx.x] = f2bf(t[threadIdx.x][threadIdx.y]);
}

// ---------------------------------------------------------------------------
// Fused QKV GEMM, v2: 2-phase prefetch double-buffer + XCD-chunked swizzle.
// (R8 version, verified <41us vs 54.7 for single-buffer)
// ---------------------------------------------------------------------------
__global__ __launch_bounds__(256) void gemm_qkv(const bf16* __restrict__ Aq,
                                                const bf16* __restrict__ Akv,
                                                const bf16* __restrict__ Wt,
                                                const float* __restrict__ bq,
                                                const float* __restrict__ bk,
                                                const float* __restrict__ bv,
                                                bf16* __restrict__ Q,
                                                bf16* __restrict__ Ko,
                                                bf16* __restrict__ V) {
    __shared__ bf16 Als[2][128 * 64];
    __shared__ bf16 Bls[2][128 * 64];
    int tid = threadIdx.x;
    int wave = tid >> 6, lane = tid & 63;
    int id = blockIdx.x;
    int swz = (id & 7) * 192 + (id >> 3);     // XCD chunk, nwg=1536
    int bm = (swz / 6) * 128, bn = (swz % 6) * 128;
    int wm = (wave >> 1) * 64, wn = (wave & 1) * 64;
    int l15 = lane & 15, g = lane >> 4;
    const int K = 256;

    int seg = bn >> 8, cloc = bn & 255;
    const bf16* A = seg == 0 ? Aq : Akv;
    const float* bias = seg == 0 ? bq : (seg == 1 ? bk : bv);
    bf16* Out = seg == 0 ? Q : (seg == 1 ? Ko : V);
    bool do_elu = seg < 2;

    f32x4 acc[4][4] = {};

#define QKV_STAGE(buf, k0)                                                      \
    {                                                                           \
        _Pragma("unroll")                                                       \
        for (int r = 0; r < 4; ++r) {                                           \
            int Lc = r * 256 + tid;                                             \
            int row = Lc >> 3, cs = Lc & 7;                                     \
            int gc = cs ^ (row & 7);                                            \
            async_cp16(A  + (size_t)(bm + row) * K + (k0) + gc * 8, &Als[buf][Lc * 8]); \
            async_cp16(Wt + (size_t)(bn + row) * K + (k0) + gc * 8, &Bls[buf][Lc * 8]); \
        }                                                                       \
    }

    QKV_STAGE(0, 0);
    __syncthreads();
    int cur = 0;
    for (int t = 0; t < 4; ++t) {
        if (t < 3) QKV_STAGE(cur ^ 1, (t + 1) * 64);
#pragma unroll
        for (int ks = 0; ks < 2; ++ks) {
            bf16x8 af[4], bfr[4];
#pragma unroll
            for (int i = 0; i < 4; ++i) {
                int row = wm + i * 16 + l15;
                int c = ks * 4 + g;
                af[i] = *(bf16x8*)&Als[cur][row * 64 + ((c ^ (row & 7)) * 8)];
            }
#pragma unroll
            for (int j = 0; j < 4; ++j) {
                int row = wn + j * 16 + l15;
                int c = ks * 4 + g;
                bfr[j] = *(bf16x8*)&Bls[cur][row * 64 + ((c ^ (row & 7)) * 8)];
            }
#pragma unroll
            for (int i = 0; i < 4; ++i)
#pragma unroll
                for (int j = 0; j < 4; ++j)
                    acc[i][j] = __builtin_amdgcn_mfma_f32_16x16x32_bf16(af[i], bfr[j], acc[i][j], 0, 0, 0);
        }
        __syncthreads();
        cur ^= 1;
    }
#undef QKV_STAGE

    int r4 = (lane >> 4) * 4;
#pragma unroll
    for (int i = 0; i < 4; ++i) {
#pragma unroll
        for (int j = 0; j < 4; ++j) {
            int cj = cloc + wn + j * 16 + l15;
            float bvv = bias[cj];
#pragma unroll
            for (int r = 0; r < 4; ++r) {
                int row = bm + wm + i * 16 + r4 + r;
                float v = acc[i][j][r] + bvv;
                if (do_elu) v = v > 0.f ? v + 1.f : expf(v);
                Out[(size_t)row * 256 + cj] = f2bf(v);
            }
        }
    }
}

// ---------------------------------------------------------------------------
// MFMA GEMM (FFN1), v2: same 2-phase prefetch + XCD swizzle (grid 1024 1D).
// ---------------------------------------------------------------------------
template <int RELU>
__global__ __launch_bounds__(256) void gemm_mfma(const bf16* __restrict__ A,
                                                 const bf16* __restrict__ Wt,
                                                 const float* __restrict__ bias,
                                                 bf16* __restrict__ C,
                                                 int N, int K, int nbn) {
    __shared__ bf16 Als[2][128 * 64];
    __shared__ bf16 Bls[2][128 * 64];
    int tid = threadIdx.x;
    int wave = tid >> 6, lane = tid & 63;
    int id = blockIdx.x;
    int nwg = gridDim.x;
    int cpx = nwg >> 3;                       // nwg % 8 == 0
    int swz = (id & 7) * cpx + (id >> 3);
    int bm = (swz / nbn) * 128, bn = (swz % nbn) * 128;
    int wm = (wave >> 1) * 64, wn = (wave & 1) * 64;
    int l15 = lane & 15, g = lane >> 4;

    f32x4 acc[4][4] = {};

#define MF_STAGE(buf, k0)                                                       \
    {                                                                           \
        _Pragma("unroll")                                                       \
        for (int r = 0; r < 4; ++r) {                                           \
            int Lc = r * 256 + tid;                                             \
            int row = Lc >> 3, cs = Lc & 7;                                     \
            int gc = cs ^ (row & 7);                                            \
            async_cp16(A  + (size_t)(bm + row) * K + (k0) + gc * 8, &Als[buf][Lc * 8]); \
            async_cp16(Wt + (size_t)(bn + row) * K + (k0) + gc * 8, &Bls[buf][Lc * 8]); \
        }                                                                       \
    }

    int nt = K >> 6;
    MF_STAGE(0, 0);
    __syncthreads();
    int cur = 0;
    for (int t = 0; t < nt; ++t) {
        if (t < nt - 1) MF_STAGE(cur ^ 1, (t + 1) * 64);
#pragma unroll
        for (int ks = 0; ks < 2; ++ks) {
            bf16x8 af[4], bfr[4];
#pragma unroll
            for (int i = 0; i < 4; ++i) {
                int row = wm + i * 16 + l15;
                int c = ks * 4 + g;
                af[i] = *(bf16x8*)&Als[cur][row * 64 + ((c ^ (row & 7)) * 8)];
            }
#pragma unroll
            for (int j = 0; j < 4; ++j) {
                int row = wn + j * 16 + l15;
                int c = ks * 4 + g;
                bfr[j] = *(bf16x8*)&Bls[cur][row * 64 + ((c ^ (row & 7)) * 8)];
            }
#pragma unroll
            for (int i = 0; i < 4; ++i)
#pragma unroll
                for (int j = 0; j < 4; ++j)
                    acc[i][j] = __builtin_amdgcn_mfma_f32_16x16x32_bf16(af[i], bfr[j], acc[i][j], 0, 0, 0);
        }
        __syncthreads();
        cur ^= 1;
    }
#undef MF_STAGE

    int r4 = (lane >> 4) * 4;
#pragma unroll
    for (int i = 0; i < 4; ++i) {
#pragma unroll
        for (int j = 0; j < 4; ++j) {
            int col = bn + wn + j * 16 + l15;
            float bvv = bias[col];
#pragma unroll
            for (int r = 0; r < 4; ++r) {
                int row = bm + wm + i * 16 + r4 + r;
                float v = acc[i][j][r] + bvv;
                if (RELU) v = fmaxf(v, 0.f);
                C[(size_t)row * N + col] = f2bf(v);
            }
        }
    }
}

// ---------------------------------------------------------------------------
// Fused GEMM (N=256) + residual + LN epilogue (FFN2), v2: 2-phase prefetch.
// Grid 256 = 1 block/CU -> doubling staging LDS (96 KB) costs no occupancy.
// Math identical to R9 gemm_ln.
// ---------------------------------------------------------------------------
__global__ __launch_bounds__(512) void gemm_ln(const bf16* __restrict__ A,
                                               const bf16* __restrict__ Wt,
                                               const float* __restrict__ bias,
                                               bf16* __restrict__ Xb,
                                               const float* __restrict__ g,
                                               const float* __restrict__ b,
                                               int K) {
    __shared__ __align__(16) char smem[98304];   // Als[2]:0..32K, Bls[2]:32K..96K
    bf16* Cls = (bf16*)smem;                     // [128][260] after K loop

    int tid = threadIdx.x;
    int wave = tid >> 6, lane = tid & 63;
    int bm = blockIdx.x * 128;
    int wm = (wave >> 2) * 64, wn = (wave & 3) * 64;
    int l15 = lane & 15, gg = lane >> 4;

    f32x4 acc[4][4] = {};

#define LN_ALS(buf) ((bf16*)(smem + (buf) * 16384))
#define LN_BLS(buf) ((bf16*)(smem + 32768 + (buf) * 32768))
#define LN_STAGE(buf, k0)                                                       \
    {                                                                           \
        _Pragma("unroll")                                                       \
        for (int r = 0; r < 2; ++r) {                                           \
            int Lc = r * 512 + tid;                                             \
            int row = Lc >> 3, cs = Lc & 7;                                     \
            int gc = cs ^ (row & 7);                                            \
            async_cp16(A + (size_t)(bm + row) * K + (k0) + gc * 8, &LN_ALS(buf)[Lc * 8]); \
        }                                                                       \
        _Pragma("unroll")                                                       \
        for (int r = 0; r < 4; ++r) {                                           \
            int Lc = r * 512 + tid;                                             \
            int row = Lc >> 3, cs = Lc & 7;                                     \
            int gc = cs ^ (row & 7);                                            \
            async_cp16(Wt + (size_t)row * K + (k0) + gc * 8, &LN_BLS(buf)[Lc * 8]); \
        }                                                                       \
    }

    int nt = K >> 6;
    LN_STAGE(0, 0);
    __syncthreads();
    int cur = 0;
    for (int t = 0; t < nt; ++t) {
        if (t < nt - 1) LN_STAGE(cur ^ 1, (t + 1) * 64);
        const bf16* Als = LN_ALS(cur);
        const bf16* Bls = LN_BLS(cur);
#pragma unroll
        for (int ks = 0; ks < 2; ++ks) {
            bf16x8 af[4], bfr[4];
#pragma unroll
            for (int i = 0; i < 4; ++i) {
                int row = wm + i * 16 + l15;
                int c = ks * 4 + gg;
                af[i] = *(bf16x8*)&Als[row * 64 + ((c ^ (row & 7)) * 8)];
            }
#pragma unroll
            for (int j = 0; j < 4; ++j) {
                int row = wn + j * 16 + l15;
                int c = ks * 4 + gg;
                bfr[j] = *(bf16x8*)&Bls[row * 64 + ((c ^ (row & 7)) * 8)];
            }
#pragma unroll
            for (int i = 0; i < 4; ++i)
#pragma unroll
                for (int j = 0; j < 4; ++j)
                    acc[i][j] = __builtin_amdgcn_mfma_f32_16x16x32_bf16(af[i], bfr[j], acc[i][j], 0, 0, 0);
        }
        __syncthreads();
        cur ^= 1;
    }
#undef LN_STAGE
#undef LN_ALS
#undef LN_BLS

    int r4 = (lane >> 4) * 4;
#pragma unroll
    for (int j = 0; j < 4; ++j) {
        int col = wn + j * 16 + l15;
        float bvv = bias[col];
#pragma unroll
        for (int i = 0; i < 4; ++i)
#pragma unroll
            for (int r = 0; r < 4; ++r)
                Cls[(wm + i * 16 + r4 + r) * 260 + col] = f2bf(acc[i][j][r] + bvv);
    }
    __syncthreads();

    int c4 = lane * 4;
    float4 gw = *(const float4*)&g[c4];
    float4 bw = *(const float4*)&b[c4];
#pragma unroll 2
    for (int rw = 0; rw < 16; ++rw) {
        int row = wave * 16 + rw;
        size_t gidx = (size_t)(bm + row) * 256 + c4;
        bf16x4 xb = *(const bf16x4*)(Xb + gidx);
        bf16x4 cb = *(const bf16x4*)&Cls[row * 260 + c4];
        float4 v;
        v.x = (float)xb[0] + (float)cb[0];
        v.y = (float)xb[1] + (float)cb[1];
        v.z = (float)xb[2] + (float)cb[2];
        v.w = (float)xb[3] + (float)cb[3];
        float s  = v.x + v.y + v.z + v.w;
        float sq = v.x * v.x + v.y * v.y + v.z * v.z + v.w * v.w;
#pragma unroll
        for (int off = 32; off > 0; off >>= 1) {
            s  += __shfl_xor(s,  off);
            sq += __shfl_xor(sq, off);
        }
        float mean = s * (1.f / 256.f);
        float var  = sq * (1.f / 256.f) - mean * mean;
        float rstd = rsqrtf(var + 1e-5f);
        bf16x4 ob;
        ob[0] = f2bf((v.x - mean) * rstd * gw.x + bw.x);
        ob[1] = f2bf((v.y - mean) * rstd * gw.y + bw.y);
        ob[2] = f2bf((v.z - mean) * rstd * gw.z + bw.z);
        ob[3] = f2bf((v.w - mean) * rstd * gw.w + bw.w);
        *(bf16x4*)(Xb + gidx) = ob;
    }
}

// ---------------------------------------------------------------------------
// Attention GEMM with in-kernel Z, v2: 2-phase prefetch double-buffer.
// A reg-stage of tile t+1 (ds_write to alt buffer) overlaps tile t's MFMA;
// one barrier per K-step. Grid 256 = 1 block/CU -> 100 KB pool is free.
// Z prologue and all math identical to R9.
// ---------------------------------------------------------------------------
__global__ __launch_bounds__(512) void gemm_attn_ln(const bf16* __restrict__ A,
                                                    const float* __restrict__ Ksum,
                                                    const bf16* __restrict__ Weff,
                                                    const float* __restrict__ bias,
                                                    bf16* __restrict__ Xb,
                                                    const float* __restrict__ g,
                                                    const float* __restrict__ b) {
    __shared__ __align__(16) char smem[102400];  // Als[2]:0..32K, Bls[2]:32K..96K, Zs:96K..100K
    bf16*  Cls = (bf16*)smem;                    // [128][260] after K loop
    float* Zs  = (float*)(smem + 98304);         // [128][8] f32

    int tid = threadIdx.x;
    int wave = tid >> 6, lane = tid & 63;
    int bm = blockIdx.x * 128;
    int n = bm >> 12;
    const bf16* Wt = Weff + (size_t)n * 65536;   // per-batch

    // --- Z prologue: row = tid>>2, heads {2*(tid&3), 2*(tid&3)+1} ---
    {
        int row = tid >> 2, part = tid & 3;
        const bf16* qp = A + (size_t)(bm + row) * 256 + part * 64;
        const float* kp = Ksum + n * 256 + part * 64;
#pragma unroll
        for (int hh = 0; hh < 2; ++hh) {
            float p[8];
#pragma unroll
            for (int i = 0; i < 8; ++i) {
                bf16x4 q = *(const bf16x4*)(qp + hh * 32 + i * 4);
                float4 k = *(const float4*)(kp + hh * 32 + i * 4);
                p[i] = (float)q[0] * k.x + (float)q[1] * k.y
                     + (float)q[2] * k.z + (float)q[3] * k.w;
            }
            float z = ((p[0] + p[1]) + (p[2] + p[3])) + ((p[4] + p[5]) + (p[6] + p[7]));
            Zs[row * 8 + part * 2 + hh] = 1.f / (z + 1e-6f);
        }
    }
    __syncthreads();

    int wm = (wave >> 2) * 64, wn = (wave & 3) * 64;
    int l15 = lane & 15, gg = lane >> 4;

    f32x4 acc[4][4] = {};

#define AT_ALS(buf) ((bf16*)(smem + (buf) * 16384))
#define AT_BLS(buf) ((bf16*)(smem + 32768 + (buf) * 32768))
#define AT_STAGE(buf, k0)                                                       \
    {                                                                           \
        _Pragma("unroll")                                                       \
        for (int r = 0; r < 4; ++r) {                                           \
            int Lc = r * 512 + tid;                                             \
            int row = Lc >> 3, cs = Lc & 7;                                     \
            int gc = cs ^ (row & 7);                                            \
            async_cp16(Wt + (size_t)row * 256 + (k0) + gc * 8, &AT_BLS(buf)[Lc * 8]); \
        }                                                                       \
        _Pragma("unroll")                                                       \
        for (int r = 0; r < 2; ++r) {                                           \
            int Lc = r * 512 + tid;                                             \
            int row = Lc >> 3, cs = Lc & 7;                                     \
            int gc = cs ^ (row & 7);                                            \
            int gcol = (k0) + gc * 8;                                           \
            bf16x8 q8 = *(const bf16x8*)(A + (size_t)(bm + row) * 256 + gcol);  \
            float z = Zs[row * 8 + (gcol >> 5)];                                \
            bf16x8 a8;                                                          \
            _Pragma("unroll")                                                   \
            for (int u = 0; u < 8; ++u) a8[u] = f2bf((float)q8[u] * z);         \
            *(bf16x8*)&AT_ALS(buf)[Lc * 8] = a8;                                \
        }                                                                       \
    }

    AT_STAGE(0, 0);
    __syncthreads();
    int cur = 0;
    for (int t = 0; t < 4; ++t) {
        if (t < 3) AT_STAGE(cur ^ 1, (t + 1) * 64);
        const bf16* Als = AT_ALS(cur);
        const bf16* Bls = AT_BLS(cur);
#pragma unroll
        for (int ks = 0; ks < 2; ++ks) {
            bf16x8 af[4], bfr[4];
#pragma unroll
            for (int i = 0; i < 4; ++i) {
                int row = wm + i * 16 + l15;
                int c = ks * 4 + gg;
                af[i] = *(bf16x8*)&Als[row * 64 + ((c ^ (row & 7)) * 8)];
            }
#pragma unroll
            for (int j = 0; j < 4; ++j) {
                int row = wn + j * 16 + l15;
                int c = ks * 4 + gg;
                bfr[j] = *(bf16x8*)&Bls[row * 64 + ((c ^ (row & 7)) * 8)];
            }
#pragma unroll
            for (int i = 0; i < 4; ++i)
#pragma unroll
                for (int j = 0; j < 4; ++j)
                    acc[i][j] = __builtin_amdgcn_mfma_f32_16x16x32_bf16(af[i], bfr[j], acc[i][j], 0, 0, 0);
        }
        __syncthreads();
        cur ^= 1;
    }
#undef AT_STAGE
#undef AT_ALS
#undef AT_BLS

    int r4 = (lane >> 4) * 4;
#pragma unroll
    for (int j = 0; j < 4; ++j) {
        int col = wn + j * 16 + l15;
        float bvv = bias[col];
#pragma unroll
        for (int i = 0; i < 4; ++i)
#pragma unroll
            for (int r = 0; r < 4; ++r)
                Cls[(wm + i * 16 + r4 + r) * 260 + col] = f2bf(acc[i][j][r] + bvv);
    }
    __syncthreads();

    int c4 = lane * 4;
    float4 gw = *(const float4*)&g[c4];
    float4 bw = *(const float4*)&b[c4];
#pragma unroll 2
    for (int rw = 0; rw < 16; ++rw) {
        int row = wave * 16 + rw;
        size_t gidx = (size_t)(bm + row) * 256 + c4;
        bf16x4 xb = *(const bf16x4*)(Xb + gidx);
        bf16x4 cb = *(const bf16x4*)&Cls[row * 260 + c4];
        float4 v;
        v.x = (float)xb[0] + (float)cb[0];
        v.y = (float)xb[1] + (float)cb[1];
        v.z = (float)xb[2] + (float)cb[2];
        v.w = (float)xb[3] + (float)cb[3];
        float s  = v.x + v.y + v.z + v.w;
        float sq = v.x * v.x + v.y * v.y + v.z * v.z + v.w * v.w;
#pragma unroll
        for (int off = 32; off > 0; off >>= 1) {
            s  += __shfl_xor(s,  off);
            sq += __shfl_xor(sq, off);
        }
        float mean = s * (1.f / 256.f);
        float var  = sq * (1.f / 256.f) - mean * mean;
        float rstd = rsqrtf(var + 1e-5f);
        bf16x4 ob;
        ob[0] = f2bf((v.x - mean) * rstd * gw.x + bw.x);
        ob[1] = f2bf((v.y - mean) * rstd * gw.y + bw.y);
        ob[2] = f2bf((v.z - mean) * rstd * gw.z + bw.z);
        ob[3] = f2bf((v.w - mean) * rstd * gw.w + bw.w);
        *(bf16x4*)(Xb + gidx) = ob;
    }
}

// ---------------------------------------------------------------------------
// KV prep: grid (32 sp, 64 nh), 256 thr = 4 waves.
// ---------------------------------------------------------------------------
__global__ __launch_bounds__(256) void kv_prep_part(const bf16* __restrict__ Kb,
                                                    const bf16* __restrict__ Vb,
                                                    float* __restrict__ Pkv,
                                                    float* __restrict__ Pks) {
    __shared__ float Ks[128][32];
    __shared__ float Vs[128][32];
    int sp = blockIdx.x;
    int nh = blockIdx.y;
    int n = nh >> 3, h = nh & 7;
    int tid = threadIdx.x;
    int wave = tid >> 6, lane = tid & 63;
    int mg = lane >> 3;
    int dg = lane & 7;
    size_t base = ((size_t)n * 4096 + sp * 128) * 256 + h * 32;

#pragma unroll
    for (int p = 0; p < 2; ++p) {
        int r = p * 64 + (tid >> 2);
        int c = (tid & 3) * 8;
        bf16x8 k8 = *(const bf16x8*)(Kb + base + (size_t)r * 256 + c);
        bf16x8 v8 = *(const bf16x8*)(Vb + base + (size_t)r * 256 + c);
#pragma unroll
        for (int u = 0; u < 8; ++u) { Ks[r][c + u] = (float)k8[u]; Vs[r][c + u] = (float)v8[u]; }
    }
    __syncthreads();

    float acc[4][4] = {};
    float ks4[4] = {};
    int s0 = wave * 32;
    for (int s = s0; s < s0 + 32; ++s) {
        float4 kq = *(float4*)&Ks[s][dg * 4];
        float4 vq = *(float4*)&Vs[s][mg * 4];
        ks4[0] += kq.x; ks4[1] += kq.y; ks4[2] += kq.z; ks4[3] += kq.w;
        acc[0][0] += vq.x * kq.x; acc[0][1] += vq.x * kq.y; acc[0][2] += vq.x * kq.z; acc[0][3] += vq.x * kq.w;
        acc[1][0] += vq.y * kq.x; acc[1][1] += vq.y * kq.y; acc[1][2] += vq.y * kq.z; acc[1][3] += vq.y * kq.w;
        acc[2][0] += vq.z * kq.x; acc[2][1] += vq.z * kq.y; acc[2][2] += vq.z * kq.z; acc[2][3] += vq.z * kq.w;
        acc[3][0] += vq.w * kq.x; acc[3][1] += vq.w * kq.y; acc[3][2] += vq.w * kq.z; acc[3][3] += vq.w * kq.w;
    }
    __syncthreads();

    float* R  = &Ks[0][0];
    float* RS = &Vs[0][0];
#pragma unroll
    for (int mi = 0; mi < 4; ++mi)
#pragma unroll
        for (int dj = 0; dj < 4; ++dj)
            R[wave * 1024 + (mg * 4 + mi) * 32 + dg * 4 + dj] = acc[mi][dj];
    if (mg == 0)
#pragma unroll
        for (int dj = 0; dj < 4; ++dj) RS[wave * 32 + dg * 4 + dj] = ks4[dj];
    __syncthreads();

    int e = tid * 4;
    float4 o0 = *(float4*)&R[e];
    float4 o1 = *(float4*)&R[1024 + e];
    float4 o2 = *(float4*)&R[2048 + e];
    float4 o3 = *(float4*)&R[3072 + e];
    float4 o = make_float4(o0.x + o1.x + o2.x + o3.x, o0.y + o1.y + o2.y + o3.y,
                           o0.z + o1.z + o2.z + o3.z, o0.w + o1.w + o2.w + o3.w);
    *(float4*)&Pkv[((size_t)nh * 32 + sp) * 1024 + e] = o;
    if (tid < 32)
        Pks[((size_t)nh * 32 + sp) * 32 + tid] = RS[tid] + RS[32 + tid] + RS[64 + tid] + RS[96 + tid];
}

// grid (64 nh, 4 quarters), 64 threads (1 wave).
__global__ __launch_bounds__(64) void kv_reduce(const float* __restrict__ Pkv,
                                                const float* __restrict__ Pks,
                                                float* __restrict__ KV,
                                                float* __restrict__ Ksum) {
    int nh = blockIdx.x;
    int q = blockIdx.y;
    int e = (q * 64 + threadIdx.x) * 4;
    float4 s = make_float4(0.f, 0.f, 0.f, 0.f);
    for (int sp = 0; sp < 32; ++sp) {
        float4 p = *(const float4*)&Pkv[((size_t)nh * 32 + sp) * 1024 + e];
        s.x += p.x; s.y += p.y; s.z += p.z; s.w += p.w;
    }
    *(float4*)&KV[(size_t)nh * 1024 + e] = s;
    if (q == 0 && threadIdx.x < 32) {
        float ss = 0.f;
        for (int sp = 0; sp < 32; ++sp) ss += Pks[((size_t)nh * 32 + sp) * 32 + threadIdx.x];
        Ksum[nh * 32 + threadIdx.x] = ss;
    }
}

// ---------------------------------------------------------------------------
// Weff[n][c][h*32+d] = sum_m KV[n,h,m,d] * Wo[(h,m),c]   (bf16, Wt layout)
// ---------------------------------------------------------------------------
__global__ __launch_bounds__(256) void weff_kernel(const float* __restrict__ KV,
                                                   const bf16* __restrict__ WtO,
                                                   bf16* __restrict__ Weff) {
    __shared__ float KVs[8][1024];   // [h][m*32+d]
    int n = blockIdx.y, c0 = blockIdx.x * 64;
    int tid = threadIdx.x;
    const float* src = KV + (size_t)n * 8192;
    for (int i = tid; i < 2048; i += 256)
        *(float4*)&((float*)KVs)[i * 4] = *(const float4*)&src[i * 4];
    __syncthreads();

    int c = c0 + (tid & 63);
    int hb = tid >> 6;               // wave id: h in {2hb, 2hb+1}
    const bf16* wrow = WtO + (size_t)c * 256 + hb * 64;
    bf16* dst = Weff + (size_t)n * 65536 + (size_t)c * 256 + hb * 64;

#pragma unroll
    for (int hh = 0; hh < 2; ++hh) {
        int h = hb * 2 + hh;
        float wo[32];
#pragma unroll
        for (int u = 0; u < 4; ++u) {
            bf16x8 w8 = *(const bf16x8*)(wrow + hh * 32 + u * 8);
#pragma unroll
            for (int v = 0; v < 8; ++v) wo[u * 8 + v] = (float)w8[v];
        }
        float s[32] = {};
        for (int m = 0; m < 32; ++m) {
            float wm = wo[m];
#pragma unroll
            for (int d4 = 0; d4 < 8; ++d4) {
                float4 kv4 = *(float4*)&KVs[h][m * 32 + d4 * 4];
                s[d4 * 4 + 0] += wm * kv4.x;
                s[d4 * 4 + 1] += wm * kv4.y;
                s[d4 * 4 + 2] += wm * kv4.z;
                s[d4 * 4 + 3] += wm * kv4.w;
            }
        }
#pragma unroll
        for (int u = 0; u < 4; ++u) {
            bf16x8 o8;
#pragma unroll
            for (int v = 0; v < 8; ++v) o8[v] = f2bf(s[u * 8 + v]);
            *(bf16x8*)(dst + hh * 32 + u * 8) = o8;
        }
    }
}

// ---------------------------------------------------------------------------
// Store: Xb[b,t,c] bf16 -> out[b,c,t] f32
// ---------------------------------------------------------------------------
__global__ __launch_bounds__(1024) void store_kernel(const bf16* __restrict__ Xb,
                                                     float* __restrict__ out) {
    __shared__ float tile[32][33];
    int b = blockIdx.z;
    int t0 = blockIdx.x * 32, c0 = blockIdx.y * 32;
    tile[threadIdx.y][threadIdx.x] =
        (float)Xb[((size_t)b * 4096 + t0 + threadIdx.y) * 256 + c0 + threadIdx.x];
    __syncthreads();
    out[((size_t)b * 256 + c0 + threadIdx.y) * 4096 + t0 + threadIdx.x] =
        tile[threadIdx.x][threadIdx.y];
}

// ---------------------------------------------------------------------------
extern "C" void kernel_launch(void* const* d_in, const int* in_sizes, int n_in,
                              void* d_out, int out_size, void* d_ws, size_t ws_size,
                              hipStream_t stream) {
    const float* ref  = (const float*)d_in[0];
    const float* srcf = (const float*)d_in[1];
    const float* Wq = (const float*)d_in[2];
    const float* bq = (const float*)d_in[3];
    const float* Wk = (const float*)d_in[4];
    const float* bk = (const float*)d_in[5];
    const float* Wv = (const float*)d_in[6];
    const float* bv = (const float*)d_in[7];
    const float* Wo = (const float*)d_in[8];
    const float* bo = (const float*)d_in[9];
    const float* W1 = (const float*)d_in[10];
    const float* b1 = (const float*)d_in[11];
    const float* W2 = (const float*)d_in[12];
    const float* b2 = (const float*)d_in[13];
    const float* g1 = (const float*)d_in[14];
    const float* be1 = (const float*)d_in[15];
    const float* g2 = (const float*)d_in[16];
    const float* be2 = (const float*)d_in[17];

    const size_t SZ = (size_t)8 * 4096 * 256;
    float* ws  = (float*)d_ws;
    float* KVb = ws;                          // 65536 f32
    float* Ksb = KVb + 65536;                 // 2048 f32
    float* Pkv = Ksb + 2048;                  // 2,097,152 f32
    float* Pks = Pkv + 2097152;               // 65536 f32
    bf16*  Wt  = (bf16*)(Pks + 65536);        // 2,097,152 bf16
    bf16*  Xb  = Wt + 2097152;                // SZ bf16 (residual stream)
    bf16*  P2b = Xb + SZ;                     // SZ bf16
    bf16*  Qb  = P2b + SZ;                    // SZ bf16
    // Weff (1 MB bf16) aliases the Pkv head (written after kv_reduce reads Pkv).
    bf16*  Weffb = (bf16*)Pkv;                // 524288 bf16 = 1 MB
    // K/V live in d_out (exact 2*SZ bf16 fit); dead before store_kernel runs.
    bf16*  Kb  = (bf16*)d_out;
    bf16*  Vb  = Kb + SZ;
    bf16*  Hb  = Kb;                          // alias: FFN hidden spans Kb+Vb

    wt_conv<<<dim3(16, 16, 24), dim3(32, 32), 0, stream>>>(Wq, Wk, Wv, Wo, W1, W2, Wt);
    encode_kernel<<<dim3(128, 8, 8), dim3(32, 32), 0, stream>>>(ref, srcf, Xb, P2b);

    for (int L = 0; L < 4; ++L) {
        const bf16* WtL = Wt + (size_t)L * 524288;
        const bf16* Akv = (L & 1) ? P2b : Xb;
        gemm_qkv<<<1536, 256, 0, stream>>>(Xb, Akv, WtL,
                                           bq + L * 256, bk + L * 256, bv + L * 256,
                                           Qb, Kb, Vb);
        kv_prep_part<<<dim3(32, 64), 256, 0, stream>>>(Kb, Vb, Pkv, Pks);
        kv_reduce<<<dim3(64, 4), 64, 0, stream>>>(Pkv, Pks, KVb, Ksb);
        weff_kernel<<<dim3(4, 8), 256, 0, stream>>>(KVb, WtL + 196608, Weffb);
        // attention + O-proj + residual + LN1 as one GEMM, Z computed in-kernel
        gemm_attn_ln<<<256, 512, 0, stream>>>(Qb, Ksb, Weffb, bo + L * 256, Xb,
                                              g1 + L * 256, be1 + L * 256);
        // FFN1 (relu) -> Hb
        gemm_mfma<1><<<1024, 256, 0, stream>>>(Xb, WtL + 262144, b1 + L * 512, Hb, 512, 256, 4);
        // FFN2 + residual + LN2 fused
        gemm_ln<<<256, 512, 0, stream>>>(Hb, WtL + 393216, b2 + L * 256, Xb,
                                         g2 + L * 256, be2 + L * 256, 512);
    }

    store_kernel<<<dim3(128, 8, 8), dim3(32, 32), 0, stream>>>(Xb, (float*)d_out);
}